// Round 2
// baseline (1635.716 us; speedup 1.0000x reference)
//
#include <hip/hip_runtime.h>
#include <cstdint>
#include <cstddef>

// ---------------- constants ----------------
constexpr int BATCH = 64, SEQ = 4096, FEAT = 8, PLEN = 16;
constexpr int DMODEL = 512, NHEAD = 8, NLAYER = 6, DFF = 2048;
constexpr int NPATCH = 256, MROWS = BATCH * NPATCH;   // 16384
constexpr int DK = 64;
constexpr int LDSP = 72;   // padded LDS row stride (u16) for attn tiles

typedef unsigned short u16t;
typedef __bf16 bf16t;
typedef bf16t bf16x8 __attribute__((ext_vector_type(8)));
typedef short s16x4 __attribute__((ext_vector_type(4)));
typedef float f32x4 __attribute__((ext_vector_type(4)));

__device__ __forceinline__ float b2f(u16t u) {
  union { unsigned int ui; float f; } v; v.ui = ((unsigned int)u) << 16; return v.f;
}
__device__ __forceinline__ u16t f2b(float f) {
  union { float f; unsigned int ui; } v; v.f = f;
  return (u16t)((v.ui + 0x7fffu + ((v.ui >> 16) & 1u)) >> 16);
}
__device__ __forceinline__ void g2l16(void* lds, const void* g) {
  __builtin_amdgcn_global_load_lds(
      (__attribute__((address_space(1))) void*)g,
      (__attribute__((address_space(3))) void*)lds, 16, 0, 0);
}

// exact-erf GELU via Abramowitz-Stegun 7.1.26 (|erf err| < 1.5e-7).
__device__ __forceinline__ float gelu_erf(float x) {
  const float z = fabsf(x) * 0.70710678118654752f;
  const float t = __builtin_amdgcn_rcpf(__builtin_fmaf(0.3275911f, z, 1.0f));
  float p = __builtin_fmaf(1.061405429f, t, -1.453152027f);
  p = __builtin_fmaf(p, t, 1.421413741f);
  p = __builtin_fmaf(p, t, -0.284496736f);
  p = __builtin_fmaf(p, t, 0.254829592f);
  const float e = __expf(-z * z);
  const float er = __builtin_fmaf(-p * t, e, 1.0f);   // erf(|z|)
  const float s = copysignf(er, x);
  return 0.5f * x * (1.0f + s);
}

// ---------------- bf16 MFMA GEMM: C[M,N] = A[M,K] @ Bt[N,K]^T (+epilogue) ----
// R11: m201-style per-phase schedule (T2+T3+T4+T5), 512 threads / 8 waves.
//  - tile 256x128, BK=32, wave-tile 64x64 (wr=wave>>1, wc=wave&1), acc[4][4].
//  - ring-of-4 LDS slots (4 x 24KB = 96KB): each slot = A 256x32 + B 128x32.
//    Phase s computes sub-tile s (slot s&3) and stages sub-tile s+3 (slot
//    (s-1)&3, last read previous phase -> WAR safe across 2 barriers).
//    Stage->consume distance = 3 phases (~2000+ cy >> 900 cy HBM latency).
//  - per phase: {8 ds_read_b128 | 3 g2l16} -> s_barrier -> lgkmcnt(0)+
//    sched_barrier(0) -> setprio(1) 16 MFMA setprio(0) -> counted vmcnt ->
//    s_barrier.  vmcnt gates (derived, 3 instr/sub-tile, prologue=3 subtiles):
//    steady 6; tail 3, 0, 0.  Never drain mid-loop.
//  - staging: global_load_lds w=16, linear LDS dest, XOR-pre-swizzled global
//    source; ds_read fragments use the same XOR => conflict-free (R10 PMC:
//    bank-conflict counter at b128 baseline only).
//  - epilogues carried unchanged from R9/R10 (proven full-sector patterns).
// mode 0: Cb = bf16(acc+bias)        mode 1: Cb = bf16(gelu(acc+bias))
// mode 2: Cf += acc+bias (residual)  mode 3: Cf  = acc+bias
__global__ __launch_bounds__(512, 2) void k_gemm(
    const u16t* __restrict__ A, const u16t* __restrict__ Bt,
    const float* __restrict__ bias, const float* __restrict__ b2,
    const float* __restrict__ b3, float* __restrict__ Cf,
    u16t* __restrict__ Cb, int M, int N, int K, int mode)
{
  __shared__ __align__(16) u16t SH[4 * 12288];   // 96 KiB ring; epilogue reuses

  // ---- XCD-aware bijective swizzle (1-D grid, nwg % 8 == 0 for all shapes)
  const int nbn = N >> 7;                       // N / 128
  const int cpx = gridDim.x >> 3;
  const int wgid = (blockIdx.x & 7) * cpx + (blockIdx.x >> 3);
  const int bm = (wgid / nbn) << 8;             // 256-row tile
  const int bn = (wgid % nbn) << 7;             // 128-col tile

  const int tid = threadIdx.x, wave = tid >> 6, lane = tid & 63;
  const int lr = lane & 15, quad = lane >> 4;
  const int wm = (wave >> 1) << 6;              // 0/64/128/192
  const int wn = (wave & 1) << 6;               // 0/64

  // staging source: chunk c = 16 rows x 64B; lane l -> row c*16 + (l>>2),
  // phys seg l&3, pre-swizzled logical seg (l&3)^((l>>3)&3)  [= (l&3)^((row>>1)&3)]
  const int sseg = (lane & 3) ^ ((lane >> 3) & 3);
  const u16t* gA0 = A + (size_t)(bm + (lane >> 2)) * K + sseg * 8;
  const u16t* gB0 = Bt + (size_t)(bn + (lane >> 2)) * K + sseg * 8;

  // fragment ds_read offsets (u16 units within one ring slot)
  const int sw8 = (quad ^ ((lr >> 1) & 3)) << 3;
  const int aoff = (wm + lr) * 32 + sw8;          // + i*512 per M-frag
  const int boff = 8192 + (wn + lr) * 32 + sw8;   // + j*512 per N-frag

  f32x4 acc[4][4] = {};   // [jN][iM]: reg r -> N-col quad*4+r, lane lr -> M-row

  const int nt = K >> 5;

  // stage one sub-tile: A (2 instr/thread) + B (1 instr/thread), issue order A,A,B
#define STAGE3(S_) do {                                                        \
    u16t* dA_ = SH + (((S_) & 3) * 12288);                                     \
    g2l16(dA_ + wave * 512,       gA0 + (size_t)(wave * 16) * K + (S_) * 32);  \
    g2l16(dA_ + (wave + 8) * 512, gA0 + (size_t)((wave + 8) * 16) * K + (S_) * 32); \
    g2l16(dA_ + 8192 + wave * 512, gB0 + (size_t)(wave * 16) * K + (S_) * 32); \
  } while (0)

  // one phase: compute sub-tile S, stage sub-tile S+3, end-gate vmcnt(NG)
#define NPHASE(S_, NG_) do {                                                   \
    const int s_ = (S_);                                                       \
    const int slot_ = (s_ & 3) * 12288;                                        \
    bf16x8 af_[4], bfr_[4];                                                    \
    _Pragma("unroll")                                                          \
    for (int i = 0; i < 4; ++i)                                                \
      af_[i] = *(const bf16x8*)&SH[slot_ + aoff + i * 512];                    \
    _Pragma("unroll")                                                          \
    for (int j = 0; j < 4; ++j)                                                \
      bfr_[j] = *(const bf16x8*)&SH[slot_ + boff + j * 512];                   \
    if (s_ + 3 < nt) STAGE3(s_ + 3);                                           \
    __builtin_amdgcn_s_barrier();                                              \
    asm volatile("s_waitcnt lgkmcnt(0)" ::: "memory");                         \
    __builtin_amdgcn_sched_barrier(0);                                         \
    __builtin_amdgcn_s_setprio(1);                                             \
    _Pragma("unroll")                                                          \
    for (int j = 0; j < 4; ++j)                                                \
      _Pragma("unroll")                                                        \
      for (int i = 0; i < 4; ++i)                                              \
        acc[j][i] = __builtin_amdgcn_mfma_f32_16x16x32_bf16(bfr_[j], af_[i], acc[j][i], 0, 0, 0); \
    __builtin_amdgcn_s_setprio(0);                                             \
    asm volatile("s_waitcnt vmcnt(" #NG_ ")" ::: "memory");                    \
    __builtin_amdgcn_s_barrier();                                              \
  } while (0)

  // prologue: stage sub-tiles 0,1,2 (9 instr); gate so sub-tile 0 landed
  STAGE3(0); STAGE3(1); STAGE3(2);
  asm volatile("s_waitcnt vmcnt(6)" ::: "memory");
  __builtin_amdgcn_s_barrier();

  for (int s = 0; s < nt - 3; ++s) NPHASE(s, 6);
  NPHASE(nt - 3, 3);
  NPHASE(nt - 2, 0);
  NPHASE(nt - 1, 0);
#undef NPHASE
#undef STAGE3

  // block-uniform bias base (fused-QKV select)
  const float* bp = bias;
  int reg0 = 0;
  if (bias && b2) { reg0 = (bn >> 9) << 9; bp = reg0 == 0 ? bias : (reg0 == 512 ? b2 : b3); }
  float4 bv[4];
  #pragma unroll
  for (int jN = 0; jN < 4; ++jN) {
    const int gn0 = bn + wn + jN * 16 + quad * 4;
    bv[jN] = bias ? *(const float4*)&bp[gn0 - reg0] : make_float4(0.f, 0.f, 0.f, 0.f);
  }

  if (mode <= 1) {
    __syncthreads();   // all waves done with ring before reuse as E
    // deposit: 8 waves, disjoint (wm, wn) 64x64 quadrants of the 256x128 tile
    u16t* E = SH;      // [256][128] u16, seg-swizzled (R8/R9-proven pattern)
    #pragma unroll
    for (int jN = 0; jN < 4; ++jN) {
      const int cl = wn + jN * 16 + quad * 4;
      const int seg = cl >> 3, intra = cl & 7;
      #pragma unroll
      for (int iM = 0; iM < 4; ++iM) {
        const int r = wm + iM * 16 + lr;
        float v0 = acc[jN][iM][0] + bv[jN].x, v1 = acc[jN][iM][1] + bv[jN].y;
        float v2 = acc[jN][iM][2] + bv[jN].z, v3 = acc[jN][iM][3] + bv[jN].w;
        union { u16t h[4]; uint2 u; } pk;
        if (mode == 1) {
          pk.h[0] = f2b(gelu_erf(v0)); pk.h[1] = f2b(gelu_erf(v1));
          pk.h[2] = f2b(gelu_erf(v2)); pk.h[3] = f2b(gelu_erf(v3));
        } else {
          pk.h[0] = f2b(v0); pk.h[1] = f2b(v1); pk.h[2] = f2b(v2); pk.h[3] = f2b(v3);
        }
        *(uint2*)&E[r * 128 + ((seg ^ (r & 7)) << 3) + intra] = pk.u;
      }
    }
    __syncthreads();
    // readout: per instruction, 4 consecutive lanes -> one full 64B sector of
    // one row (R7-verified); 2 passes x 128 rows cover 256 rows.
    const int rr = tid >> 2, s0 = tid & 3;
    #pragma unroll
    for (int pass = 0; pass < 2; ++pass) {
      const int r = pass * 128 + rr;
      u16t* gout = Cb + (size_t)(bm + r) * N + bn;
      #pragma unroll
      for (int it = 0; it < 4; ++it) {
        const int s = s0 + it * 4;
        uint4 u = *(const uint4*)&E[r * 128 + ((s ^ (r & 7)) << 3)];
        *(uint4*)(gout + s * 8) = u;
      }
    }
  } else {
    // fp32: direct (full-sector: 4 quads x 16B = 64B per row per instr)
    #pragma unroll
    for (int jN = 0; jN < 4; ++jN) {
      const int gn0 = bn + wn + jN * 16 + quad * 4;
      #pragma unroll
      for (int iM = 0; iM < 4; ++iM) {
        const int gm = bm + wm + iM * 16 + lr;
        const size_t off = (size_t)gm * N + gn0;
        float v0 = acc[jN][iM][0] + bv[jN].x, v1 = acc[jN][iM][1] + bv[jN].y;
        float v2 = acc[jN][iM][2] + bv[jN].z, v3 = acc[jN][iM][3] + bv[jN].w;
        if (mode == 2) {
          float4 c = *(float4*)(Cf + off);
          c.x += v0; c.y += v1; c.z += v2; c.w += v3;
          *(float4*)(Cf + off) = c;
        } else {
          *(float4*)(Cf + off) = make_float4(v0, v1, v2, v3);
        }
      }
    }
  }
}

// ---------------- weight prep: Wt[orow0+n][k] = bf16(W[k][n] (+ 2*down@up)) -
__global__ __launch_bounds__(256) void k_prep_w(
    const float* __restrict__ W, const float* __restrict__ down,
    const float* __restrict__ up, u16t* __restrict__ Wt, int K, int N,
    size_t ostride, int orow0)
{
  __shared__ float t[32][33];
  const int z = blockIdx.z;
  const float* Wz = W + (size_t)z * K * N;
  u16t* Wtz = Wt + (size_t)z * ostride + (size_t)orow0 * K;
  const int k0 = blockIdx.x * 32, n0 = blockIdx.y * 32;
  const int tx = threadIdx.x & 31, ty = threadIdx.x >> 5;
  for (int i = ty; i < 32; i += 8) {
    const int kk = k0 + i, nn = n0 + tx;
    float v = Wz[(size_t)kk * N + nn];
    if (down) {
      const float* dz = down + (size_t)z * K * 8 + (size_t)kk * 8;
      const float* uz = up + (size_t)z * 8 * N + nn;
      float lv = 0.f;
      #pragma unroll
      for (int r = 0; r < 8; ++r) lv += dz[r] * uz[(size_t)r * N];
      v += 2.0f * lv;   // LORA_SCALING
    }
    t[i][tx] = v;
  }
  __syncthreads();
  for (int i = ty; i < 32; i += 8)
    Wtz[(size_t)(n0 + i) * K + k0 + tx] = f2b(t[tx][i]);
}

// ---------------- patch gather: pt[(b*256+np)*128 + f*16+p] = x[b, np*16+p, f]
__global__ void k_patch(const float* __restrict__ x, u16t* __restrict__ pt) {
  const int idx = blockIdx.x * 256 + threadIdx.x;
  const int col = idx & 127, row = idx >> 7;
  const int f = col >> 4, pp = col & 15;
  const int b = row >> 8, np = row & 255;
  pt[idx] = f2b(x[(((size_t)b << 12) + np * 16 + pp) * 8 + f]);
}

// ---------------- LayerNorm (one wave per 512-row) -> bf16 ----------------
__global__ __launch_bounds__(256) void k_ln(
    const float* __restrict__ xin, const float* __restrict__ w,
    const float* __restrict__ bb, u16t* __restrict__ y)
{
  const int row = blockIdx.x * 4 + (threadIdx.x >> 6);
  const int lane = threadIdx.x & 63;
  const float4* xr = (const float4*)(xin + (size_t)row * 512);
  float4 a = xr[lane * 2], c = xr[lane * 2 + 1];
  float s = a.x + a.y + a.z + a.w + c.x + c.y + c.z + c.w;
  float qq = a.x * a.x + a.y * a.y + a.z * a.z + a.w * a.w +
             c.x * c.x + c.y * c.y + c.z * c.z + c.w * c.w;
  #pragma unroll
  for (int o = 32; o > 0; o >>= 1) { s += __shfl_xor(s, o); qq += __shfl_xor(qq, o); }
  const float mean = s * (1.f / 512.f);
  const float rs = rsqrtf(qq * (1.f / 512.f) - mean * mean + 1e-5f);
  const float4* wr = (const float4*)w; const float4* br = (const float4*)bb;
  float4 w0 = wr[lane * 2], w1 = wr[lane * 2 + 1];
  float4 b0 = br[lane * 2], b1 = br[lane * 2 + 1];
  union { u16t h[8]; uint4 v; } pk;
  pk.h[0] = f2b((a.x - mean) * rs * w0.x + b0.x);
  pk.h[1] = f2b((a.y - mean) * rs * w0.y + b0.y);
  pk.h[2] = f2b((a.z - mean) * rs * w0.z + b0.z);
  pk.h[3] = f2b((a.w - mean) * rs * w0.w + b0.w);
  pk.h[4] = f2b((c.x - mean) * rs * w1.x + b1.x);
  pk.h[5] = f2b((c.y - mean) * rs * w1.y + b1.y);
  pk.h[6] = f2b((c.z - mean) * rs * w1.z + b1.z);
  pk.h[7] = f2b((c.w - mean) * rs * w1.w + b1.w);
  *(uint4*)(y + (size_t)row * 512 + lane * 8) = pk.v;
}

// ---------------- patch LN + pos_enc -> h (fp32) ----------------
__global__ __launch_bounds__(256) void k_ln_pos(
    const float* __restrict__ xin, const float* __restrict__ w,
    const float* __restrict__ bb, const float* __restrict__ pos,
    float* __restrict__ h)
{
  const int row = blockIdx.x * 4 + (threadIdx.x >> 6);
  const int lane = threadIdx.x & 63;
  const float4* xr = (const float4*)(xin + (size_t)row * 512);
  float4 a = xr[lane * 2], c = xr[lane * 2 + 1];
  float s = a.x + a.y + a.z + a.w + c.x + c.y + c.z + c.w;
  float qq = a.x * a.x + a.y * a.y + a.z * a.z + a.w * a.w +
             c.x * c.x + c.y * c.y + c.z * c.z + c.w * c.w;
  #pragma unroll
  for (int o = 32; o > 0; o >>= 1) { s += __shfl_xor(s, o); qq += __shfl_xor(qq, o); }
  const float mean = s * (1.f / 512.f);
  const float rs = rsqrtf(qq * (1.f / 512.f) - mean * mean + 1e-5f);
  const float4* wr = (const float4*)w; const float4* br = (const float4*)bb;
  float4 w0 = wr[lane * 2], w1 = wr[lane * 2 + 1];
  float4 b0 = br[lane * 2], b1 = br[lane * 2 + 1];
  const int np = row & 255;
  const float4* pr = (const float4*)(pos + (size_t)np * 512);
  float4 p0 = pr[lane * 2], p1 = pr[lane * 2 + 1];
  float4 o0, o1;
  o0.x = (a.x - mean) * rs * w0.x + b0.x + p0.x;
  o0.y = (a.y - mean) * rs * w0.y + b0.y + p0.y;
  o0.z = (a.z - mean) * rs * w0.z + b0.z + p0.z;
  o0.w = (a.w - mean) * rs * w0.w + b0.w + p0.w;
  o1.x = (c.x - mean) * rs * w1.x + b1.x + p1.x;
  o1.y = (c.y - mean) * rs * w1.y + b1.y + p1.y;
  o1.z = (c.z - mean) * rs * w1.z + b1.z + p1.z;
  o1.w = (c.w - mean) * rs * w1.w + b1.w + p1.w;
  float4* hr = (float4*)(h + (size_t)row * 512);
  hr[lane * 2] = o0; hr[lane * 2 + 1] = o1;
}

// ---------------- MFMA flash attention -------------------------------------
__global__ __launch_bounds__(256) void k_attn(
    const u16t* __restrict__ qkv, u16t* __restrict__ out)
{
  __shared__ __align__(16) u16t Qs[128 * LDSP];
  __shared__ __align__(16) u16t Ks[64 * LDSP];
  __shared__ __align__(16) u16t Vts[64 * LDSP];

  const int bh = blockIdx.x >> 1, half = blockIdx.x & 1;
  const int b = bh >> 3, hd = bh & 7;
  const int tid = threadIdx.x, wave = tid >> 6, lane = tid & 63;
  const int lr = lane & 15, quad = lane >> 4;

  const size_t rowbase = (size_t)b * 256;
  const u16t* qg = qkv + (rowbase + half * 128) * 1536 + hd * 64;
  const u16t* kg = qkv + rowbase * 1536 + 512 + hd * 64;
  const u16t* vg = qkv + rowbase * 1536 + 1024 + hd * 64;

  #pragma unroll
  for (int i = 0; i < 4; ++i) {
    const int idx = tid + i * 256, row = idx >> 3, seg = idx & 7;
    uint4 u = *(const uint4*)(qg + (size_t)row * 1536 + seg * 8);
    *(uint4*)&Qs[row * LDSP + seg * 8] = u;
  }
  __syncthreads();

  bf16x8 qf[2][2];
  #pragma unroll
  for (int qi = 0; qi < 2; ++qi)
    #pragma unroll
    for (int dh = 0; dh < 2; ++dh)
      qf[qi][dh] = *(const bf16x8*)&Qs[(wave * 32 + qi * 16 + lr) * LDSP + dh * 32 + quad * 8];

  f32x4 O[2][4] = {};
  float mrun[2] = {-1e30f, -1e30f}, lrun[2] = {0.f, 0.f};

  for (int c = 0; c < 4; ++c) {
    __syncthreads();
    #pragma unroll
    for (int i = 0; i < 2; ++i) {
      const int idx = tid + i * 256, row = idx >> 3, seg = idx & 7;
      uint4 u = *(const uint4*)(kg + (size_t)(c * 64 + row) * 1536 + seg * 8);
      *(uint4*)&Ks[row * LDSP + seg * 8] = u;
    }
    {
      const int key = tid & 63, dg = (tid >> 6) * 16;
      const u16t* vrow = vg + (size_t)(c * 64 + key) * 1536 + dg;
      union { u16t h[16]; uint4 v[2]; } tmp;
      tmp.v[0] = *(const uint4*)(vrow);
      tmp.v[1] = *(const uint4*)(vrow + 8);
      #pragma unroll
      for (int i = 0; i < 16; ++i)
        Vts[(dg + i) * LDSP + key] = tmp.h[i];
    }
    __syncthreads();

    #pragma unroll
    for (int qi = 0; qi < 2; ++qi) {
      f32x4 s[4];
      #pragma unroll
      for (int kt = 0; kt < 4; ++kt) {
        f32x4 a = {};
        #pragma unroll
        for (int dh = 0; dh < 2; ++dh) {
          bf16x8 kf = *(const bf16x8*)&Ks[(kt * 16 + lr) * LDSP + dh * 32 + quad * 8];
          a = __builtin_amdgcn_mfma_f32_16x16x32_bf16(kf, qf[qi][dh], a, 0, 0, 0);
        }
        s[kt] = a;
      }
      constexpr float SC = 0.125f * 1.44269504088896f;
      float cmax = -1e30f;
      #pragma unroll
      for (int kt = 0; kt < 4; ++kt)
        #pragma unroll
        for (int r = 0; r < 4; ++r) { s[kt][r] *= SC; cmax = fmaxf(cmax, s[kt][r]); }
      cmax = fmaxf(cmax, __shfl_xor(cmax, 16));
      cmax = fmaxf(cmax, __shfl_xor(cmax, 32));
      const float mn = fmaxf(mrun[qi], cmax);
      const float alpha = exp2f(mrun[qi] - mn);
      mrun[qi] = mn;
      float lsum = 0.f;
      s16x4 pf[4];
      #pragma unroll
      for (int kt = 0; kt < 4; ++kt) {
        #pragma unroll
        for (int r = 0; r < 4; ++r) {
          const u16t eb = f2b(exp2f(s[kt][r] - mn));
          pf[kt][r] = (short)eb;
          lsum += b2f(eb);
        }
      }
      lsum += __shfl_xor(lsum, 16);
      lsum += __shfl_xor(lsum, 32);
      lrun[qi] = lrun[qi] * alpha + lsum;
      #pragma unroll
      for (int dt = 0; dt < 4; ++dt) {
        f32x4 o = O[qi][dt];
        o[0] *= alpha; o[1] *= alpha; o[2] *= alpha; o[3] *= alpha;
        #pragma unroll
        for (int kt = 0; kt < 4; ++kt) {
          s16x4 vf = *(const s16x4*)&Vts[(dt * 16 + lr) * LDSP + kt * 16 + quad * 4];
          o = __builtin_amdgcn_mfma_f32_16x16x16bf16_1k(vf, pf[kt], o, 0, 0, 0);
        }
        O[qi][dt] = o;
      }
    }
  }
  #pragma unroll
  for (int qi = 0; qi < 2; ++qi) {
    const float rl = 1.f / lrun[qi];
    u16t* orow = out + (rowbase + half * 128 + wave * 32 + qi * 16 + lr) * 512 + hd * 64 + quad * 4;
    #pragma unroll
    for (int dt = 0; dt < 4; ++dt) {
      union { u16t h[4]; uint2 v; } pk;
      #pragma unroll
      for (int r = 0; r < 4; ++r) pk.h[r] = f2b(O[qi][dt][r] * rl);
      *(uint2*)(orow + dt * 16) = pk.v;
    }
  }
}

// ---------------- final mean over patches ----------------
__global__ void k_mean(const u16t* __restrict__ y, float* __restrict__ out) {
  const int b = blockIdx.x, d = threadIdx.x;   // 64 x 512
  float s = 0.f;
  #pragma unroll 8
  for (int np = 0; np < 256; ++np) s += b2f(y[((size_t)b * 256 + np) * 512 + d]);
  out[(size_t)b * 512 + d] = s * (1.f / 256.f);
}

// ---------------- host ----------------
extern "C" void kernel_launch(void* const* d_in, const int* in_sizes, int n_in,
                              void* d_out, int out_size, void* d_ws, size_t ws_size,
                              hipStream_t stream)
{
  (void)in_sizes; (void)n_in; (void)out_size;
  const float* x        = (const float*)d_in[0];
  const float* patch_w  = (const float*)d_in[1];
  const float* patch_b  = (const float*)d_in[2];
  const float* patch_ln_w = (const float*)d_in[3];
  const float* patch_ln_b = (const float*)d_in[4];
  const float* pos_enc  = (const float*)d_in[5];
  const float* ln1_w    = (const float*)d_in[6];
  const float* ln1_b    = (const float*)d_in[7];
  const float* q_w      = (const float*)d_in[8];
  const float* q_b      = (const float*)d_in[9];
  const float* k_w      = (const float*)d_in[10];
  const float* k_b      = (const float*)d_in[11];
  const float* v_w      = (const float*)d_in[12];
  const float* v_b      = (const float*)d_in[13];
  const float* lq_down  = (const float*)d_in[14];
  const float* lq_up    = (const float*)d_in[15];
  const float* lk_down  = (const float*)d_in[16];
  const float* lk_up    = (const float*)d_in[17];
  const float* lv_down  = (const float*)d_in[18];
  const float* lv_up    = (const float*)d_in[19];
  const float* o_w      = (const float*)d_in[20];
  const float* o_b      = (const float*)d_in[21];
  const float* ln2_w    = (const float*)d_in[22];
  const float* ln2_b    = (const float*)d_in[23];
  const float* ff1_w    = (const float*)d_in[24];
  const float* ff1_b    = (const float*)d_in[25];
  const float* ff2_w    = (const float*)d_in[26];
  const float* ff2_b    = (const float*)d_in[27];
  const float* norm_w   = (const float*)d_in[28];
  const float* norm_b   = (const float*)d_in[29];
  float* out = (float*)d_out;

  // workspace carve (~148.1 MiB)
  char* p = (char*)d_ws;
  float* h  = (float*)p;  p += (size_t)MROWS * 512 * 4;       // 32 MB
  u16t*  y  = (u16t*)p;   p += (size_t)MROWS * 512 * 2;       // 16 MB
  char* uni = p;          p += (size_t)4 * MROWS * 512 * 2;   // 64 MB union
  u16t* qkvb = (u16t*)uni;                                    // [M,1536] (48 MB)
  u16t* ab = (u16t*)(uni + (size_t)MROWS * 1536 * 2);         // [M,512]  (16 MB)
  u16t* g  = (u16t*)uni;                                      // [M,2048] aliases qkv+ab
  float* pe = (float*)uni;                                    // [M,512] fp32 (pre-LN patch)
  u16t* pt = (u16t*)(uni + (size_t)MROWS * 512 * 4);          // [M,128] after pe
  u16t* wqkv = (u16t*)p; p += (size_t)NLAYER * 1536 * 512 * 2;
  u16t* wo = (u16t*)p; p += (size_t)NLAYER * 512 * 512 * 2;
  u16t* w1 = (u16t*)p; p += (size_t)NLAYER * 512 * 2048 * 2;
  u16t* w2 = (u16t*)p; p += (size_t)NLAYER * 2048 * 512 * 2;
  u16t* wp = (u16t*)p; p += (size_t)512 * 128 * 2;
  if ((size_t)(p - (char*)d_ws) > ws_size) return;

  const dim3 blk(256);
  const dim3 gblk(512);
  const size_t QKVS = (size_t)1536 * 512;
  k_prep_w<<<dim3(16, 16, NLAYER), blk, 0, stream>>>(q_w, lq_down, lq_up, wqkv, 512, 512, QKVS, 0);
  k_prep_w<<<dim3(16, 16, NLAYER), blk, 0, stream>>>(k_w, lk_down, lk_up, wqkv, 512, 512, QKVS, 512);
  k_prep_w<<<dim3(16, 16, NLAYER), blk, 0, stream>>>(v_w, lv_down, lv_up, wqkv, 512, 512, QKVS, 1024);
  k_prep_w<<<dim3(16, 16, NLAYER), blk, 0, stream>>>(o_w, nullptr, nullptr, wo, 512, 512, (size_t)512 * 512, 0);
  k_prep_w<<<dim3(16, 64, NLAYER), blk, 0, stream>>>(ff1_w, nullptr, nullptr, w1, 512, 2048, (size_t)512 * 2048, 0);
  k_prep_w<<<dim3(64, 16, NLAYER), blk, 0, stream>>>(ff2_w, nullptr, nullptr, w2, 2048, 512, (size_t)2048 * 512, 0);
  k_prep_w<<<dim3(4, 16, 1),       blk, 0, stream>>>(patch_w, nullptr, nullptr, wp, 128, 512, 0, 0);

  k_patch<<<dim3(MROWS * 128 / 256), blk, 0, stream>>>(x, pt);
  // grids: (MROWS/256) * (N/128) blocks, 1-D (all multiples of 8 for swizzle)
  k_gemm<<<dim3(64 * 4), gblk, 0, stream>>>(pt, wp, patch_b, nullptr, nullptr, pe, nullptr, MROWS, 512, 128, 3);
  k_ln_pos<<<dim3(MROWS / 4), blk, 0, stream>>>(pe, patch_ln_w, patch_ln_b, pos_enc, h);

  for (int i = 0; i < NLAYER; ++i) {
    const size_t ws512 = (size_t)i * 512 * 512, wsff = (size_t)i * 512 * 2048;
    k_ln<<<dim3(MROWS / 4), blk, 0, stream>>>(h, ln1_w + i * 512, ln1_b + i * 512, y);
    k_gemm<<<dim3(64 * 12), gblk, 0, stream>>>(y, wqkv + i * QKVS, q_b + i * 512, k_b + i * 512,
                                               v_b + i * 512, nullptr, qkvb, MROWS, 1536, 512, 0);
    k_attn<<<dim3(1024), blk, 0, stream>>>(qkvb, ab);
    k_gemm<<<dim3(64 * 4), gblk, 0, stream>>>(ab, wo + ws512, o_b + i * 512, nullptr, nullptr, h, nullptr, MROWS, 512, 512, 2);
    k_ln<<<dim3(MROWS / 4), blk, 0, stream>>>(h, ln2_w + i * 512, ln2_b + i * 512, y);
    k_gemm<<<dim3(64 * 16), gblk, 0, stream>>>(y, w1 + wsff, ff1_b + i * 2048, nullptr, nullptr, nullptr, g, MROWS, 2048, 512, 1);
    k_gemm<<<dim3(64 * 4), gblk, 0, stream>>>(g, w2 + wsff, ff2_b + i * 512, nullptr, nullptr, h, nullptr, MROWS, 512, 2048, 2);
  }
  k_ln<<<dim3(MROWS / 4), blk, 0, stream>>>(h, norm_w, norm_b, y);
  k_mean<<<dim3(BATCH), dim3(512), 0, stream>>>(y, out);
}

// Round 3
// 1600.361 us; speedup vs baseline: 1.0221x; 1.0221x over previous
//
#include <hip/hip_runtime.h>
#include <cstdint>
#include <cstddef>

// ---------------- constants ----------------
constexpr int BATCH = 64, SEQ = 4096, FEAT = 8, PLEN = 16;
constexpr int DMODEL = 512, NHEAD = 8, NLAYER = 6, DFF = 2048;
constexpr int NPATCH = 256, MROWS = BATCH * NPATCH;   // 16384
constexpr int DK = 64;
constexpr int LDSP = 72;   // padded LDS row stride (u16) for attn tiles

typedef unsigned short u16t;
typedef __bf16 bf16t;
typedef bf16t bf16x8 __attribute__((ext_vector_type(8)));
typedef short s16x4 __attribute__((ext_vector_type(4)));
typedef float f32x4 __attribute__((ext_vector_type(4)));

__device__ __forceinline__ float b2f(u16t u) {
  union { unsigned int ui; float f; } v; v.ui = ((unsigned int)u) << 16; return v.f;
}
__device__ __forceinline__ u16t f2b(float f) {
  union { float f; unsigned int ui; } v; v.f = f;
  return (u16t)((v.ui + 0x7fffu + ((v.ui >> 16) & 1u)) >> 16);
}
__device__ __forceinline__ void g2l16(void* lds, const void* g) {
  __builtin_amdgcn_global_load_lds(
      (__attribute__((address_space(1))) void*)g,
      (__attribute__((address_space(3))) void*)lds, 16, 0, 0);
}

// exact-erf GELU via Abramowitz-Stegun 7.1.26 (|erf err| < 1.5e-7).
__device__ __forceinline__ float gelu_erf(float x) {
  const float z = fabsf(x) * 0.70710678118654752f;
  const float t = __builtin_amdgcn_rcpf(__builtin_fmaf(0.3275911f, z, 1.0f));
  float p = __builtin_fmaf(1.061405429f, t, -1.453152027f);
  p = __builtin_fmaf(p, t, 1.421413741f);
  p = __builtin_fmaf(p, t, -0.284496736f);
  p = __builtin_fmaf(p, t, 0.254829592f);
  const float e = __expf(-z * z);
  const float er = __builtin_fmaf(-p * t, e, 1.0f);   // erf(|z|)
  const float s = copysignf(er, x);
  return 0.5f * x * (1.0f + s);
}

// ---------------- R10 GEMM (proven 59.8us FF1-class): 256x128, 4 waves ------
// ring-3, counted vmcnt(6), 1 barrier/K-tile.  Used for O / FF2 / patch.
// mode 0: Cb = bf16(acc+bias)        mode 1: Cb = bf16(gelu(acc+bias))
// mode 2: Cf += acc+bias (residual)  mode 3: Cf  = acc+bias
__global__ __launch_bounds__(256, 2) void k_gemm(
    const u16t* __restrict__ A, const u16t* __restrict__ Bt,
    const float* __restrict__ bias, const float* __restrict__ b2,
    const float* __restrict__ b3, float* __restrict__ Cf,
    u16t* __restrict__ Cb, int M, int N, int K, int mode)
{
  __shared__ __align__(16) u16t SH[3 * 12288];   // 72 KiB ring; epilogue reuses

  const int nbn = N >> 7;                       // N / 128
  const int cpx = gridDim.x >> 3;
  const int wgid = (blockIdx.x & 7) * cpx + (blockIdx.x >> 3);
  const int bm = (wgid / nbn) << 8;             // 256-row tile
  const int bn = (wgid % nbn) << 7;             // 128-col tile

  const int tid = threadIdx.x, wave = tid >> 6, lane = tid & 63;
  const int lr = lane & 15, quad = lane >> 4;
  const int wm = (wave >> 1) << 7;              // 0 / 128
  const int wn = (wave & 1) << 6;               // 0 / 64

  const int sseg = (lane & 3) ^ ((lane >> 3) & 3);
  const u16t* gA = A + (size_t)(bm + (lane >> 2)) * K + sseg * 8;
  const u16t* gB = Bt + (size_t)(bn + (lane >> 2)) * K + sseg * 8;

  const int sw8 = (quad ^ ((lr >> 1) & 3)) << 3;
  const int aoff = (wm + lr) * 32 + sw8;          // + i*512 per M-frag
  const int boff = 8192 + (wn + lr) * 32 + sw8;   // + j*512 per N-frag

  f32x4 acc[4][8] = {};   // [jN][iM]

  u16t* buf0 = SH;
  u16t* buf1 = SH + 12288;
  u16t* buf2 = SH + 24576;

#define STAGE_R10(BUF_, S_) do {                                               \
    g2l16((BUF_) + wave * 512,        gA + (size_t)(wave * 16) * K + (S_) * 32);   \
    g2l16((BUF_) + (wave + 4) * 512,  gA + (size_t)((wave + 4) * 16) * K + (S_) * 32); \
    g2l16((BUF_) + (wave + 8) * 512,  gA + (size_t)((wave + 8) * 16) * K + (S_) * 32); \
    g2l16((BUF_) + (wave + 12) * 512, gA + (size_t)((wave + 12) * 16) * K + (S_) * 32); \
    g2l16((BUF_) + 8192 + wave * 512, gB + (size_t)(wave * 16) * K + (S_) * 32);   \
    g2l16((BUF_) + 8192 + (wave + 4) * 512, gB + (size_t)((wave + 4) * 16) * K + (S_) * 32); \
  } while (0)

  const int nt = K >> 5;
  STAGE_R10(buf0, 0);
  STAGE_R10(buf1, 1);

  for (int t = 0; t < nt - 1; ++t) {
    asm volatile("s_waitcnt vmcnt(6)" ::: "memory");
    __builtin_amdgcn_s_barrier();
    asm volatile("" ::: "memory");
    if (t + 2 < nt) STAGE_R10(buf2, t + 2);
    bf16x8 af[8], bfr[4];
    #pragma unroll
    for (int i = 0; i < 8; ++i) af[i] = *(const bf16x8*)&buf0[aoff + i * 512];
    #pragma unroll
    for (int j = 0; j < 4; ++j) bfr[j] = *(const bf16x8*)&buf0[boff + j * 512];
    __builtin_amdgcn_s_setprio(1);
    #pragma unroll
    for (int j = 0; j < 4; ++j)
      #pragma unroll
      for (int i = 0; i < 8; ++i)
        acc[j][i] = __builtin_amdgcn_mfma_f32_16x16x32_bf16(bfr[j], af[i], acc[j][i], 0, 0, 0);
    __builtin_amdgcn_s_setprio(0);
    u16t* tmp = buf0; buf0 = buf1; buf1 = buf2; buf2 = tmp;
  }
  {
    asm volatile("s_waitcnt vmcnt(0)" ::: "memory");
    __builtin_amdgcn_s_barrier();
    asm volatile("" ::: "memory");
    bf16x8 af[8], bfr[4];
    #pragma unroll
    for (int i = 0; i < 8; ++i) af[i] = *(const bf16x8*)&buf0[aoff + i * 512];
    #pragma unroll
    for (int j = 0; j < 4; ++j) bfr[j] = *(const bf16x8*)&buf0[boff + j * 512];
    __builtin_amdgcn_s_setprio(1);
    #pragma unroll
    for (int j = 0; j < 4; ++j)
      #pragma unroll
      for (int i = 0; i < 8; ++i)
        acc[j][i] = __builtin_amdgcn_mfma_f32_16x16x32_bf16(bfr[j], af[i], acc[j][i], 0, 0, 0);
    __builtin_amdgcn_s_setprio(0);
  }
#undef STAGE_R10

  const float* bp = bias;
  int reg0 = 0;
  if (bias && b2) { reg0 = (bn >> 9) << 9; bp = reg0 == 0 ? bias : (reg0 == 512 ? b2 : b3); }
  float4 bv[4];
  #pragma unroll
  for (int jN = 0; jN < 4; ++jN) {
    const int gn0 = bn + wn + jN * 16 + quad * 4;
    bv[jN] = bias ? *(const float4*)&bp[gn0 - reg0] : make_float4(0.f, 0.f, 0.f, 0.f);
  }

  if (mode <= 1) {
    __syncthreads();
    u16t* E = SH;
    #pragma unroll
    for (int jN = 0; jN < 4; ++jN) {
      const int cl = wn + jN * 16 + quad * 4;
      const int seg = cl >> 3, intra = cl & 7;
      #pragma unroll
      for (int iM = 0; iM < 8; ++iM) {
        const int r = wm + iM * 16 + lr;
        float v0 = acc[jN][iM][0] + bv[jN].x, v1 = acc[jN][iM][1] + bv[jN].y;
        float v2 = acc[jN][iM][2] + bv[jN].z, v3 = acc[jN][iM][3] + bv[jN].w;
        union { u16t h[4]; uint2 u; } pk;
        if (mode == 1) {
          pk.h[0] = f2b(gelu_erf(v0)); pk.h[1] = f2b(gelu_erf(v1));
          pk.h[2] = f2b(gelu_erf(v2)); pk.h[3] = f2b(gelu_erf(v3));
        } else {
          pk.h[0] = f2b(v0); pk.h[1] = f2b(v1); pk.h[2] = f2b(v2); pk.h[3] = f2b(v3);
        }
        *(uint2*)&E[r * 128 + ((seg ^ (r & 7)) << 3) + intra] = pk.u;
      }
    }
    __syncthreads();
    const int rr = tid >> 2, s0 = tid & 3;
    #pragma unroll
    for (int pass = 0; pass < 4; ++pass) {
      const int r = pass * 64 + rr;
      u16t* gout = Cb + (size_t)(bm + r) * N + bn;
      #pragma unroll
      for (int it = 0; it < 4; ++it) {
        const int s = s0 + it * 4;
        uint4 u = *(const uint4*)&E[r * 128 + ((s ^ (r & 7)) << 3)];
        *(uint4*)(gout + s * 8) = u;
      }
    }
  } else {
    #pragma unroll
    for (int jN = 0; jN < 4; ++jN) {
      const int gn0 = bn + wn + jN * 16 + quad * 4;
      #pragma unroll
      for (int iM = 0; iM < 8; ++iM) {
        const int gm = bm + wm + iM * 16 + lr;
        const size_t off = (size_t)gm * N + gn0;
        float v0 = acc[jN][iM][0] + bv[jN].x, v1 = acc[jN][iM][1] + bv[jN].y;
        float v2 = acc[jN][iM][2] + bv[jN].z, v3 = acc[jN][iM][3] + bv[jN].w;
        if (mode == 2) {
          float4 c = *(float4*)(Cf + off);
          c.x += v0; c.y += v1; c.z += v2; c.w += v3;
          *(float4*)(Cf + off) = c;
        } else {
          *(float4*)(Cf + off) = make_float4(v0, v1, v2, v3);
        }
      }
    }
  }
}

// ---------------- R12: m201-template 256x256 GEMM (FF1 / QKV only) ----------
// 512 thr / 8 waves (2M x 4N), per-wave C 128x64, BK=64, 2 K-tiles per iter,
// 8 phases/iter: {ds_read 12|4, stage 1 half-tile, barrier, lgkm0+schedbar,
// setprio 16 MFMA, [vmcnt(2) at p3/p7], barrier}.  LDS 128KB = 2dbuf x 2half
// x (A,B) x 16KB.  Stage slot order WAR-safe: p0:A1(t+1) p1:B0 p2:B1
// p3:A0(t+2) p4:A1 p5:B0 p6:B1 p7:A0(t+3).  Gates: FIFO of 5 half-tiles in
// flight, vmcnt(2) => oldest 4 (= next K-tile) landed.  Tail iter: vmcnt(0).
// Output bf16 only (mode 0 = +bias, mode 1 = gelu+bias).
__global__ __launch_bounds__(512, 2) void k_gemm256(
    const u16t* __restrict__ A, const u16t* __restrict__ Bt,
    const float* __restrict__ bias, const float* __restrict__ b2,
    const float* __restrict__ b3, u16t* __restrict__ Cb,
    int M, int N, int K, int mode)
{
  __shared__ __align__(16) u16t SH[65536];   // 128 KiB: A 4x8192 | B 4x8192

  const int nbn = N >> 8;
  const int cpx = gridDim.x >> 3;
  const int wgid = (blockIdx.x & 7) * cpx + (blockIdx.x >> 3);
  const int bm = (wgid / nbn) << 8;
  const int bn = (wgid % nbn) << 8;

  const int tid = threadIdx.x, wave = tid >> 6, lane = tid & 63;
  const int lr = lane & 15, quad = lane >> 4, lr7 = lane & 7;
  const int wm = (wave >> 2) << 7;       // 0/128 (= A-half select)
  const int wn = (wave & 3) << 6;        // 0/64/128/192
  const int hA = wave >> 2;              // A half this wave reads
  const int hB = (wave >> 1) & 1;        // B half this wave reads
  const int rB0 = (wave & 1) << 6;       // row base within B half

  // staging: half-tile = 128 rows x 128B; 2 g2l16/thread (rows j*64+(tid>>3))
  const int srow = tid >> 3;                           // 0..63
  const int sdst = srow * 64 + (tid & 7) * 8;          // u16 within half-buf
  const int ssegx = ((tid & 7) ^ (srow & 7)) * 8;      // pre-swizzled src col
  const u16t* gA0 = A + (size_t)(bm + srow) * K + ssegx;
  const u16t* gB0 = Bt + (size_t)(bn + srow) * K + ssegx;

  f32x4 acc[4][8] = {};   // [jN][iM]: reg r -> N-col quad*4+r, lane lr -> M-row
  bf16x8 af_[4][2], bfr_[2][2];
  const int NT = K >> 6, NIT = NT >> 1;

#define STG(T_, H_) do { if ((T_) < NT) {                                      \
    const int dd_ = ((T_) & 1) * 2;                                            \
    u16t* dst_; const u16t* sp_;                                               \
    if ((H_) < 2) {                                                            \
      dst_ = SH + (dd_ + (H_)) * 8192 + sdst;                                  \
      sp_ = gA0 + (size_t)((H_) * 128) * K + (T_) * 64;                        \
    } else {                                                                   \
      dst_ = SH + 32768 + (dd_ + (H_) - 2) * 8192 + sdst;                      \
      sp_ = gB0 + (size_t)(((H_) - 2) * 128) * K + (T_) * 64;                  \
    }                                                                          \
    g2l16(dst_, sp_); g2l16(dst_ + 4096, sp_ + (size_t)64 * K);                \
  } } while (0)

#define GATE2 asm volatile("s_waitcnt vmcnt(2)" ::: "memory")
#define GATE0 asm volatile("s_waitcnt vmcnt(0)" ::: "memory")
#define GNONE (void)0

#define PHASE(D_, MQ_, NQ_, ST_, SHF_, GATE_) do {                             \
    if ((NQ_) == 0) {                                                          \
      _Pragma("unroll") for (int i = 0; i < 4; ++i)                            \
        _Pragma("unroll") for (int kk = 0; kk < 2; ++kk)                       \
          af_[i][kk] = *(const bf16x8*)&SH[((D_) * 2 + hA) * 8192 +            \
              (((MQ_) * 4 + i) * 16 + lr) * 64 + (((kk * 4 + quad) ^ lr7) << 3)]; \
    }                                                                          \
    _Pragma("unroll") for (int j = 0; j < 2; ++j)                              \
      _Pragma("unroll") for (int kk = 0; kk < 2; ++kk)                         \
        bfr_[j][kk] = *(const bf16x8*)&SH[32768 + ((D_) * 2 + hB) * 8192 +     \
            (rB0 + ((NQ_) * 2 + j) * 16 + lr) * 64 + (((kk * 4 + quad) ^ lr7) << 3)]; \
    STG(ST_, SHF_);                                                            \
    if ((NQ_) == 0) asm volatile("s_waitcnt lgkmcnt(8)" ::: "memory");         \
    __builtin_amdgcn_s_barrier();                                              \
    asm volatile("s_waitcnt lgkmcnt(0)" ::: "memory");                         \
    __builtin_amdgcn_sched_barrier(0);                                         \
    __builtin_amdgcn_s_setprio(1);                                             \
    _Pragma("unroll") for (int j = 0; j < 2; ++j)                              \
      _Pragma("unroll") for (int i = 0; i < 4; ++i)                            \
        _Pragma("unroll") for (int kk = 0; kk < 2; ++kk)                       \
          acc[(NQ_) * 2 + j][(MQ_) * 4 + i] = __builtin_amdgcn_mfma_f32_16x16x32_bf16( \
              bfr_[j][kk], af_[i][kk], acc[(NQ_) * 2 + j][(MQ_) * 4 + i], 0, 0, 0); \
    __builtin_amdgcn_s_setprio(0);                                             \
    GATE_;                                                                     \
    __builtin_amdgcn_s_barrier();                                              \
  } while (0)

  // prologue: K-tile 0 (A0,A1,B0,B1) + A0(1); gate K-tile 0 landed
  STG(0, 0); STG(0, 1); STG(0, 2); STG(0, 3); STG(1, 0);
  GATE2;
  __builtin_amdgcn_s_barrier();

  for (int i = 0; i < NIT - 1; ++i) {
    const int tb = 2 * i;
    PHASE(0, 0, 0, tb + 1, 1, GNONE);
    PHASE(0, 0, 1, tb + 1, 2, GNONE);
    PHASE(0, 1, 0, tb + 1, 3, GNONE);
    PHASE(0, 1, 1, tb + 2, 0, GATE2);
    PHASE(1, 0, 0, tb + 2, 1, GNONE);
    PHASE(1, 0, 1, tb + 2, 2, GNONE);
    PHASE(1, 1, 0, tb + 2, 3, GNONE);
    PHASE(1, 1, 1, tb + 3, 0, GATE2);
  }
  {  // tail iteration: OOB stages skipped by guard; full drain at gates
    const int tb = 2 * (NIT - 1);
    PHASE(0, 0, 0, tb + 1, 1, GNONE);
    PHASE(0, 0, 1, tb + 1, 2, GNONE);
    PHASE(0, 1, 0, tb + 1, 3, GNONE);
    PHASE(0, 1, 1, tb + 2, 0, GATE0);
    PHASE(1, 0, 0, tb + 2, 1, GNONE);
    PHASE(1, 0, 1, tb + 2, 2, GNONE);
    PHASE(1, 1, 0, tb + 2, 3, GNONE);
    PHASE(1, 1, 1, tb + 3, 0, GATE0);
  }
#undef PHASE
#undef STG

  // bias (fused-QKV select; bn is 256-aligned, always within one 512-group)
  const float* bp = bias;
  int reg0 = 0;
  if (bias && b2) { reg0 = (bn >> 9) << 9; bp = reg0 == 0 ? bias : (reg0 == 512 ? b2 : b3); }
  float4 bv[4];
  #pragma unroll
  for (int jN = 0; jN < 4; ++jN) {
    const int gn0 = bn + wn + jN * 16 + quad * 4;
    bv[jN] = bias ? *(const float4*)&bp[gn0 - reg0] : make_float4(0.f, 0.f, 0.f, 0.f);
  }

  // epilogue: LDS transpose (E = [256][256] u16, seg-swizzled) + full-sector
  u16t* E = SH;
  #pragma unroll
  for (int jN = 0; jN < 4; ++jN) {
    const int cl = wn + jN * 16 + quad * 4;
    const int seg = cl >> 3, intra = cl & 7;
    #pragma unroll
    for (int iM = 0; iM < 8; ++iM) {
      const int r = wm + iM * 16 + lr;
      float v0 = acc[jN][iM][0] + bv[jN].x, v1 = acc[jN][iM][1] + bv[jN].y;
      float v2 = acc[jN][iM][2] + bv[jN].z, v3 = acc[jN][iM][3] + bv[jN].w;
      union { u16t h[4]; uint2 u; } pk;
      if (mode == 1) {
        pk.h[0] = f2b(gelu_erf(v0)); pk.h[1] = f2b(gelu_erf(v1));
        pk.h[2] = f2b(gelu_erf(v2)); pk.h[3] = f2b(gelu_erf(v3));
      } else {
        pk.h[0] = f2b(v0); pk.h[1] = f2b(v1); pk.h[2] = f2b(v2); pk.h[3] = f2b(v3);
      }
      *(uint2*)&E[r * 256 + ((seg ^ (r & 7)) << 3) + intra] = pk.u;
    }
  }
  __syncthreads();
  // readout: 4 consecutive lanes -> one 64B sector; 32 threads/row, 16 rows/pass
  const int rr = tid >> 5, t32 = tid & 31;
  const int seg16 = t32;     // (t32>>2)*4 + (t32&3) == t32: 16B units 0..31
  #pragma unroll
  for (int pass = 0; pass < 16; ++pass) {
    const int r = pass * 16 + rr;
    uint4 u = *(const uint4*)&E[r * 256 + ((seg16 ^ (r & 7)) << 3)];
    *(uint4*)(Cb + (size_t)(bm + r) * N + bn + seg16 * 8) = u;
  }
}

// ---------------- weight prep: Wt[orow0+n][k] = bf16(W[k][n] (+ 2*down@up)) -
__global__ __launch_bounds__(256) void k_prep_w(
    const float* __restrict__ W, const float* __restrict__ down,
    const float* __restrict__ up, u16t* __restrict__ Wt, int K, int N,
    size_t ostride, int orow0)
{
  __shared__ float t[32][33];
  const int z = blockIdx.z;
  const float* Wz = W + (size_t)z * K * N;
  u16t* Wtz = Wt + (size_t)z * ostride + (size_t)orow0 * K;
  const int k0 = blockIdx.x * 32, n0 = blockIdx.y * 32;
  const int tx = threadIdx.x & 31, ty = threadIdx.x >> 5;
  for (int i = ty; i < 32; i += 8) {
    const int kk = k0 + i, nn = n0 + tx;
    float v = Wz[(size_t)kk * N + nn];
    if (down) {
      const float* dz = down + (size_t)z * K * 8 + (size_t)kk * 8;
      const float* uz = up + (size_t)z * 8 * N + nn;
      float lv = 0.f;
      #pragma unroll
      for (int r = 0; r < 8; ++r) lv += dz[r] * uz[(size_t)r * N];
      v += 2.0f * lv;   // LORA_SCALING
    }
    t[i][tx] = v;
  }
  __syncthreads();
  for (int i = ty; i < 32; i += 8)
    Wtz[(size_t)(n0 + i) * K + k0 + tx] = f2b(t[tx][i]);
}

// ---------------- patch gather: pt[(b*256+np)*128 + f*16+p] = x[b, np*16+p, f]
__global__ void k_patch(const float* __restrict__ x, u16t* __restrict__ pt) {
  const int idx = blockIdx.x * 256 + threadIdx.x;
  const int col = idx & 127, row = idx >> 7;
  const int f = col >> 4, pp = col & 15;
  const int b = row >> 8, np = row & 255;
  pt[idx] = f2b(x[(((size_t)b << 12) + np * 16 + pp) * 8 + f]);
}

// ---------------- LayerNorm (one wave per 512-row) -> bf16 ----------------
__global__ __launch_bounds__(256) void k_ln(
    const float* __restrict__ xin, const float* __restrict__ w,
    const float* __restrict__ bb, u16t* __restrict__ y)
{
  const int row = blockIdx.x * 4 + (threadIdx.x >> 6);
  const int lane = threadIdx.x & 63;
  const float4* xr = (const float4*)(xin + (size_t)row * 512);
  float4 a = xr[lane * 2], c = xr[lane * 2 + 1];
  float s = a.x + a.y + a.z + a.w + c.x + c.y + c.z + c.w;
  float qq = a.x * a.x + a.y * a.y + a.z * a.z + a.w * a.w +
             c.x * c.x + c.y * c.y + c.z * c.z + c.w * c.w;
  #pragma unroll
  for (int o = 32; o > 0; o >>= 1) { s += __shfl_xor(s, o); qq += __shfl_xor(qq, o); }
  const float mean = s * (1.f / 512.f);
  const float rs = rsqrtf(qq * (1.f / 512.f) - mean * mean + 1e-5f);
  const float4* wr = (const float4*)w; const float4* br = (const float4*)bb;
  float4 w0 = wr[lane * 2], w1 = wr[lane * 2 + 1];
  float4 b0 = br[lane * 2], b1 = br[lane * 2 + 1];
  union { u16t h[8]; uint4 v; } pk;
  pk.h[0] = f2b((a.x - mean) * rs * w0.x + b0.x);
  pk.h[1] = f2b((a.y - mean) * rs * w0.y + b0.y);
  pk.h[2] = f2b((a.z - mean) * rs * w0.z + b0.z);
  pk.h[3] = f2b((a.w - mean) * rs * w0.w + b0.w);
  pk.h[4] = f2b((c.x - mean) * rs * w1.x + b1.x);
  pk.h[5] = f2b((c.y - mean) * rs * w1.y + b1.y);
  pk.h[6] = f2b((c.z - mean) * rs * w1.z + b1.z);
  pk.h[7] = f2b((c.w - mean) * rs * w1.w + b1.w);
  *(uint4*)(y + (size_t)row * 512 + lane * 8) = pk.v;
}

// ---------------- patch LN + pos_enc -> h (fp32) ----------------
__global__ __launch_bounds__(256) void k_ln_pos(
    const float* __restrict__ xin, const float* __restrict__ w,
    const float* __restrict__ bb, const float* __restrict__ pos,
    float* __restrict__ h)
{
  const int row = blockIdx.x * 4 + (threadIdx.x >> 6);
  const int lane = threadIdx.x & 63;
  const float4* xr = (const float4*)(xin + (size_t)row * 512);
  float4 a = xr[lane * 2], c = xr[lane * 2 + 1];
  float s = a.x + a.y + a.z + a.w + c.x + c.y + c.z + c.w;
  float qq = a.x * a.x + a.y * a.y + a.z * a.z + a.w * a.w +
             c.x * c.x + c.y * c.y + c.z * c.z + c.w * c.w;
  #pragma unroll
  for (int o = 32; o > 0; o >>= 1) { s += __shfl_xor(s, o); qq += __shfl_xor(qq, o); }
  const float mean = s * (1.f / 512.f);
  const float rs = rsqrtf(qq * (1.f / 512.f) - mean * mean + 1e-5f);
  const float4* wr = (const float4*)w; const float4* br = (const float4*)bb;
  float4 w0 = wr[lane * 2], w1 = wr[lane * 2 + 1];
  float4 b0 = br[lane * 2], b1 = br[lane * 2 + 1];
  const int np = row & 255;
  const float4* pr = (const float4*)(pos + (size_t)np * 512);
  float4 p0 = pr[lane * 2], p1 = pr[lane * 2 + 1];
  float4 o0, o1;
  o0.x = (a.x - mean) * rs * w0.x + b0.x + p0.x;
  o0.y = (a.y - mean) * rs * w0.y + b0.y + p0.y;
  o0.z = (a.z - mean) * rs * w0.z + b0.z + p0.z;
  o0.w = (a.w - mean) * rs * w0.w + b0.w + p0.w;
  o1.x = (c.x - mean) * rs * w1.x + b1.x + p1.x;
  o1.y = (c.y - mean) * rs * w1.y + b1.y + p1.y;
  o1.z = (c.z - mean) * rs * w1.z + b1.z + p1.z;
  o1.w = (c.w - mean) * rs * w1.w + b1.w + p1.w;
  float4* hr = (float4*)(h + (size_t)row * 512);
  hr[lane * 2] = o0; hr[lane * 2 + 1] = o1;
}

// ---------------- MFMA flash attention -------------------------------------
__global__ __launch_bounds__(256) void k_attn(
    const u16t* __restrict__ qkv, u16t* __restrict__ out)
{
  __shared__ __align__(16) u16t Qs[128 * LDSP];
  __shared__ __align__(16) u16t Ks[64 * LDSP];
  __shared__ __align__(16) u16t Vts[64 * LDSP];

  const int bh = blockIdx.x >> 1, half = blockIdx.x & 1;
  const int b = bh >> 3, hd = bh & 7;
  const int tid = threadIdx.x, wave = tid >> 6, lane = tid & 63;
  const int lr = lane & 15, quad = lane >> 4;

  const size_t rowbase = (size_t)b * 256;
  const u16t* qg = qkv + (rowbase + half * 128) * 1536 + hd * 64;
  const u16t* kg = qkv + rowbase * 1536 + 512 + hd * 64;
  const u16t* vg = qkv + rowbase * 1536 + 1024 + hd * 64;

  #pragma unroll
  for (int i = 0; i < 4; ++i) {
    const int idx = tid + i * 256, row = idx >> 3, seg = idx & 7;
    uint4 u = *(const uint4*)(qg + (size_t)row * 1536 + seg * 8);
    *(uint4*)&Qs[row * LDSP + seg * 8] = u;
  }
  __syncthreads();

  bf16x8 qf[2][2];
  #pragma unroll
  for (int qi = 0; qi < 2; ++qi)
    #pragma unroll
    for (int dh = 0; dh < 2; ++dh)
      qf[qi][dh] = *(const bf16x8*)&Qs[(wave * 32 + qi * 16 + lr) * LDSP + dh * 32 + quad * 8];

  f32x4 O[2][4] = {};
  float mrun[2] = {-1e30f, -1e30f}, lrun[2] = {0.f, 0.f};

  for (int c = 0; c < 4; ++c) {
    __syncthreads();
    #pragma unroll
    for (int i = 0; i < 2; ++i) {
      const int idx = tid + i * 256, row = idx >> 3, seg = idx & 7;
      uint4 u = *(const uint4*)(kg + (size_t)(c * 64 + row) * 1536 + seg * 8);
      *(uint4*)&Ks[row * LDSP + seg * 8] = u;
    }
    {
      const int key = tid & 63, dg = (tid >> 6) * 16;
      const u16t* vrow = vg + (size_t)(c * 64 + key) * 1536 + dg;
      union { u16t h[16]; uint4 v[2]; } tmp;
      tmp.v[0] = *(const uint4*)(vrow);
      tmp.v[1] = *(const uint4*)(vrow + 8);
      #pragma unroll
      for (int i = 0; i < 16; ++i)
        Vts[(dg + i) * LDSP + key] = tmp.h[i];
    }
    __syncthreads();

    #pragma unroll
    for (int qi = 0; qi < 2; ++qi) {
      f32x4 s[4];
      #pragma unroll
      for (int kt = 0; kt < 4; ++kt) {
        f32x4 a = {};
        #pragma unroll
        for (int dh = 0; dh < 2; ++dh) {
          bf16x8 kf = *(const bf16x8*)&Ks[(kt * 16 + lr) * LDSP + dh * 32 + quad * 8];
          a = __builtin_amdgcn_mfma_f32_16x16x32_bf16(kf, qf[qi][dh], a, 0, 0, 0);
        }
        s[kt] = a;
      }
      constexpr float SC = 0.125f * 1.44269504088896f;
      float cmax = -1e30f;
      #pragma unroll
      for (int kt = 0; kt < 4; ++kt)
        #pragma unroll
        for (int r = 0; r < 4; ++r) { s[kt][r] *= SC; cmax = fmaxf(cmax, s[kt][r]); }
      cmax = fmaxf(cmax, __shfl_xor(cmax, 16));
      cmax = fmaxf(cmax, __shfl_xor(cmax, 32));
      const float mn = fmaxf(mrun[qi], cmax);
      const float alpha = exp2f(mrun[qi] - mn);
      mrun[qi] = mn;
      float lsum = 0.f;
      s16x4 pf[4];
      #pragma unroll
      for (int kt = 0; kt < 4; ++kt) {
        #pragma unroll
        for (int r = 0; r < 4; ++r) {
          const u16t eb = f2b(exp2f(s[kt][r] - mn));
          pf[kt][r] = (short)eb;
          lsum += b2f(eb);
        }
      }
      lsum += __shfl_xor(lsum, 16);
      lsum += __shfl_xor(lsum, 32);
      lrun[qi] = lrun[qi] * alpha + lsum;
      #pragma unroll
      for (int dt = 0; dt < 4; ++dt) {
        f32x4 o = O[qi][dt];
        o[0] *= alpha; o[1] *= alpha; o[2] *= alpha; o[3] *= alpha;
        #pragma unroll
        for (int kt = 0; kt < 4; ++kt) {
          s16x4 vf = *(const s16x4*)&Vts[(dt * 16 + lr) * LDSP + kt * 16 + quad * 4];
          o = __builtin_amdgcn_mfma_f32_16x16x16bf16_1k(vf, pf[kt], o, 0, 0, 0);
        }
        O[qi][dt] = o;
      }
    }
  }
  #pragma unroll
  for (int qi = 0; qi < 2; ++qi) {
    const float rl = 1.f / lrun[qi];
    u16t* orow = out + (rowbase + half * 128 + wave * 32 + qi * 16 + lr) * 512 + hd * 64 + quad * 4;
    #pragma unroll
    for (int dt = 0; dt < 4; ++dt) {
      union { u16t h[4]; uint2 v; } pk;
      #pragma unroll
      for (int r = 0; r < 4; ++r) pk.h[r] = f2b(O[qi][dt][r] * rl);
      *(uint2*)(orow + dt * 16) = pk.v;
    }
  }
}

// ---------------- final mean over patches ----------------
__global__ void k_mean(const u16t* __restrict__ y, float* __restrict__ out) {
  const int b = blockIdx.x, d = threadIdx.x;   // 64 x 512
  float s = 0.f;
  #pragma unroll 8
  for (int np = 0; np < 256; ++np) s += b2f(y[((size_t)b * 256 + np) * 512 + d]);
  out[(size_t)b * 512 + d] = s * (1.f / 256.f);
}

// ---------------- host ----------------
extern "C" void kernel_launch(void* const* d_in, const int* in_sizes, int n_in,
                              void* d_out, int out_size, void* d_ws, size_t ws_size,
                              hipStream_t stream)
{
  (void)in_sizes; (void)n_in; (void)out_size;
  const float* x        = (const float*)d_in[0];
  const float* patch_w  = (const float*)d_in[1];
  const float* patch_b  = (const float*)d_in[2];
  const float* patch_ln_w = (const float*)d_in[3];
  const float* patch_ln_b = (const float*)d_in[4];
  const float* pos_enc  = (const float*)d_in[5];
  const float* ln1_w    = (const float*)d_in[6];
  const float* ln1_b    = (const float*)d_in[7];
  const float* q_w      = (const float*)d_in[8];
  const float* q_b      = (const float*)d_in[9];
  const float* k_w      = (const float*)d_in[10];
  const float* k_b      = (const float*)d_in[11];
  const float* v_w      = (const float*)d_in[12];
  const float* v_b      = (const float*)d_in[13];
  const float* lq_down  = (const float*)d_in[14];
  const float* lq_up    = (const float*)d_in[15];
  const float* lk_down  = (const float*)d_in[16];
  const float* lk_up    = (const float*)d_in[17];
  const float* lv_down  = (const float*)d_in[18];
  const float* lv_up    = (const float*)d_in[19];
  const float* o_w      = (const float*)d_in[20];
  const float* o_b      = (const float*)d_in[21];
  const float* ln2_w    = (const float*)d_in[22];
  const float* ln2_b    = (const float*)d_in[23];
  const float* ff1_w    = (const float*)d_in[24];
  const float* ff1_b    = (const float*)d_in[25];
  const float* ff2_w    = (const float*)d_in[26];
  const float* ff2_b    = (const float*)d_in[27];
  const float* norm_w   = (const float*)d_in[28];
  const float* norm_b   = (const float*)d_in[29];
  float* out = (float*)d_out;

  // workspace carve (~148.1 MiB)
  char* p = (char*)d_ws;
  float* h  = (float*)p;  p += (size_t)MROWS * 512 * 4;       // 32 MB
  u16t*  y  = (u16t*)p;   p += (size_t)MROWS * 512 * 2;       // 16 MB
  char* uni = p;          p += (size_t)4 * MROWS * 512 * 2;   // 64 MB union
  u16t* qkvb = (u16t*)uni;                                    // [M,1536] (48 MB)
  u16t* ab = (u16t*)(uni + (size_t)MROWS * 1536 * 2);         // [M,512]  (16 MB)
  u16t* g  = (u16t*)uni;                                      // [M,2048] aliases qkv+ab
  float* pe = (float*)uni;                                    // [M,512] fp32 (pre-LN patch)
  u16t* pt = (u16t*)(uni + (size_t)MROWS * 512 * 4);          // [M,128] after pe
  u16t* wqkv = (u16t*)p; p += (size_t)NLAYER * 1536 * 512 * 2;
  u16t* wo = (u16t*)p; p += (size_t)NLAYER * 512 * 512 * 2;
  u16t* w1 = (u16t*)p; p += (size_t)NLAYER * 512 * 2048 * 2;
  u16t* w2 = (u16t*)p; p += (size_t)NLAYER * 2048 * 512 * 2;
  u16t* wp = (u16t*)p; p += (size_t)512 * 128 * 2;
  if ((size_t)(p - (char*)d_ws) > ws_size) return;

  const dim3 blk(256);
  const dim3 gblk(512);
  const size_t QKVS = (size_t)1536 * 512;
  k_prep_w<<<dim3(16, 16, NLAYER), blk, 0, stream>>>(q_w, lq_down, lq_up, wqkv, 512, 512, QKVS, 0);
  k_prep_w<<<dim3(16, 16, NLAYER), blk, 0, stream>>>(k_w, lk_down, lk_up, wqkv, 512, 512, QKVS, 512);
  k_prep_w<<<dim3(16, 16, NLAYER), blk, 0, stream>>>(v_w, lv_down, lv_up, wqkv, 512, 512, QKVS, 1024);
  k_prep_w<<<dim3(16, 16, NLAYER), blk, 0, stream>>>(o_w, nullptr, nullptr, wo, 512, 512, (size_t)512 * 512, 0);
  k_prep_w<<<dim3(16, 64, NLAYER), blk, 0, stream>>>(ff1_w, nullptr, nullptr, w1, 512, 2048, (size_t)512 * 2048, 0);
  k_prep_w<<<dim3(64, 16, NLAYER), blk, 0, stream>>>(ff2_w, nullptr, nullptr, w2, 2048, 512, (size_t)2048 * 512, 0);
  k_prep_w<<<dim3(4, 16, 1),       blk, 0, stream>>>(patch_w, nullptr, nullptr, wp, 128, 512, 0, 0);

  k_patch<<<dim3(MROWS * 128 / 256), blk, 0, stream>>>(x, pt);
  k_gemm<<<dim3(64 * 4), blk, 0, stream>>>(pt, wp, patch_b, nullptr, nullptr, pe, nullptr, MROWS, 512, 128, 3);
  k_ln_pos<<<dim3(MROWS / 4), blk, 0, stream>>>(pe, patch_ln_w, patch_ln_b, pos_enc, h);

  for (int i = 0; i < NLAYER; ++i) {
    const size_t ws512 = (size_t)i * 512 * 512, wsff = (size_t)i * 512 * 2048;
    k_ln<<<dim3(MROWS / 4), blk, 0, stream>>>(h, ln1_w + i * 512, ln1_b + i * 512, y);
    k_gemm256<<<dim3(64 * 6), gblk, 0, stream>>>(y, wqkv + i * QKVS, q_b + i * 512, k_b + i * 512,
                                                 v_b + i * 512, qkvb, MROWS, 1536, 512, 0);
    k_attn<<<dim3(1024), blk, 0, stream>>>(qkvb, ab);
    k_gemm<<<dim3(64 * 4), blk, 0, stream>>>(ab, wo + ws512, o_b + i * 512, nullptr, nullptr, h, nullptr, MROWS, 512, 512, 2);
    k_ln<<<dim3(MROWS / 4), blk, 0, stream>>>(h, ln2_w + i * 512, ln2_b + i * 512, y);
    k_gemm256<<<dim3(64 * 8), gblk, 0, stream>>>(y, w1 + wsff, ff1_b + i * 2048, nullptr, nullptr,
                                                 g, MROWS, 2048, 512, 1);
    k_gemm<<<dim3(64 * 4), blk, 0, stream>>>(g, w2 + wsff, ff2_b + i * 512, nullptr, nullptr, h, nullptr, MROWS, 512, 2048, 2);
  }
  k_ln<<<dim3(MROWS / 4), blk, 0, stream>>>(h, norm_w, norm_b, y);
  k_mean<<<dim3(BATCH), dim3(512), 0, stream>>>(y, out);
}

// Round 4
// 1481.605 us; speedup vs baseline: 1.1040x; 1.0802x over previous
//
#include <hip/hip_runtime.h>
#include <cstdint>
#include <cstddef>

// ---------------- constants ----------------
constexpr int BATCH = 64, SEQ = 4096, FEAT = 8, PLEN = 16;
constexpr int DMODEL = 512, NHEAD = 8, NLAYER = 6, DFF = 2048;
constexpr int NPATCH = 256, MROWS = BATCH * NPATCH;   // 16384
constexpr int DK = 64;
constexpr int LDSP = 72;   // padded LDS row stride (u16) for attn tiles

typedef unsigned short u16t;
typedef __bf16 bf16t;
typedef bf16t bf16x8 __attribute__((ext_vector_type(8)));
typedef short s16x4 __attribute__((ext_vector_type(4)));
typedef float f32x4 __attribute__((ext_vector_type(4)));

__device__ __forceinline__ float b2f(u16t u) {
  union { unsigned int ui; float f; } v; v.ui = ((unsigned int)u) << 16; return v.f;
}
__device__ __forceinline__ u16t f2b(float f) {
  union { float f; unsigned int ui; } v; v.f = f;
  return (u16t)((v.ui + 0x7fffu + ((v.ui >> 16) & 1u)) >> 16);
}
__device__ __forceinline__ void g2l16(void* lds, const void* g) {
  __builtin_amdgcn_global_load_lds(
      (__attribute__((address_space(1))) void*)g,
      (__attribute__((address_space(3))) void*)lds, 16, 0, 0);
}

// exact-erf GELU via Abramowitz-Stegun 7.1.26 (|erf err| < 1.5e-7).
__device__ __forceinline__ float gelu_erf(float x) {
  const float z = fabsf(x) * 0.70710678118654752f;
  const float t = __builtin_amdgcn_rcpf(__builtin_fmaf(0.3275911f, z, 1.0f));
  float p = __builtin_fmaf(1.061405429f, t, -1.453152027f);
  p = __builtin_fmaf(p, t, 1.421413741f);
  p = __builtin_fmaf(p, t, -0.284496736f);
  p = __builtin_fmaf(p, t, 0.254829592f);
  const float e = __expf(-z * z);
  const float er = __builtin_fmaf(-p * t, e, 1.0f);   // erf(|z|)
  const float s = copysignf(er, x);
  return 0.5f * x * (1.0f + s);
}

// ---------------- R13 GEMM: 128x128 tile (m103-verified 912-TF geometry) ----
// C[M,N] = A[M,K] @ Bt[N,K]^T (+epilogue).  4 waves / 256 thr, per-wave 64x64
// (acc[4][4] = 64 AGPR), BK=32, ring-3 LDS (3 x 16KB = 48KB -> 3 blocks/CU,
// 12 waves/CU = 3/SIMD).  R10-proven schedule: stage tile t+2 at top of iter
// t; ONE barrier per K-tile gated by counted s_waitcnt vmcnt(4) (per-wave: 4
// staging instr/tile; the 4 outstanding are always the NEXT tile's).  Peeled
// final tile drains vmcnt(0).  Tail verified for nt = 4 / 16 / 64.
// Staging: global_load_lds w=16, linear LDS dest, XOR-pre-swizzled global
// source (seg^((row>>1)&3)); ds_read_b128 fragments use the same XOR =>
// conflict-free (R10 PMC: bank-conflict at b128 baseline only).
// Epilogues: R7/R9-proven full-sector patterns (bf16 via 32KB LDS transpose).
// mode 0: Cb = bf16(acc+bias)        mode 1: Cb = bf16(gelu(acc+bias))
// mode 2: Cf += acc+bias (residual)  mode 3: Cf  = acc+bias
__global__ __launch_bounds__(256, 3) void k_gemm(
    const u16t* __restrict__ A, const u16t* __restrict__ Bt,
    const float* __restrict__ bias, const float* __restrict__ b2,
    const float* __restrict__ b3, float* __restrict__ Cf,
    u16t* __restrict__ Cb, int M, int N, int K, int mode)
{
  __shared__ __align__(16) u16t SH[3 * 8192];   // 48 KiB ring; epilogue reuses

  // ---- XCD-aware bijective swizzle (1-D grid, nwg % 8 == 0 for all shapes)
  const int nbn = N >> 7;                       // N / 128
  const int cpx = gridDim.x >> 3;
  const int wgid = (blockIdx.x & 7) * cpx + (blockIdx.x >> 3);
  const int bm = (wgid / nbn) << 7;             // 128-row tile
  const int bn = (wgid % nbn) << 7;             // 128-col tile

  const int tid = threadIdx.x, wave = tid >> 6, lane = tid & 63;
  const int lr = lane & 15, quad = lane >> 4;
  const int wm = (wave >> 1) << 6;              // 0 / 64
  const int wn = (wave & 1) << 6;               // 0 / 64

  // staging source: chunk = 16 rows x 64B; lane l -> row chunk*16 + (l>>2),
  // phys seg l&3, pre-swizzled logical seg (l&3)^((l>>3)&3) = (l&3)^((row>>1)&3)
  const int sseg = (lane & 3) ^ ((lane >> 3) & 3);
  const u16t* gA = A + (size_t)(bm + (lane >> 2)) * K + sseg * 8;
  const u16t* gB = Bt + (size_t)(bn + (lane >> 2)) * K + sseg * 8;

  // fragment ds_read offsets (u16 units within one 8192-u16 ring slot)
  const int sw8 = (quad ^ ((lr >> 1) & 3)) << 3;
  const int aoff = (wm + lr) * 32 + sw8;          // + i*512 per M-frag (16 rows)
  const int boff = 4096 + (wn + lr) * 32 + sw8;   // + j*512 per N-frag

  f32x4 acc[4][4] = {};   // [jN][iM]: reg r -> N-col quad*4+r, lane lr -> M-row

  u16t* buf0 = SH;
  u16t* buf1 = SH + 8192;
  u16t* buf2 = SH + 16384;

  // one K-tile stage: 4 instr/wave (A: 8 chunks, B: 8 chunks over 4 waves)
#define STAGE(BUF_, S_) do {                                                   \
    g2l16((BUF_) + wave * 512,        gA + (size_t)(wave * 16) * K + (S_) * 32);   \
    g2l16((BUF_) + (wave + 4) * 512,  gA + (size_t)((wave + 4) * 16) * K + (S_) * 32); \
    g2l16((BUF_) + 4096 + wave * 512, gB + (size_t)(wave * 16) * K + (S_) * 32);   \
    g2l16((BUF_) + 4096 + (wave + 4) * 512, gB + (size_t)((wave + 4) * 16) * K + (S_) * 32); \
  } while (0)

  const int nt = K >> 5;
  STAGE(buf0, 0);
  STAGE(buf1, 1);

  for (int t = 0; t < nt - 1; ++t) {
    // own-tile gate: 4 outstanding = tile t+1's; tile t landed for this wave.
    // barrier then makes it landed for ALL waves.
    asm volatile("s_waitcnt vmcnt(4)" ::: "memory");
    __builtin_amdgcn_s_barrier();
    asm volatile("" ::: "memory");
    if (t + 2 < nt) STAGE(buf2, t + 2);   // buf2 free: last read ended iter t-1
    bf16x8 af[4], bfr[4];
    #pragma unroll
    for (int i = 0; i < 4; ++i) af[i] = *(const bf16x8*)&buf0[aoff + i * 512];
    #pragma unroll
    for (int j = 0; j < 4; ++j) bfr[j] = *(const bf16x8*)&buf0[boff + j * 512];
    __builtin_amdgcn_s_setprio(1);
    #pragma unroll
    for (int j = 0; j < 4; ++j)
      #pragma unroll
      for (int i = 0; i < 4; ++i)
        acc[j][i] = __builtin_amdgcn_mfma_f32_16x16x32_bf16(bfr[j], af[i], acc[j][i], 0, 0, 0);
    __builtin_amdgcn_s_setprio(0);
    u16t* tmp = buf0; buf0 = buf1; buf1 = buf2; buf2 = tmp;
  }
  {  // peeled final tile: full drain (once per kernel)
    asm volatile("s_waitcnt vmcnt(0)" ::: "memory");
    __builtin_amdgcn_s_barrier();
    asm volatile("" ::: "memory");
    bf16x8 af[4], bfr[4];
    #pragma unroll
    for (int i = 0; i < 4; ++i) af[i] = *(const bf16x8*)&buf0[aoff + i * 512];
    #pragma unroll
    for (int j = 0; j < 4; ++j) bfr[j] = *(const bf16x8*)&buf0[boff + j * 512];
    __builtin_amdgcn_s_setprio(1);
    #pragma unroll
    for (int j = 0; j < 4; ++j)
      #pragma unroll
      for (int i = 0; i < 4; ++i)
        acc[j][i] = __builtin_amdgcn_mfma_f32_16x16x32_bf16(bfr[j], af[i], acc[j][i], 0, 0, 0);
    __builtin_amdgcn_s_setprio(0);
  }
#undef STAGE

  // block-uniform bias base (fused-QKV select; bn 128-aligned)
  const float* bp = bias;
  int reg0 = 0;
  if (bias && b2) { reg0 = (bn >> 9) << 9; bp = reg0 == 0 ? bias : (reg0 == 512 ? b2 : b3); }
  float4 bv[4];
  #pragma unroll
  for (int jN = 0; jN < 4; ++jN) {
    const int gn0 = bn + wn + jN * 16 + quad * 4;
    bv[jN] = bias ? *(const float4*)&bp[gn0 - reg0] : make_float4(0.f, 0.f, 0.f, 0.f);
  }

  if (mode <= 1) {
    __syncthreads();   // all waves done with ring before reuse as E
    // deposit: 4 waves, disjoint (wm, wn) 64x64 quadrants of the 128x128 tile
    u16t* E = SH;      // [128][128] u16 (32KB), seg-swizzled (R8/R9 pattern)
    #pragma unroll
    for (int jN = 0; jN < 4; ++jN) {
      const int cl = wn + jN * 16 + quad * 4;
      const int seg = cl >> 3, intra = cl & 7;
      #pragma unroll
      for (int iM = 0; iM < 4; ++iM) {
        const int r = wm + iM * 16 + lr;
        float v0 = acc[jN][iM][0] + bv[jN].x, v1 = acc[jN][iM][1] + bv[jN].y;
        float v2 = acc[jN][iM][2] + bv[jN].z, v3 = acc[jN][iM][3] + bv[jN].w;
        union { u16t h[4]; uint2 u; } pk;
        if (mode == 1) {
          pk.h[0] = f2b(gelu_erf(v0)); pk.h[1] = f2b(gelu_erf(v1));
          pk.h[2] = f2b(gelu_erf(v2)); pk.h[3] = f2b(gelu_erf(v3));
        } else {
          pk.h[0] = f2b(v0); pk.h[1] = f2b(v1); pk.h[2] = f2b(v2); pk.h[3] = f2b(v3);
        }
        *(uint2*)&E[r * 128 + ((seg ^ (r & 7)) << 3) + intra] = pk.u;
      }
    }
    __syncthreads();
    // readout: per instruction, 4 consecutive lanes -> one full 64B sector of
    // one row (R7-verified); 2 passes x 64 rows cover 128 rows.
    const int rr = tid >> 2, s0 = tid & 3;
    #pragma unroll
    for (int pass = 0; pass < 2; ++pass) {
      const int r = pass * 64 + rr;
      u16t* gout = Cb + (size_t)(bm + r) * N + bn;
      #pragma unroll
      for (int it = 0; it < 4; ++it) {
        const int s = s0 + it * 4;
        uint4 u = *(const uint4*)&E[r * 128 + ((s ^ (r & 7)) << 3)];
        *(uint4*)(gout + s * 8) = u;
      }
    }
  } else {
    // fp32: direct (full-sector: 4 quads x 16B = 64B per row per instr)
    #pragma unroll
    for (int jN = 0; jN < 4; ++jN) {
      const int gn0 = bn + wn + jN * 16 + quad * 4;
      #pragma unroll
      for (int iM = 0; iM < 4; ++iM) {
        const int gm = bm + wm + iM * 16 + lr;
        const size_t off = (size_t)gm * N + gn0;
        float v0 = acc[jN][iM][0] + bv[jN].x, v1 = acc[jN][iM][1] + bv[jN].y;
        float v2 = acc[jN][iM][2] + bv[jN].z, v3 = acc[jN][iM][3] + bv[jN].w;
        if (mode == 2) {
          float4 c = *(float4*)(Cf + off);
          c.x += v0; c.y += v1; c.z += v2; c.w += v3;
          *(float4*)(Cf + off) = c;
        } else {
          *(float4*)(Cf + off) = make_float4(v0, v1, v2, v3);
        }
      }
    }
  }
}

// ---------------- weight prep: Wt[orow0+n][k] = bf16(W[k][n] (+ 2*down@up)) -
__global__ __launch_bounds__(256) void k_prep_w(
    const float* __restrict__ W, const float* __restrict__ down,
    const float* __restrict__ up, u16t* __restrict__ Wt, int K, int N,
    size_t ostride, int orow0)
{
  __shared__ float t[32][33];
  const int z = blockIdx.z;
  const float* Wz = W + (size_t)z * K * N;
  u16t* Wtz = Wt + (size_t)z * ostride + (size_t)orow0 * K;
  const int k0 = blockIdx.x * 32, n0 = blockIdx.y * 32;
  const int tx = threadIdx.x & 31, ty = threadIdx.x >> 5;
  for (int i = ty; i < 32; i += 8) {
    const int kk = k0 + i, nn = n0 + tx;
    float v = Wz[(size_t)kk * N + nn];
    if (down) {
      const float* dz = down + (size_t)z * K * 8 + (size_t)kk * 8;
      const float* uz = up + (size_t)z * 8 * N + nn;
      float lv = 0.f;
      #pragma unroll
      for (int r = 0; r < 8; ++r) lv += dz[r] * uz[(size_t)r * N];
      v += 2.0f * lv;   // LORA_SCALING
    }
    t[i][tx] = v;
  }
  __syncthreads();
  for (int i = ty; i < 32; i += 8)
    Wtz[(size_t)(n0 + i) * K + k0 + tx] = f2b(t[tx][i]);
}

// ---------------- patch gather: pt[(b*256+np)*128 + f*16+p] = x[b, np*16+p, f]
__global__ void k_patch(const float* __restrict__ x, u16t* __restrict__ pt) {
  const int idx = blockIdx.x * 256 + threadIdx.x;
  const int col = idx & 127, row = idx >> 7;
  const int f = col >> 4, pp = col & 15;
  const int b = row >> 8, np = row & 255;
  pt[idx] = f2b(x[(((size_t)b << 12) + np * 16 + pp) * 8 + f]);
}

// ---------------- LayerNorm (one wave per 512-row) -> bf16 ----------------
__global__ __launch_bounds__(256) void k_ln(
    const float* __restrict__ xin, const float* __restrict__ w,
    const float* __restrict__ bb, u16t* __restrict__ y)
{
  const int row = blockIdx.x * 4 + (threadIdx.x >> 6);
  const int lane = threadIdx.x & 63;
  const float4* xr = (const float4*)(xin + (size_t)row * 512);
  float4 a = xr[lane * 2], c = xr[lane * 2 + 1];
  float s = a.x + a.y + a.z + a.w + c.x + c.y + c.z + c.w;
  float qq = a.x * a.x + a.y * a.y + a.z * a.z + a.w * a.w +
             c.x * c.x + c.y * c.y + c.z * c.z + c.w * c.w;
  #pragma unroll
  for (int o = 32; o > 0; o >>= 1) { s += __shfl_xor(s, o); qq += __shfl_xor(qq, o); }
  const float mean = s * (1.f / 512.f);
  const float rs = rsqrtf(qq * (1.f / 512.f) - mean * mean + 1e-5f);
  const float4* wr = (const float4*)w; const float4* br = (const float4*)bb;
  float4 w0 = wr[lane * 2], w1 = wr[lane * 2 + 1];
  float4 b0 = br[lane * 2], b1 = br[lane * 2 + 1];
  union { u16t h[8]; uint4 v; } pk;
  pk.h[0] = f2b((a.x - mean) * rs * w0.x + b0.x);
  pk.h[1] = f2b((a.y - mean) * rs * w0.y + b0.y);
  pk.h[2] = f2b((a.z - mean) * rs * w0.z + b0.z);
  pk.h[3] = f2b((a.w - mean) * rs * w0.w + b0.w);
  pk.h[4] = f2b((c.x - mean) * rs * w1.x + b1.x);
  pk.h[5] = f2b((c.y - mean) * rs * w1.y + b1.y);
  pk.h[6] = f2b((c.z - mean) * rs * w1.z + b1.z);
  pk.h[7] = f2b((c.w - mean) * rs * w1.w + b1.w);
  *(uint4*)(y + (size_t)row * 512 + lane * 8) = pk.v;
}

// ---------------- patch LN + pos_enc -> h (fp32) ----------------
__global__ __launch_bounds__(256) void k_ln_pos(
    const float* __restrict__ xin, const float* __restrict__ w,
    const float* __restrict__ bb, const float* __restrict__ pos,
    float* __restrict__ h)
{
  const int row = blockIdx.x * 4 + (threadIdx.x >> 6);
  const int lane = threadIdx.x & 63;
  const float4* xr = (const float4*)(xin + (size_t)row * 512);
  float4 a = xr[lane * 2], c = xr[lane * 2 + 1];
  float s = a.x + a.y + a.z + a.w + c.x + c.y + c.z + c.w;
  float qq = a.x * a.x + a.y * a.y + a.z * a.z + a.w * a.w +
             c.x * c.x + c.y * c.y + c.z * c.z + c.w * c.w;
  #pragma unroll
  for (int o = 32; o > 0; o >>= 1) { s += __shfl_xor(s, o); qq += __shfl_xor(qq, o); }
  const float mean = s * (1.f / 512.f);
  const float rs = rsqrtf(qq * (1.f / 512.f) - mean * mean + 1e-5f);
  const float4* wr = (const float4*)w; const float4* br = (const float4*)bb;
  float4 w0 = wr[lane * 2], w1 = wr[lane * 2 + 1];
  float4 b0 = br[lane * 2], b1 = br[lane * 2 + 1];
  const int np = row & 255;
  const float4* pr = (const float4*)(pos + (size_t)np * 512);
  float4 p0 = pr[lane * 2], p1 = pr[lane * 2 + 1];
  float4 o0, o1;
  o0.x = (a.x - mean) * rs * w0.x + b0.x + p0.x;
  o0.y = (a.y - mean) * rs * w0.y + b0.y + p0.y;
  o0.z = (a.z - mean) * rs * w0.z + b0.z + p0.z;
  o0.w = (a.w - mean) * rs * w0.w + b0.w + p0.w;
  o1.x = (c.x - mean) * rs * w1.x + b1.x + p1.x;
  o1.y = (c.y - mean) * rs * w1.y + b1.y + p1.y;
  o1.z = (c.z - mean) * rs * w1.z + b1.z + p1.z;
  o1.w = (c.w - mean) * rs * w1.w + b1.w + p1.w;
  float4* hr = (float4*)(h + (size_t)row * 512);
  hr[lane * 2] = o0; hr[lane * 2 + 1] = o1;
}

// ---------------- MFMA flash attention -------------------------------------
__global__ __launch_bounds__(256) void k_attn(
    const u16t* __restrict__ qkv, u16t* __restrict__ out)
{
  __shared__ __align__(16) u16t Qs[128 * LDSP];
  __shared__ __align__(16) u16t Ks[64 * LDSP];
  __shared__ __align__(16) u16t Vts[64 * LDSP];

  const int bh = blockIdx.x >> 1, half = blockIdx.x & 1;
  const int b = bh >> 3, hd = bh & 7;
  const int tid = threadIdx.x, wave = tid >> 6, lane = tid & 63;
  const int lr = lane & 15, quad = lane >> 4;

  const size_t rowbase = (size_t)b * 256;
  const u16t* qg = qkv + (rowbase + half * 128) * 1536 + hd * 64;
  const u16t* kg = qkv + rowbase * 1536 + 512 + hd * 64;
  const u16t* vg = qkv + rowbase * 1536 + 1024 + hd * 64;

  #pragma unroll
  for (int i = 0; i < 4; ++i) {
    const int idx = tid + i * 256, row = idx >> 3, seg = idx & 7;
    uint4 u = *(const uint4*)(qg + (size_t)row * 1536 + seg * 8);
    *(uint4*)&Qs[row * LDSP + seg * 8] = u;
  }
  __syncthreads();

  bf16x8 qf[2][2];
  #pragma unroll
  for (int qi = 0; qi < 2; ++qi)
    #pragma unroll
    for (int dh = 0; dh < 2; ++dh)
      qf[qi][dh] = *(const bf16x8*)&Qs[(wave * 32 + qi * 16 + lr) * LDSP + dh * 32 + quad * 8];

  f32x4 O[2][4] = {};
  float mrun[2] = {-1e30f, -1e30f}, lrun[2] = {0.f, 0.f};

  for (int c = 0; c < 4; ++c) {
    __syncthreads();
    #pragma unroll
    for (int i = 0; i < 2; ++i) {
      const int idx = tid + i * 256, row = idx >> 3, seg = idx & 7;
      uint4 u = *(const uint4*)(kg + (size_t)(c * 64 + row) * 1536 + seg * 8);
      *(uint4*)&Ks[row * LDSP + seg * 8] = u;
    }
    {
      const int key = tid & 63, dg = (tid >> 6) * 16;
      const u16t* vrow = vg + (size_t)(c * 64 + key) * 1536 + dg;
      union { u16t h[16]; uint4 v[2]; } tmp;
      tmp.v[0] = *(const uint4*)(vrow);
      tmp.v[1] = *(const uint4*)(vrow + 8);
      #pragma unroll
      for (int i = 0; i < 16; ++i)
        Vts[(dg + i) * LDSP + key] = tmp.h[i];
    }
    __syncthreads();

    #pragma unroll
    for (int qi = 0; qi < 2; ++qi) {
      f32x4 s[4];
      #pragma unroll
      for (int kt = 0; kt < 4; ++kt) {
        f32x4 a = {};
        #pragma unroll
        for (int dh = 0; dh < 2; ++dh) {
          bf16x8 kf = *(const bf16x8*)&Ks[(kt * 16 + lr) * LDSP + dh * 32 + quad * 8];
          a = __builtin_amdgcn_mfma_f32_16x16x32_bf16(kf, qf[qi][dh], a, 0, 0, 0);
        }
        s[kt] = a;
      }
      constexpr float SC = 0.125f * 1.44269504088896f;
      float cmax = -1e30f;
      #pragma unroll
      for (int kt = 0; kt < 4; ++kt)
        #pragma unroll
        for (int r = 0; r < 4; ++r) { s[kt][r] *= SC; cmax = fmaxf(cmax, s[kt][r]); }
      cmax = fmaxf(cmax, __shfl_xor(cmax, 16));
      cmax = fmaxf(cmax, __shfl_xor(cmax, 32));
      const float mn = fmaxf(mrun[qi], cmax);
      const float alpha = exp2f(mrun[qi] - mn);
      mrun[qi] = mn;
      float lsum = 0.f;
      s16x4 pf[4];
      #pragma unroll
      for (int kt = 0; kt < 4; ++kt) {
        #pragma unroll
        for (int r = 0; r < 4; ++r) {
          const u16t eb = f2b(exp2f(s[kt][r] - mn));
          pf[kt][r] = (short)eb;
          lsum += b2f(eb);
        }
      }
      lsum += __shfl_xor(lsum, 16);
      lsum += __shfl_xor(lsum, 32);
      lrun[qi] = lrun[qi] * alpha + lsum;
      #pragma unroll
      for (int dt = 0; dt < 4; ++dt) {
        f32x4 o = O[qi][dt];
        o[0] *= alpha; o[1] *= alpha; o[2] *= alpha; o[3] *= alpha;
        #pragma unroll
        for (int kt = 0; kt < 4; ++kt) {
          s16x4 vf = *(const s16x4*)&Vts[(dt * 16 + lr) * LDSP + kt * 16 + quad * 4];
          o = __builtin_amdgcn_mfma_f32_16x16x16bf16_1k(vf, pf[kt], o, 0, 0, 0);
        }
        O[qi][dt] = o;
      }
    }
  }
  #pragma unroll
  for (int qi = 0; qi < 2; ++qi) {
    const float rl = 1.f / lrun[qi];
    u16t* orow = out + (rowbase + half * 128 + wave * 32 + qi * 16 + lr) * 512 + hd * 64 + quad * 4;
    #pragma unroll
    for (int dt = 0; dt < 4; ++dt) {
      union { u16t h[4]; uint2 v; } pk;
      #pragma unroll
      for (int r = 0; r < 4; ++r) pk.h[r] = f2b(O[qi][dt][r] * rl);
      *(uint2*)(orow + dt * 16) = pk.v;
    }
  }
}

// ---------------- final mean over patches ----------------
__global__ void k_mean(const u16t* __restrict__ y, float* __restrict__ out) {
  const int b = blockIdx.x, d = threadIdx.x;   // 64 x 512
  float s = 0.f;
  #pragma unroll 8
  for (int np = 0; np < 256; ++np) s += b2f(y[((size_t)b * 256 + np) * 512 + d]);
  out[(size_t)b * 512 + d] = s * (1.f / 256.f);
}

// ---------------- host ----------------
extern "C" void kernel_launch(void* const* d_in, const int* in_sizes, int n_in,
                              void* d_out, int out_size, void* d_ws, size_t ws_size,
                              hipStream_t stream)
{
  (void)in_sizes; (void)n_in; (void)out_size;
  const float* x        = (const float*)d_in[0];
  const float* patch_w  = (const float*)d_in[1];
  const float* patch_b  = (const float*)d_in[2];
  const float* patch_ln_w = (const float*)d_in[3];
  const float* patch_ln_b = (const float*)d_in[4];
  const float* pos_enc  = (const float*)d_in[5];
  const float* ln1_w    = (const float*)d_in[6];
  const float* ln1_b    = (const float*)d_in[7];
  const float* q_w      = (const float*)d_in[8];
  const float* q_b      = (const float*)d_in[9];
  const float* k_w      = (const float*)d_in[10];
  const float* k_b      = (const float*)d_in[11];
  const float* v_w      = (const float*)d_in[12];
  const float* v_b      = (const float*)d_in[13];
  const float* lq_down  = (const float*)d_in[14];
  const float* lq_up    = (const float*)d_in[15];
  const float* lk_down  = (const float*)d_in[16];
  const float* lk_up    = (const float*)d_in[17];
  const float* lv_down  = (const float*)d_in[18];
  const float* lv_up    = (const float*)d_in[19];
  const float* o_w      = (const float*)d_in[20];
  const float* o_b      = (const float*)d_in[21];
  const float* ln2_w    = (const float*)d_in[22];
  const float* ln2_b    = (const float*)d_in[23];
  const float* ff1_w    = (const float*)d_in[24];
  const float* ff1_b    = (const float*)d_in[25];
  const float* ff2_w    = (const float*)d_in[26];
  const float* ff2_b    = (const float*)d_in[27];
  const float* norm_w   = (const float*)d_in[28];
  const float* norm_b   = (const float*)d_in[29];
  float* out = (float*)d_out;

  // workspace carve (~148.1 MiB)
  char* p = (char*)d_ws;
  float* h  = (float*)p;  p += (size_t)MROWS * 512 * 4;       // 32 MB
  u16t*  y  = (u16t*)p;   p += (size_t)MROWS * 512 * 2;       // 16 MB
  char* uni = p;          p += (size_t)4 * MROWS * 512 * 2;   // 64 MB union
  u16t* qkvb = (u16t*)uni;                                    // [M,1536] (48 MB)
  u16t* ab = (u16t*)(uni + (size_t)MROWS * 1536 * 2);         // [M,512]  (16 MB)
  u16t* g  = (u16t*)uni;                                      // [M,2048] aliases qkv+ab
  float* pe = (float*)uni;                                    // [M,512] fp32 (pre-LN patch)
  u16t* pt = (u16t*)(uni + (size_t)MROWS * 512 * 4);          // [M,128] after pe
  u16t* wqkv = (u16t*)p; p += (size_t)NLAYER * 1536 * 512 * 2;
  u16t* wo = (u16t*)p; p += (size_t)NLAYER * 512 * 512 * 2;
  u16t* w1 = (u16t*)p; p += (size_t)NLAYER * 512 * 2048 * 2;
  u16t* w2 = (u16t*)p; p += (size_t)NLAYER * 2048 * 512 * 2;
  u16t* wp = (u16t*)p; p += (size_t)512 * 128 * 2;
  if ((size_t)(p - (char*)d_ws) > ws_size) return;

  const dim3 blk(256);
  const size_t QKVS = (size_t)1536 * 512;
  k_prep_w<<<dim3(16, 16, NLAYER), blk, 0, stream>>>(q_w, lq_down, lq_up, wqkv, 512, 512, QKVS, 0);
  k_prep_w<<<dim3(16, 16, NLAYER), blk, 0, stream>>>(k_w, lk_down, lk_up, wqkv, 512, 512, QKVS, 512);
  k_prep_w<<<dim3(16, 16, NLAYER), blk, 0, stream>>>(v_w, lv_down, lv_up, wqkv, 512, 512, QKVS, 1024);
  k_prep_w<<<dim3(16, 16, NLAYER), blk, 0, stream>>>(o_w, nullptr, nullptr, wo, 512, 512, (size_t)512 * 512, 0);
  k_prep_w<<<dim3(16, 64, NLAYER), blk, 0, stream>>>(ff1_w, nullptr, nullptr, w1, 512, 2048, (size_t)512 * 2048, 0);
  k_prep_w<<<dim3(64, 16, NLAYER), blk, 0, stream>>>(ff2_w, nullptr, nullptr, w2, 2048, 512, (size_t)2048 * 512, 0);
  k_prep_w<<<dim3(4, 16, 1),       blk, 0, stream>>>(patch_w, nullptr, nullptr, wp, 128, 512, 0, 0);

  k_patch<<<dim3(MROWS * 128 / 256), blk, 0, stream>>>(x, pt);
  // grids: (MROWS/128) * (N/128) blocks, 1-D (all multiples of 8 for swizzle)
  k_gemm<<<dim3(128 * 4), blk, 0, stream>>>(pt, wp, patch_b, nullptr, nullptr, pe, nullptr, MROWS, 512, 128, 3);
  k_ln_pos<<<dim3(MROWS / 4), blk, 0, stream>>>(pe, patch_ln_w, patch_ln_b, pos_enc, h);

  for (int i = 0; i < NLAYER; ++i) {
    const size_t ws512 = (size_t)i * 512 * 512, wsff = (size_t)i * 512 * 2048;
    k_ln<<<dim3(MROWS / 4), blk, 0, stream>>>(h, ln1_w + i * 512, ln1_b + i * 512, y);
    k_gemm<<<dim3(128 * 12), blk, 0, stream>>>(y, wqkv + i * QKVS, q_b + i * 512, k_b + i * 512,
                                               v_b + i * 512, nullptr, qkvb, MROWS, 1536, 512, 0);
    k_attn<<<dim3(1024), blk, 0, stream>>>(qkvb, ab);
    k_gemm<<<dim3(128 * 4), blk, 0, stream>>>(ab, wo + ws512, o_b + i * 512, nullptr, nullptr, h, nullptr, MROWS, 512, 512, 2);
    k_ln<<<dim3(MROWS / 4), blk, 0, stream>>>(h, ln2_w + i * 512, ln2_b + i * 512, y);
    k_gemm<<<dim3(128 * 16), blk, 0, stream>>>(y, w1 + wsff, ff1_b + i * 2048, nullptr, nullptr, nullptr, g, MROWS, 2048, 512, 1);
    k_gemm<<<dim3(128 * 4), blk, 0, stream>>>(g, w2 + wsff, ff2_b + i * 512, nullptr, nullptr, h, nullptr, MROWS, 512, 2048, 2);
  }
  k_ln<<<dim3(MROWS / 4), blk, 0, stream>>>(h, norm_w, norm_b, y);
  k_mean<<<dim3(BATCH), dim3(512), 0, stream>>>(y, out);
}

// Round 5
// 1468.770 us; speedup vs baseline: 1.1137x; 1.0087x over previous
//
#include <hip/hip_runtime.h>
#include <cstdint>
#include <cstddef>

// ---------------- constants ----------------
constexpr int BATCH = 64, SEQ = 4096, FEAT = 8, PLEN = 16;
constexpr int DMODEL = 512, NHEAD = 8, NLAYER = 6, DFF = 2048;
constexpr int NPATCH = 256, MROWS = BATCH * NPATCH;   // 16384
constexpr int DK = 64;
constexpr int LDSP = 72;   // padded LDS row stride (u16) for attn tiles

typedef unsigned short u16t;
typedef __bf16 bf16t;
typedef bf16t bf16x8 __attribute__((ext_vector_type(8)));
typedef short s16x4 __attribute__((ext_vector_type(4)));
typedef float f32x4 __attribute__((ext_vector_type(4)));

__device__ __forceinline__ float b2f(u16t u) {
  union { unsigned int ui; float f; } v; v.ui = ((unsigned int)u) << 16; return v.f;
}
__device__ __forceinline__ u16t f2b(float f) {
  union { float f; unsigned int ui; } v; v.f = f;
  return (u16t)((v.ui + 0x7fffu + ((v.ui >> 16) & 1u)) >> 16);
}
__device__ __forceinline__ void g2l16(void* lds, const void* g) {
  __builtin_amdgcn_global_load_lds(
      (__attribute__((address_space(1))) void*)g,
      (__attribute__((address_space(3))) void*)lds, 16, 0, 0);
}

// exact-erf GELU via Abramowitz-Stegun 7.1.26 (|erf err| < 1.5e-7).
__device__ __forceinline__ float gelu_erf(float x) {
  const float z = fabsf(x) * 0.70710678118654752f;
  const float t = __builtin_amdgcn_rcpf(__builtin_fmaf(0.3275911f, z, 1.0f));
  float p = __builtin_fmaf(1.061405429f, t, -1.453152027f);
  p = __builtin_fmaf(p, t, 1.421413741f);
  p = __builtin_fmaf(p, t, -0.284496736f);
  p = __builtin_fmaf(p, t, 0.254829592f);
  const float e = __expf(-z * z);
  const float er = __builtin_fmaf(-p * t, e, 1.0f);   // erf(|z|)
  const float s = copysignf(er, x);
  return 0.5f * x * (1.0f + s);
}

// ---------------- R13 GEMM: 128x128 tile, 3 blocks/CU --------------------
// Routed to shapes whose grid is round-exact at this geometry:
// QKV (1536 blk = 2.0 rounds @3/CU), O/FF2/patch (512 blk = balanced 2/CU).
// R4-verified.  Ring-3 x 16KB, counted vmcnt(4), 1 barrier/K-tile.
// mode 0: Cb = bf16(acc+bias)        mode 1: Cb = bf16(gelu(acc+bias))
// mode 2: Cf += acc+bias (residual)  mode 3: Cf  = acc+bias
__global__ __launch_bounds__(256, 3) void k_gemm(
    const u16t* __restrict__ A, const u16t* __restrict__ Bt,
    const float* __restrict__ bias, const float* __restrict__ b2,
    const float* __restrict__ b3, float* __restrict__ Cf,
    u16t* __restrict__ Cb, int M, int N, int K, int mode)
{
  __shared__ __align__(16) u16t SH[3 * 8192];   // 48 KiB ring; epilogue reuses

  const int nbn = N >> 7;                       // N / 128
  const int cpx = gridDim.x >> 3;
  const int wgid = (blockIdx.x & 7) * cpx + (blockIdx.x >> 3);
  const int bm = (wgid / nbn) << 7;             // 128-row tile
  const int bn = (wgid % nbn) << 7;             // 128-col tile

  const int tid = threadIdx.x, wave = tid >> 6, lane = tid & 63;
  const int lr = lane & 15, quad = lane >> 4;
  const int wm = (wave >> 1) << 6;              // 0 / 64
  const int wn = (wave & 1) << 6;               // 0 / 64

  const int sseg = (lane & 3) ^ ((lane >> 3) & 3);
  const u16t* gA = A + (size_t)(bm + (lane >> 2)) * K + sseg * 8;
  const u16t* gB = Bt + (size_t)(bn + (lane >> 2)) * K + sseg * 8;

  const int sw8 = (quad ^ ((lr >> 1) & 3)) << 3;
  const int aoff = (wm + lr) * 32 + sw8;          // + i*512 per M-frag
  const int boff = 4096 + (wn + lr) * 32 + sw8;   // + j*512 per N-frag

  f32x4 acc[4][4] = {};

  u16t* buf0 = SH;
  u16t* buf1 = SH + 8192;
  u16t* buf2 = SH + 16384;

#define STAGE(BUF_, S_) do {                                                   \
    g2l16((BUF_) + wave * 512,        gA + (size_t)(wave * 16) * K + (S_) * 32);   \
    g2l16((BUF_) + (wave + 4) * 512,  gA + (size_t)((wave + 4) * 16) * K + (S_) * 32); \
    g2l16((BUF_) + 4096 + wave * 512, gB + (size_t)(wave * 16) * K + (S_) * 32);   \
    g2l16((BUF_) + 4096 + (wave + 4) * 512, gB + (size_t)((wave + 4) * 16) * K + (S_) * 32); \
  } while (0)

  const int nt = K >> 5;
  STAGE(buf0, 0);
  STAGE(buf1, 1);

  for (int t = 0; t < nt - 1; ++t) {
    asm volatile("s_waitcnt vmcnt(4)" ::: "memory");
    __builtin_amdgcn_s_barrier();
    asm volatile("" ::: "memory");
    if (t + 2 < nt) STAGE(buf2, t + 2);
    bf16x8 af[4], bfr[4];
    #pragma unroll
    for (int i = 0; i < 4; ++i) af[i] = *(const bf16x8*)&buf0[aoff + i * 512];
    #pragma unroll
    for (int j = 0; j < 4; ++j) bfr[j] = *(const bf16x8*)&buf0[boff + j * 512];
    __builtin_amdgcn_s_setprio(1);
    #pragma unroll
    for (int j = 0; j < 4; ++j)
      #pragma unroll
      for (int i = 0; i < 4; ++i)
        acc[j][i] = __builtin_amdgcn_mfma_f32_16x16x32_bf16(bfr[j], af[i], acc[j][i], 0, 0, 0);
    __builtin_amdgcn_s_setprio(0);
    u16t* tmp = buf0; buf0 = buf1; buf1 = buf2; buf2 = tmp;
  }
  {
    asm volatile("s_waitcnt vmcnt(0)" ::: "memory");
    __builtin_amdgcn_s_barrier();
    asm volatile("" ::: "memory");
    bf16x8 af[4], bfr[4];
    #pragma unroll
    for (int i = 0; i < 4; ++i) af[i] = *(const bf16x8*)&buf0[aoff + i * 512];
    #pragma unroll
    for (int j = 0; j < 4; ++j) bfr[j] = *(const bf16x8*)&buf0[boff + j * 512];
    __builtin_amdgcn_s_setprio(1);
    #pragma unroll
    for (int j = 0; j < 4; ++j)
      #pragma unroll
      for (int i = 0; i < 4; ++i)
        acc[j][i] = __builtin_amdgcn_mfma_f32_16x16x32_bf16(bfr[j], af[i], acc[j][i], 0, 0, 0);
    __builtin_amdgcn_s_setprio(0);
  }
#undef STAGE

  const float* bp = bias;
  int reg0 = 0;
  if (bias && b2) { reg0 = (bn >> 9) << 9; bp = reg0 == 0 ? bias : (reg0 == 512 ? b2 : b3); }
  float4 bv[4];
  #pragma unroll
  for (int jN = 0; jN < 4; ++jN) {
    const int gn0 = bn + wn + jN * 16 + quad * 4;
    bv[jN] = bias ? *(const float4*)&bp[gn0 - reg0] : make_float4(0.f, 0.f, 0.f, 0.f);
  }

  if (mode <= 1) {
    __syncthreads();
    u16t* E = SH;      // [128][128] u16 (32KB), seg-swizzled
    #pragma unroll
    for (int jN = 0; jN < 4; ++jN) {
      const int cl = wn + jN * 16 + quad * 4;
      const int seg = cl >> 3, intra = cl & 7;
      #pragma unroll
      for (int iM = 0; iM < 4; ++iM) {
        const int r = wm + iM * 16 + lr;
        float v0 = acc[jN][iM][0] + bv[jN].x, v1 = acc[jN][iM][1] + bv[jN].y;
        float v2 = acc[jN][iM][2] + bv[jN].z, v3 = acc[jN][iM][3] + bv[jN].w;
        union { u16t h[4]; uint2 u; } pk;
        if (mode == 1) {
          pk.h[0] = f2b(gelu_erf(v0)); pk.h[1] = f2b(gelu_erf(v1));
          pk.h[2] = f2b(gelu_erf(v2)); pk.h[3] = f2b(gelu_erf(v3));
        } else {
          pk.h[0] = f2b(v0); pk.h[1] = f2b(v1); pk.h[2] = f2b(v2); pk.h[3] = f2b(v3);
        }
        *(uint2*)&E[r * 128 + ((seg ^ (r & 7)) << 3) + intra] = pk.u;
      }
    }
    __syncthreads();
    const int rr = tid >> 2, s0 = tid & 3;
    #pragma unroll
    for (int pass = 0; pass < 2; ++pass) {
      const int r = pass * 64 + rr;
      u16t* gout = Cb + (size_t)(bm + r) * N + bn;
      #pragma unroll
      for (int it = 0; it < 4; ++it) {
        const int s = s0 + it * 4;
        uint4 u = *(const uint4*)&E[r * 128 + ((s ^ (r & 7)) << 3)];
        *(uint4*)(gout + s * 8) = u;
      }
    }
  } else {
    #pragma unroll
    for (int jN = 0; jN < 4; ++jN) {
      const int gn0 = bn + wn + jN * 16 + quad * 4;
      #pragma unroll
      for (int iM = 0; iM < 4; ++iM) {
        const int gm = bm + wm + iM * 16 + lr;
        const size_t off = (size_t)gm * N + gn0;
        float v0 = acc[jN][iM][0] + bv[jN].x, v1 = acc[jN][iM][1] + bv[jN].y;
        float v2 = acc[jN][iM][2] + bv[jN].z, v3 = acc[jN][iM][3] + bv[jN].w;
        if (mode == 2) {
          float4 c = *(float4*)(Cf + off);
          c.x += v0; c.y += v1; c.z += v2; c.w += v3;
          *(float4*)(Cf + off) = c;
        } else {
          *(float4*)(Cf + off) = make_float4(v0, v1, v2, v3);
        }
      }
    }
  }
}

// ---------------- R10 GEMM: 256x128 tile, 2 blocks/CU (FF1 route) ----------
// Best measured FF1 (59.8us): 1024 blocks = exactly 2.0 rounds @2/CU, and
// highest compute intensity (1.14e-5 staged-B/FLOP).  R1/R3-verified.
__global__ __launch_bounds__(256, 2) void k_gemmw(
    const u16t* __restrict__ A, const u16t* __restrict__ Bt,
    const float* __restrict__ bias, const float* __restrict__ b2,
    const float* __restrict__ b3, float* __restrict__ Cf,
    u16t* __restrict__ Cb, int M, int N, int K, int mode)
{
  __shared__ __align__(16) u16t SH[3 * 12288];   // 72 KiB ring; epilogue reuses

  const int nbn = N >> 7;                       // N / 128
  const int cpx = gridDim.x >> 3;
  const int wgid = (blockIdx.x & 7) * cpx + (blockIdx.x >> 3);
  const int bm = (wgid / nbn) << 8;             // 256-row tile
  const int bn = (wgid % nbn) << 7;             // 128-col tile

  const int tid = threadIdx.x, wave = tid >> 6, lane = tid & 63;
  const int lr = lane & 15, quad = lane >> 4;
  const int wm = (wave >> 1) << 7;              // 0 / 128
  const int wn = (wave & 1) << 6;               // 0 / 64

  const int sseg = (lane & 3) ^ ((lane >> 3) & 3);
  const u16t* gA = A + (size_t)(bm + (lane >> 2)) * K + sseg * 8;
  const u16t* gB = Bt + (size_t)(bn + (lane >> 2)) * K + sseg * 8;

  const int sw8 = (quad ^ ((lr >> 1) & 3)) << 3;
  const int aoff = (wm + lr) * 32 + sw8;          // + i*512 per M-frag
  const int boff = 8192 + (wn + lr) * 32 + sw8;   // + j*512 per N-frag

  f32x4 acc[4][8] = {};   // [jN][iM]

  u16t* buf0 = SH;
  u16t* buf1 = SH + 12288;
  u16t* buf2 = SH + 24576;

#define STAGE_W(BUF_, S_) do {                                                 \
    g2l16((BUF_) + wave * 512,        gA + (size_t)(wave * 16) * K + (S_) * 32);   \
    g2l16((BUF_) + (wave + 4) * 512,  gA + (size_t)((wave + 4) * 16) * K + (S_) * 32); \
    g2l16((BUF_) + (wave + 8) * 512,  gA + (size_t)((wave + 8) * 16) * K + (S_) * 32); \
    g2l16((BUF_) + (wave + 12) * 512, gA + (size_t)((wave + 12) * 16) * K + (S_) * 32); \
    g2l16((BUF_) + 8192 + wave * 512, gB + (size_t)(wave * 16) * K + (S_) * 32);   \
    g2l16((BUF_) + 8192 + (wave + 4) * 512, gB + (size_t)((wave + 4) * 16) * K + (S_) * 32); \
  } while (0)

  const int nt = K >> 5;
  STAGE_W(buf0, 0);
  STAGE_W(buf1, 1);

  for (int t = 0; t < nt - 1; ++t) {
    asm volatile("s_waitcnt vmcnt(6)" ::: "memory");
    __builtin_amdgcn_s_barrier();
    asm volatile("" ::: "memory");
    if (t + 2 < nt) STAGE_W(buf2, t + 2);
    bf16x8 af[8], bfr[4];
    #pragma unroll
    for (int i = 0; i < 8; ++i) af[i] = *(const bf16x8*)&buf0[aoff + i * 512];
    #pragma unroll
    for (int j = 0; j < 4; ++j) bfr[j] = *(const bf16x8*)&buf0[boff + j * 512];
    __builtin_amdgcn_s_setprio(1);
    #pragma unroll
    for (int j = 0; j < 4; ++j)
      #pragma unroll
      for (int i = 0; i < 8; ++i)
        acc[j][i] = __builtin_amdgcn_mfma_f32_16x16x32_bf16(bfr[j], af[i], acc[j][i], 0, 0, 0);
    __builtin_amdgcn_s_setprio(0);
    u16t* tmp = buf0; buf0 = buf1; buf1 = buf2; buf2 = tmp;
  }
  {
    asm volatile("s_waitcnt vmcnt(0)" ::: "memory");
    __builtin_amdgcn_s_barrier();
    asm volatile("" ::: "memory");
    bf16x8 af[8], bfr[4];
    #pragma unroll
    for (int i = 0; i < 8; ++i) af[i] = *(const bf16x8*)&buf0[aoff + i * 512];
    #pragma unroll
    for (int j = 0; j < 4; ++j) bfr[j] = *(const bf16x8*)&buf0[boff + j * 512];
    __builtin_amdgcn_s_setprio(1);
    #pragma unroll
    for (int j = 0; j < 4; ++j)
      #pragma unroll
      for (int i = 0; i < 8; ++i)
        acc[j][i] = __builtin_amdgcn_mfma_f32_16x16x32_bf16(bfr[j], af[i], acc[j][i], 0, 0, 0);
    __builtin_amdgcn_s_setprio(0);
  }
#undef STAGE_W

  const float* bp = bias;
  int reg0 = 0;
  if (bias && b2) { reg0 = (bn >> 9) << 9; bp = reg0 == 0 ? bias : (reg0 == 512 ? b2 : b3); }
  float4 bv[4];
  #pragma unroll
  for (int jN = 0; jN < 4; ++jN) {
    const int gn0 = bn + wn + jN * 16 + quad * 4;
    bv[jN] = bias ? *(const float4*)&bp[gn0 - reg0] : make_float4(0.f, 0.f, 0.f, 0.f);
  }

  if (mode <= 1) {
    __syncthreads();
    u16t* E = SH;
    #pragma unroll
    for (int jN = 0; jN < 4; ++jN) {
      const int cl = wn + jN * 16 + quad * 4;
      const int seg = cl >> 3, intra = cl & 7;
      #pragma unroll
      for (int iM = 0; iM < 8; ++iM) {
        const int r = wm + iM * 16 + lr;
        float v0 = acc[jN][iM][0] + bv[jN].x, v1 = acc[jN][iM][1] + bv[jN].y;
        float v2 = acc[jN][iM][2] + bv[jN].z, v3 = acc[jN][iM][3] + bv[jN].w;
        union { u16t h[4]; uint2 u; } pk;
        if (mode == 1) {
          pk.h[0] = f2b(gelu_erf(v0)); pk.h[1] = f2b(gelu_erf(v1));
          pk.h[2] = f2b(gelu_erf(v2)); pk.h[3] = f2b(gelu_erf(v3));
        } else {
          pk.h[0] = f2b(v0); pk.h[1] = f2b(v1); pk.h[2] = f2b(v2); pk.h[3] = f2b(v3);
        }
        *(uint2*)&E[r * 128 + ((seg ^ (r & 7)) << 3) + intra] = pk.u;
      }
    }
    __syncthreads();
    const int rr = tid >> 2, s0 = tid & 3;
    #pragma unroll
    for (int pass = 0; pass < 4; ++pass) {
      const int r = pass * 64 + rr;
      u16t* gout = Cb + (size_t)(bm + r) * N + bn;
      #pragma unroll
      for (int it = 0; it < 4; ++it) {
        const int s = s0 + it * 4;
        uint4 u = *(const uint4*)&E[r * 128 + ((s ^ (r & 7)) << 3)];
        *(uint4*)(gout + s * 8) = u;
      }
    }
  } else {
    #pragma unroll
    for (int jN = 0; jN < 4; ++jN) {
      const int gn0 = bn + wn + jN * 16 + quad * 4;
      #pragma unroll
      for (int iM = 0; iM < 8; ++iM) {
        const int gm = bm + wm + iM * 16 + lr;
        const size_t off = (size_t)gm * N + gn0;
        float v0 = acc[jN][iM][0] + bv[jN].x, v1 = acc[jN][iM][1] + bv[jN].y;
        float v2 = acc[jN][iM][2] + bv[jN].z, v3 = acc[jN][iM][3] + bv[jN].w;
        if (mode == 2) {
          float4 c = *(float4*)(Cf + off);
          c.x += v0; c.y += v1; c.z += v2; c.w += v3;
          *(float4*)(Cf + off) = c;
        } else {
          *(float4*)(Cf + off) = make_float4(v0, v1, v2, v3);
        }
      }
    }
  }
}

// ---------------- weight prep: Wt[orow0+n][k] = bf16(W[k][n] (+ 2*down@up)) -
__global__ __launch_bounds__(256) void k_prep_w(
    const float* __restrict__ W, const float* __restrict__ down,
    const float* __restrict__ up, u16t* __restrict__ Wt, int K, int N,
    size_t ostride, int orow0)
{
  __shared__ float t[32][33];
  const int z = blockIdx.z;
  const float* Wz = W + (size_t)z * K * N;
  u16t* Wtz = Wt + (size_t)z * ostride + (size_t)orow0 * K;
  const int k0 = blockIdx.x * 32, n0 = blockIdx.y * 32;
  const int tx = threadIdx.x & 31, ty = threadIdx.x >> 5;
  for (int i = ty; i < 32; i += 8) {
    const int kk = k0 + i, nn = n0 + tx;
    float v = Wz[(size_t)kk * N + nn];
    if (down) {
      const float* dz = down + (size_t)z * K * 8 + (size_t)kk * 8;
      const float* uz = up + (size_t)z * 8 * N + nn;
      float lv = 0.f;
      #pragma unroll
      for (int r = 0; r < 8; ++r) lv += dz[r] * uz[(size_t)r * N];
      v += 2.0f * lv;   // LORA_SCALING
    }
    t[i][tx] = v;
  }
  __syncthreads();
  for (int i = ty; i < 32; i += 8)
    Wtz[(size_t)(n0 + i) * K + k0 + tx] = f2b(t[tx][i]);
}

// ---------------- patch gather: pt[(b*256+np)*128 + f*16+p] = x[b, np*16+p, f]
__global__ void k_patch(const float* __restrict__ x, u16t* __restrict__ pt) {
  const int idx = blockIdx.x * 256 + threadIdx.x;
  const int col = idx & 127, row = idx >> 7;
  const int f = col >> 4, pp = col & 15;
  const int b = row >> 8, np = row & 255;
  pt[idx] = f2b(x[(((size_t)b << 12) + np * 16 + pp) * 8 + f]);
}

// ---------------- LayerNorm (one wave per 512-row) -> bf16 ----------------
__global__ __launch_bounds__(256) void k_ln(
    const float* __restrict__ xin, const float* __restrict__ w,
    const float* __restrict__ bb, u16t* __restrict__ y)
{
  const int row = blockIdx.x * 4 + (threadIdx.x >> 6);
  const int lane = threadIdx.x & 63;
  const float4* xr = (const float4*)(xin + (size_t)row * 512);
  float4 a = xr[lane * 2], c = xr[lane * 2 + 1];
  float s = a.x + a.y + a.z + a.w + c.x + c.y + c.z + c.w;
  float qq = a.x * a.x + a.y * a.y + a.z * a.z + a.w * a.w +
             c.x * c.x + c.y * c.y + c.z * c.z + c.w * c.w;
  #pragma unroll
  for (int o = 32; o > 0; o >>= 1) { s += __shfl_xor(s, o); qq += __shfl_xor(qq, o); }
  const float mean = s * (1.f / 512.f);
  const float rs = rsqrtf(qq * (1.f / 512.f) - mean * mean + 1e-5f);
  const float4* wr = (const float4*)w; const float4* br = (const float4*)bb;
  float4 w0 = wr[lane * 2], w1 = wr[lane * 2 + 1];
  float4 b0 = br[lane * 2], b1 = br[lane * 2 + 1];
  union { u16t h[8]; uint4 v; } pk;
  pk.h[0] = f2b((a.x - mean) * rs * w0.x + b0.x);
  pk.h[1] = f2b((a.y - mean) * rs * w0.y + b0.y);
  pk.h[2] = f2b((a.z - mean) * rs * w0.z + b0.z);
  pk.h[3] = f2b((a.w - mean) * rs * w0.w + b0.w);
  pk.h[4] = f2b((c.x - mean) * rs * w1.x + b1.x);
  pk.h[5] = f2b((c.y - mean) * rs * w1.y + b1.y);
  pk.h[6] = f2b((c.z - mean) * rs * w1.z + b1.z);
  pk.h[7] = f2b((c.w - mean) * rs * w1.w + b1.w);
  *(uint4*)(y + (size_t)row * 512 + lane * 8) = pk.v;
}

// ---------------- patch LN + pos_enc -> h (fp32) ----------------
__global__ __launch_bounds__(256) void k_ln_pos(
    const float* __restrict__ xin, const float* __restrict__ w,
    const float* __restrict__ bb, const float* __restrict__ pos,
    float* __restrict__ h)
{
  const int row = blockIdx.x * 4 + (threadIdx.x >> 6);
  const int lane = threadIdx.x & 63;
  const float4* xr = (const float4*)(xin + (size_t)row * 512);
  float4 a = xr[lane * 2], c = xr[lane * 2 + 1];
  float s = a.x + a.y + a.z + a.w + c.x + c.y + c.z + c.w;
  float qq = a.x * a.x + a.y * a.y + a.z * a.z + a.w * a.w +
             c.x * c.x + c.y * c.y + c.z * c.z + c.w * c.w;
  #pragma unroll
  for (int o = 32; o > 0; o >>= 1) { s += __shfl_xor(s, o); qq += __shfl_xor(qq, o); }
  const float mean = s * (1.f / 512.f);
  const float rs = rsqrtf(qq * (1.f / 512.f) - mean * mean + 1e-5f);
  const float4* wr = (const float4*)w; const float4* br = (const float4*)bb;
  float4 w0 = wr[lane * 2], w1 = wr[lane * 2 + 1];
  float4 b0 = br[lane * 2], b1 = br[lane * 2 + 1];
  const int np = row & 255;
  const float4* pr = (const float4*)(pos + (size_t)np * 512);
  float4 p0 = pr[lane * 2], p1 = pr[lane * 2 + 1];
  float4 o0, o1;
  o0.x = (a.x - mean) * rs * w0.x + b0.x + p0.x;
  o0.y = (a.y - mean) * rs * w0.y + b0.y + p0.y;
  o0.z = (a.z - mean) * rs * w0.z + b0.z + p0.z;
  o0.w = (a.w - mean) * rs * w0.w + b0.w + p0.w;
  o1.x = (c.x - mean) * rs * w1.x + b1.x + p1.x;
  o1.y = (c.y - mean) * rs * w1.y + b1.y + p1.y;
  o1.z = (c.z - mean) * rs * w1.z + b1.z + p1.z;
  o1.w = (c.w - mean) * rs * w1.w + b1.w + p1.w;
  float4* hr = (float4*)(h + (size_t)row * 512);
  hr[lane * 2] = o0; hr[lane * 2 + 1] = o1;
}

// ---------------- MFMA flash attention -------------------------------------
__global__ __launch_bounds__(256) void k_attn(
    const u16t* __restrict__ qkv, u16t* __restrict__ out)
{
  __shared__ __align__(16) u16t Qs[128 * LDSP];
  __shared__ __align__(16) u16t Ks[64 * LDSP];
  __shared__ __align__(16) u16t Vts[64 * LDSP];

  const int bh = blockIdx.x >> 1, half = blockIdx.x & 1;
  const int b = bh >> 3, hd = bh & 7;
  const int tid = threadIdx.x, wave = tid >> 6, lane = tid & 63;
  const int lr = lane & 15, quad = lane >> 4;

  const size_t rowbase = (size_t)b * 256;
  const u16t* qg = qkv + (rowbase + half * 128) * 1536 + hd * 64;
  const u16t* kg = qkv + rowbase * 1536 + 512 + hd * 64;
  const u16t* vg = qkv + rowbase * 1536 + 1024 + hd * 64;

  #pragma unroll
  for (int i = 0; i < 4; ++i) {
    const int idx = tid + i * 256, row = idx >> 3, seg = idx & 7;
    uint4 u = *(const uint4*)(qg + (size_t)row * 1536 + seg * 8);
    *(uint4*)&Qs[row * LDSP + seg * 8] = u;
  }
  __syncthreads();

  bf16x8 qf[2][2];
  #pragma unroll
  for (int qi = 0; qi < 2; ++qi)
    #pragma unroll
    for (int dh = 0; dh < 2; ++dh)
      qf[qi][dh] = *(const bf16x8*)&Qs[(wave * 32 + qi * 16 + lr) * LDSP + dh * 32 + quad * 8];

  f32x4 O[2][4] = {};
  float mrun[2] = {-1e30f, -1e30f}, lrun[2] = {0.f, 0.f};

  for (int c = 0; c < 4; ++c) {
    __syncthreads();
    #pragma unroll
    for (int i = 0; i < 2; ++i) {
      const int idx = tid + i * 256, row = idx >> 3, seg = idx & 7;
      uint4 u = *(const uint4*)(kg + (size_t)(c * 64 + row) * 1536 + seg * 8);
      *(uint4*)&Ks[row * LDSP + seg * 8] = u;
    }
    {
      const int key = tid & 63, dg = (tid >> 6) * 16;
      const u16t* vrow = vg + (size_t)(c * 64 + key) * 1536 + dg;
      union { u16t h[16]; uint4 v[2]; } tmp;
      tmp.v[0] = *(const uint4*)(vrow);
      tmp.v[1] = *(const uint4*)(vrow + 8);
      #pragma unroll
      for (int i = 0; i < 16; ++i)
        Vts[(dg + i) * LDSP + key] = tmp.h[i];
    }
    __syncthreads();

    #pragma unroll
    for (int qi = 0; qi < 2; ++qi) {
      f32x4 s[4];
      #pragma unroll
      for (int kt = 0; kt < 4; ++kt) {
        f32x4 a = {};
        #pragma unroll
        for (int dh = 0; dh < 2; ++dh) {
          bf16x8 kf = *(const bf16x8*)&Ks[(kt * 16 + lr) * LDSP + dh * 32 + quad * 8];
          a = __builtin_amdgcn_mfma_f32_16x16x32_bf16(kf, qf[qi][dh], a, 0, 0, 0);
        }
        s[kt] = a;
      }
      constexpr float SC = 0.125f * 1.44269504088896f;
      float cmax = -1e30f;
      #pragma unroll
      for (int kt = 0; kt < 4; ++kt)
        #pragma unroll
        for (int r = 0; r < 4; ++r) { s[kt][r] *= SC; cmax = fmaxf(cmax, s[kt][r]); }
      cmax = fmaxf(cmax, __shfl_xor(cmax, 16));
      cmax = fmaxf(cmax, __shfl_xor(cmax, 32));
      const float mn = fmaxf(mrun[qi], cmax);
      const float alpha = exp2f(mrun[qi] - mn);
      mrun[qi] = mn;
      float lsum = 0.f;
      s16x4 pf[4];
      #pragma unroll
      for (int kt = 0; kt < 4; ++kt) {
        #pragma unroll
        for (int r = 0; r < 4; ++r) {
          const u16t eb = f2b(exp2f(s[kt][r] - mn));
          pf[kt][r] = (short)eb;
          lsum += b2f(eb);
        }
      }
      lsum += __shfl_xor(lsum, 16);
      lsum += __shfl_xor(lsum, 32);
      lrun[qi] = lrun[qi] * alpha + lsum;
      #pragma unroll
      for (int dt = 0; dt < 4; ++dt) {
        f32x4 o = O[qi][dt];
        o[0] *= alpha; o[1] *= alpha; o[2] *= alpha; o[3] *= alpha;
        #pragma unroll
        for (int kt = 0; kt < 4; ++kt) {
          s16x4 vf = *(const s16x4*)&Vts[(dt * 16 + lr) * LDSP + kt * 16 + quad * 4];
          o = __builtin_amdgcn_mfma_f32_16x16x16bf16_1k(vf, pf[kt], o, 0, 0, 0);
        }
        O[qi][dt] = o;
      }
    }
  }
  #pragma unroll
  for (int qi = 0; qi < 2; ++qi) {
    const float rl = 1.f / lrun[qi];
    u16t* orow = out + (rowbase + half * 128 + wave * 32 + qi * 16 + lr) * 512 + hd * 64 + quad * 4;
    #pragma unroll
    for (int dt = 0; dt < 4; ++dt) {
      union { u16t h[4]; uint2 v; } pk;
      #pragma unroll
      for (int r = 0; r < 4; ++r) pk.h[r] = f2b(O[qi][dt][r] * rl);
      *(uint2*)(orow + dt * 16) = pk.v;
    }
  }
}

// ---------------- final mean over patches ----------------
__global__ void k_mean(const u16t* __restrict__ y, float* __restrict__ out) {
  const int b = blockIdx.x, d = threadIdx.x;   // 64 x 512
  float s = 0.f;
  #pragma unroll 8
  for (int np = 0; np < 256; ++np) s += b2f(y[((size_t)b * 256 + np) * 512 + d]);
  out[(size_t)b * 512 + d] = s * (1.f / 256.f);
}

// ---------------- host ----------------
extern "C" void kernel_launch(void* const* d_in, const int* in_sizes, int n_in,
                              void* d_out, int out_size, void* d_ws, size_t ws_size,
                              hipStream_t stream)
{
  (void)in_sizes; (void)n_in; (void)out_size;
  const float* x        = (const float*)d_in[0];
  const float* patch_w  = (const float*)d_in[1];
  const float* patch_b  = (const float*)d_in[2];
  const float* patch_ln_w = (const float*)d_in[3];
  const float* patch_ln_b = (const float*)d_in[4];
  const float* pos_enc  = (const float*)d_in[5];
  const float* ln1_w    = (const float*)d_in[6];
  const float* ln1_b    = (const float*)d_in[7];
  const float* q_w      = (const float*)d_in[8];
  const float* q_b      = (const float*)d_in[9];
  const float* k_w      = (const float*)d_in[10];
  const float* k_b      = (const float*)d_in[11];
  const float* v_w      = (const float*)d_in[12];
  const float* v_b      = (const float*)d_in[13];
  const float* lq_down  = (const float*)d_in[14];
  const float* lq_up    = (const float*)d_in[15];
  const float* lk_down  = (const float*)d_in[16];
  const float* lk_up    = (const float*)d_in[17];
  const float* lv_down  = (const float*)d_in[18];
  const float* lv_up    = (const float*)d_in[19];
  const float* o_w      = (const float*)d_in[20];
  const float* o_b      = (const float*)d_in[21];
  const float* ln2_w    = (const float*)d_in[22];
  const float* ln2_b    = (const float*)d_in[23];
  const float* ff1_w    = (const float*)d_in[24];
  const float* ff1_b    = (const float*)d_in[25];
  const float* ff2_w    = (const float*)d_in[26];
  const float* ff2_b    = (const float*)d_in[27];
  const float* norm_w   = (const float*)d_in[28];
  const float* norm_b   = (const float*)d_in[29];
  float* out = (float*)d_out;

  // workspace carve (~148.1 MiB)
  char* p = (char*)d_ws;
  float* h  = (float*)p;  p += (size_t)MROWS * 512 * 4;       // 32 MB
  u16t*  y  = (u16t*)p;   p += (size_t)MROWS * 512 * 2;       // 16 MB
  char* uni = p;          p += (size_t)4 * MROWS * 512 * 2;   // 64 MB union
  u16t* qkvb = (u16t*)uni;                                    // [M,1536] (48 MB)
  u16t* ab = (u16t*)(uni + (size_t)MROWS * 1536 * 2);         // [M,512]  (16 MB)
  u16t* g  = (u16t*)uni;                                      // [M,2048] aliases qkv+ab
  float* pe = (float*)uni;                                    // [M,512] fp32 (pre-LN patch)
  u16t* pt = (u16t*)(uni + (size_t)MROWS * 512 * 4);          // [M,128] after pe
  u16t* wqkv = (u16t*)p; p += (size_t)NLAYER * 1536 * 512 * 2;
  u16t* wo = (u16t*)p; p += (size_t)NLAYER * 512 * 512 * 2;
  u16t* w1 = (u16t*)p; p += (size_t)NLAYER * 512 * 2048 * 2;
  u16t* w2 = (u16t*)p; p += (size_t)NLAYER * 2048 * 512 * 2;
  u16t* wp = (u16t*)p; p += (size_t)512 * 128 * 2;
  if ((size_t)(p - (char*)d_ws) > ws_size) return;

  const dim3 blk(256);
  const size_t QKVS = (size_t)1536 * 512;
  k_prep_w<<<dim3(16, 16, NLAYER), blk, 0, stream>>>(q_w, lq_down, lq_up, wqkv, 512, 512, QKVS, 0);
  k_prep_w<<<dim3(16, 16, NLAYER), blk, 0, stream>>>(k_w, lk_down, lk_up, wqkv, 512, 512, QKVS, 512);
  k_prep_w<<<dim3(16, 16, NLAYER), blk, 0, stream>>>(v_w, lv_down, lv_up, wqkv, 512, 512, QKVS, 1024);
  k_prep_w<<<dim3(16, 16, NLAYER), blk, 0, stream>>>(o_w, nullptr, nullptr, wo, 512, 512, (size_t)512 * 512, 0);
  k_prep_w<<<dim3(16, 64, NLAYER), blk, 0, stream>>>(ff1_w, nullptr, nullptr, w1, 512, 2048, (size_t)512 * 2048, 0);
  k_prep_w<<<dim3(64, 16, NLAYER), blk, 0, stream>>>(ff2_w, nullptr, nullptr, w2, 2048, 512, (size_t)2048 * 512, 0);
  k_prep_w<<<dim3(4, 16, 1),       blk, 0, stream>>>(patch_w, nullptr, nullptr, wp, 128, 512, 0, 0);

  k_patch<<<dim3(MROWS * 128 / 256), blk, 0, stream>>>(x, pt);
  // 128^2 kernel: (MROWS/128)*(N/128) blocks; 256x128 kernel: (MROWS/256)*(N/128)
  k_gemm<<<dim3(128 * 4), blk, 0, stream>>>(pt, wp, patch_b, nullptr, nullptr, pe, nullptr, MROWS, 512, 128, 3);
  k_ln_pos<<<dim3(MROWS / 4), blk, 0, stream>>>(pe, patch_ln_w, patch_ln_b, pos_enc, h);

  for (int i = 0; i < NLAYER; ++i) {
    const size_t ws512 = (size_t)i * 512 * 512, wsff = (size_t)i * 512 * 2048;
    k_ln<<<dim3(MROWS / 4), blk, 0, stream>>>(h, ln1_w + i * 512, ln1_b + i * 512, y);
    k_gemm<<<dim3(128 * 12), blk, 0, stream>>>(y, wqkv + i * QKVS, q_b + i * 512, k_b + i * 512,
                                               v_b + i * 512, nullptr, qkvb, MROWS, 1536, 512, 0);
    k_attn<<<dim3(1024), blk, 0, stream>>>(qkvb, ab);
    k_gemm<<<dim3(128 * 4), blk, 0, stream>>>(ab, wo + ws512, o_b + i * 512, nullptr, nullptr, h, nullptr, MROWS, 512, 512, 2);
    k_ln<<<dim3(MROWS / 4), blk, 0, stream>>>(h, ln2_w + i * 512, ln2_b + i * 512, y);
    k_gemmw<<<dim3(64 * 16), blk, 0, stream>>>(y, w1 + wsff, ff1_b + i * 2048, nullptr, nullptr, nullptr, g, MROWS, 2048, 512, 1);
    k_gemm<<<dim3(128 * 4), blk, 0, stream>>>(g, w2 + wsff, ff2_b + i * 512, nullptr, nullptr, h, nullptr, MROWS, 512, 2048, 2);
  }
  k_ln<<<dim3(MROWS / 4), blk, 0, stream>>>(h, norm_w, norm_b, y);
  k_mean<<<dim3(BATCH), dim3(512), 0, stream>>>(y, out);
}

// Round 6
// 1452.193 us; speedup vs baseline: 1.1264x; 1.0114x over previous
//
#include <hip/hip_runtime.h>
#include <cstdint>
#include <cstddef>

// ---------------- constants ----------------
constexpr int BATCH = 64, SEQ = 4096, FEAT = 8, PLEN = 16;
constexpr int DMODEL = 512, NHEAD = 8, NLAYER = 6, DFF = 2048;
constexpr int NPATCH = 256, MROWS = BATCH * NPATCH;   // 16384
constexpr int DK = 64;
constexpr int LDSP = 72;   // padded LDS row stride (u16) for attn tiles

typedef unsigned short u16t;
typedef __bf16 bf16t;
typedef bf16t bf16x8 __attribute__((ext_vector_type(8)));
typedef short s16x4 __attribute__((ext_vector_type(4)));
typedef float f32x4 __attribute__((ext_vector_type(4)));

__device__ __forceinline__ float b2f(u16t u) {
  union { unsigned int ui; float f; } v; v.ui = ((unsigned int)u) << 16; return v.f;
}
__device__ __forceinline__ u16t f2b(float f) {
  union { float f; unsigned int ui; } v; v.f = f;
  return (u16t)((v.ui + 0x7fffu + ((v.ui >> 16) & 1u)) >> 16);
}
__device__ __forceinline__ void g2l16(void* lds, const void* g) {
  __builtin_amdgcn_global_load_lds(
      (__attribute__((address_space(1))) void*)g,
      (__attribute__((address_space(3))) void*)lds, 16, 0, 0);
}

// exact-erf GELU via Abramowitz-Stegun 7.1.26 (|erf err| < 1.5e-7).
__device__ __forceinline__ float gelu_erf(float x) {
  const float z = fabsf(x) * 0.70710678118654752f;
  const float t = __builtin_amdgcn_rcpf(__builtin_fmaf(0.3275911f, z, 1.0f));
  float p = __builtin_fmaf(1.061405429f, t, -1.453152027f);
  p = __builtin_fmaf(p, t, 1.421413741f);
  p = __builtin_fmaf(p, t, -0.284496736f);
  p = __builtin_fmaf(p, t, 0.254829592f);
  const float e = __expf(-z * z);
  const float er = __builtin_fmaf(-p * t, e, 1.0f);   // erf(|z|)
  const float s = copysignf(er, x);
  return 0.5f * x * (1.0f + s);
}

// ---------------- packed-weight layout (R15) --------------------------------
// PW[(nb*(K/32) + kt)*4096 + c*512 + (rl*4 + (seg^((rl>>1)&3)))*8 + intra]
//  = W^T[n = nb*128 + c*16 + rl][k = kt*32 + seg*8 + intra]     (u16 units)
// i.e. for each (128-row N-block, 32-col K-tile): one contiguous 8KB blob in
// EXACTLY the order the wave's lanes stage it (XOR swizzle baked in).  B
// staging thus reads contiguous 1KB per g2l16 (8x128B line requests) instead
// of 16 scattered 64B rows -> halves VMEM request count for the B side.
// LDS contents after staging are byte-identical to the old path.

// ---------------- R13 GEMM: 128x128 tile, 3 blocks/CU --------------------
// Routed to QKV (1536 blk = 2.0 rounds @3/CU), O/FF2/patch (512 blk).
// Ring-3 x 16KB, counted vmcnt(4), 1 barrier/K-tile.  B operand PACKED.
// mode 0: Cb = bf16(acc+bias)        mode 1: Cb = bf16(gelu(acc+bias))
// mode 2: Cf += acc+bias (residual)  mode 3: Cf  = acc+bias
__global__ __launch_bounds__(256, 3) void k_gemm(
    const u16t* __restrict__ A, const u16t* __restrict__ Bt,
    const float* __restrict__ bias, const float* __restrict__ b2,
    const float* __restrict__ b3, float* __restrict__ Cf,
    u16t* __restrict__ Cb, int M, int N, int K, int mode)
{
  __shared__ __align__(16) u16t SH[3 * 8192];   // 48 KiB ring; epilogue reuses

  const int nbn = N >> 7;                       // N / 128
  const int cpx = gridDim.x >> 3;
  const int wgid = (blockIdx.x & 7) * cpx + (blockIdx.x >> 3);
  const int bm = (wgid / nbn) << 7;             // 128-row tile
  const int bn = (wgid % nbn) << 7;             // 128-col tile

  const int tid = threadIdx.x, wave = tid >> 6, lane = tid & 63;
  const int lr = lane & 15, quad = lane >> 4;
  const int wm = (wave >> 1) << 6;              // 0 / 64
  const int wn = (wave & 1) << 6;               // 0 / 64

  const int sseg = (lane & 3) ^ ((lane >> 3) & 3);
  const u16t* gA = A + (size_t)(bm + (lane >> 2)) * K + sseg * 8;
  // packed B: per K-tile one contiguous 8KB blob
  const u16t* gBp = Bt + ((size_t)(bn >> 7) * (K >> 5)) * 4096 + (size_t)lane * 8;

  const int sw8 = (quad ^ ((lr >> 1) & 3)) << 3;
  const int aoff = (wm + lr) * 32 + sw8;          // + i*512 per M-frag
  const int boff = 4096 + (wn + lr) * 32 + sw8;   // + j*512 per N-frag

  f32x4 acc[4][4] = {};

  u16t* buf0 = SH;
  u16t* buf1 = SH + 8192;
  u16t* buf2 = SH + 16384;

#define STAGE(BUF_, S_) do {                                                   \
    g2l16((BUF_) + wave * 512,        gA + (size_t)(wave * 16) * K + (S_) * 32);   \
    g2l16((BUF_) + (wave + 4) * 512,  gA + (size_t)((wave + 4) * 16) * K + (S_) * 32); \
    g2l16((BUF_) + 4096 + wave * 512,       gBp + (size_t)(S_) * 4096 + wave * 512);   \
    g2l16((BUF_) + 4096 + (wave + 4) * 512, gBp + (size_t)(S_) * 4096 + (wave + 4) * 512); \
  } while (0)

  const int nt = K >> 5;
  STAGE(buf0, 0);
  STAGE(buf1, 1);

  for (int t = 0; t < nt - 1; ++t) {
    asm volatile("s_waitcnt vmcnt(4)" ::: "memory");
    __builtin_amdgcn_s_barrier();
    asm volatile("" ::: "memory");
    if (t + 2 < nt) STAGE(buf2, t + 2);
    bf16x8 af[4], bfr[4];
    #pragma unroll
    for (int i = 0; i < 4; ++i) af[i] = *(const bf16x8*)&buf0[aoff + i * 512];
    #pragma unroll
    for (int j = 0; j < 4; ++j) bfr[j] = *(const bf16x8*)&buf0[boff + j * 512];
    __builtin_amdgcn_s_setprio(1);
    #pragma unroll
    for (int j = 0; j < 4; ++j)
      #pragma unroll
      for (int i = 0; i < 4; ++i)
        acc[j][i] = __builtin_amdgcn_mfma_f32_16x16x32_bf16(bfr[j], af[i], acc[j][i], 0, 0, 0);
    __builtin_amdgcn_s_setprio(0);
    u16t* tmp = buf0; buf0 = buf1; buf1 = buf2; buf2 = tmp;
  }
  {
    asm volatile("s_waitcnt vmcnt(0)" ::: "memory");
    __builtin_amdgcn_s_barrier();
    asm volatile("" ::: "memory");
    bf16x8 af[4], bfr[4];
    #pragma unroll
    for (int i = 0; i < 4; ++i) af[i] = *(const bf16x8*)&buf0[aoff + i * 512];
    #pragma unroll
    for (int j = 0; j < 4; ++j) bfr[j] = *(const bf16x8*)&buf0[boff + j * 512];
    __builtin_amdgcn_s_setprio(1);
    #pragma unroll
    for (int j = 0; j < 4; ++j)
      #pragma unroll
      for (int i = 0; i < 4; ++i)
        acc[j][i] = __builtin_amdgcn_mfma_f32_16x16x32_bf16(bfr[j], af[i], acc[j][i], 0, 0, 0);
    __builtin_amdgcn_s_setprio(0);
  }
#undef STAGE

  const float* bp = bias;
  int reg0 = 0;
  if (bias && b2) { reg0 = (bn >> 9) << 9; bp = reg0 == 0 ? bias : (reg0 == 512 ? b2 : b3); }
  float4 bv[4];
  #pragma unroll
  for (int jN = 0; jN < 4; ++jN) {
    const int gn0 = bn + wn + jN * 16 + quad * 4;
    bv[jN] = bias ? *(const float4*)&bp[gn0 - reg0] : make_float4(0.f, 0.f, 0.f, 0.f);
  }

  if (mode <= 1) {
    __syncthreads();
    u16t* E = SH;      // [128][128] u16 (32KB), seg-swizzled
    #pragma unroll
    for (int jN = 0; jN < 4; ++jN) {
      const int cl = wn + jN * 16 + quad * 4;
      const int seg = cl >> 3, intra = cl & 7;
      #pragma unroll
      for (int iM = 0; iM < 4; ++iM) {
        const int r = wm + iM * 16 + lr;
        float v0 = acc[jN][iM][0] + bv[jN].x, v1 = acc[jN][iM][1] + bv[jN].y;
        float v2 = acc[jN][iM][2] + bv[jN].z, v3 = acc[jN][iM][3] + bv[jN].w;
        union { u16t h[4]; uint2 u; } pk;
        if (mode == 1) {
          pk.h[0] = f2b(gelu_erf(v0)); pk.h[1] = f2b(gelu_erf(v1));
          pk.h[2] = f2b(gelu_erf(v2)); pk.h[3] = f2b(gelu_erf(v3));
        } else {
          pk.h[0] = f2b(v0); pk.h[1] = f2b(v1); pk.h[2] = f2b(v2); pk.h[3] = f2b(v3);
        }
        *(uint2*)&E[r * 128 + ((seg ^ (r & 7)) << 3) + intra] = pk.u;
      }
    }
    __syncthreads();
    const int rr = tid >> 2, s0 = tid & 3;
    #pragma unroll
    for (int pass = 0; pass < 2; ++pass) {
      const int r = pass * 64 + rr;
      u16t* gout = Cb + (size_t)(bm + r) * N + bn;
      #pragma unroll
      for (int it = 0; it < 4; ++it) {
        const int s = s0 + it * 4;
        uint4 u = *(const uint4*)&E[r * 128 + ((s ^ (r & 7)) << 3)];
        *(uint4*)(gout + s * 8) = u;
      }
    }
  } else {
    #pragma unroll
    for (int jN = 0; jN < 4; ++jN) {
      const int gn0 = bn + wn + jN * 16 + quad * 4;
      #pragma unroll
      for (int iM = 0; iM < 4; ++iM) {
        const int gm = bm + wm + iM * 16 + lr;
        const size_t off = (size_t)gm * N + gn0;
        float v0 = acc[jN][iM][0] + bv[jN].x, v1 = acc[jN][iM][1] + bv[jN].y;
        float v2 = acc[jN][iM][2] + bv[jN].z, v3 = acc[jN][iM][3] + bv[jN].w;
        if (mode == 2) {
          float4 c = *(float4*)(Cf + off);
          c.x += v0; c.y += v1; c.z += v2; c.w += v3;
          *(float4*)(Cf + off) = c;
        } else {
          *(float4*)(Cf + off) = make_float4(v0, v1, v2, v3);
        }
      }
    }
  }
}

// ---------------- R10 GEMM: 256x128 tile, 2 blocks/CU (FF1 route) ----------
// 1024 blocks = exactly 2.0 rounds @2/CU.  B operand PACKED.
__global__ __launch_bounds__(256, 2) void k_gemmw(
    const u16t* __restrict__ A, const u16t* __restrict__ Bt,
    const float* __restrict__ bias, const float* __restrict__ b2,
    const float* __restrict__ b3, float* __restrict__ Cf,
    u16t* __restrict__ Cb, int M, int N, int K, int mode)
{
  __shared__ __align__(16) u16t SH[3 * 12288];   // 72 KiB ring; epilogue reuses

  const int nbn = N >> 7;                       // N / 128
  const int cpx = gridDim.x >> 3;
  const int wgid = (blockIdx.x & 7) * cpx + (blockIdx.x >> 3);
  const int bm = (wgid / nbn) << 8;             // 256-row tile
  const int bn = (wgid % nbn) << 7;             // 128-col tile

  const int tid = threadIdx.x, wave = tid >> 6, lane = tid & 63;
  const int lr = lane & 15, quad = lane >> 4;
  const int wm = (wave >> 1) << 7;              // 0 / 128
  const int wn = (wave & 1) << 6;               // 0 / 64

  const int sseg = (lane & 3) ^ ((lane >> 3) & 3);
  const u16t* gA = A + (size_t)(bm + (lane >> 2)) * K + sseg * 8;
  const u16t* gBp = Bt + ((size_t)(bn >> 7) * (K >> 5)) * 4096 + (size_t)lane * 8;

  const int sw8 = (quad ^ ((lr >> 1) & 3)) << 3;
  const int aoff = (wm + lr) * 32 + sw8;          // + i*512 per M-frag
  const int boff = 8192 + (wn + lr) * 32 + sw8;   // + j*512 per N-frag

  f32x4 acc[4][8] = {};   // [jN][iM]

  u16t* buf0 = SH;
  u16t* buf1 = SH + 12288;
  u16t* buf2 = SH + 24576;

#define STAGE_W(BUF_, S_) do {                                                 \
    g2l16((BUF_) + wave * 512,        gA + (size_t)(wave * 16) * K + (S_) * 32);   \
    g2l16((BUF_) + (wave + 4) * 512,  gA + (size_t)((wave + 4) * 16) * K + (S_) * 32); \
    g2l16((BUF_) + (wave + 8) * 512,  gA + (size_t)((wave + 8) * 16) * K + (S_) * 32); \
    g2l16((BUF_) + (wave + 12) * 512, gA + (size_t)((wave + 12) * 16) * K + (S_) * 32); \
    g2l16((BUF_) + 8192 + wave * 512,       gBp + (size_t)(S_) * 4096 + wave * 512);   \
    g2l16((BUF_) + 8192 + (wave + 4) * 512, gBp + (size_t)(S_) * 4096 + (wave + 4) * 512); \
  } while (0)

  const int nt = K >> 5;
  STAGE_W(buf0, 0);
  STAGE_W(buf1, 1);

  for (int t = 0; t < nt - 1; ++t) {
    asm volatile("s_waitcnt vmcnt(6)" ::: "memory");
    __builtin_amdgcn_s_barrier();
    asm volatile("" ::: "memory");
    if (t + 2 < nt) STAGE_W(buf2, t + 2);
    bf16x8 af[8], bfr[4];
    #pragma unroll
    for (int i = 0; i < 8; ++i) af[i] = *(const bf16x8*)&buf0[aoff + i * 512];
    #pragma unroll
    for (int j = 0; j < 4; ++j) bfr[j] = *(const bf16x8*)&buf0[boff + j * 512];
    __builtin_amdgcn_s_setprio(1);
    #pragma unroll
    for (int j = 0; j < 4; ++j)
      #pragma unroll
      for (int i = 0; i < 8; ++i)
        acc[j][i] = __builtin_amdgcn_mfma_f32_16x16x32_bf16(bfr[j], af[i], acc[j][i], 0, 0, 0);
    __builtin_amdgcn_s_setprio(0);
    u16t* tmp = buf0; buf0 = buf1; buf1 = buf2; buf2 = tmp;
  }
  {
    asm volatile("s_waitcnt vmcnt(0)" ::: "memory");
    __builtin_amdgcn_s_barrier();
    asm volatile("" ::: "memory");
    bf16x8 af[8], bfr[4];
    #pragma unroll
    for (int i = 0; i < 8; ++i) af[i] = *(const bf16x8*)&buf0[aoff + i * 512];
    #pragma unroll
    for (int j = 0; j < 4; ++j) bfr[j] = *(const bf16x8*)&buf0[boff + j * 512];
    __builtin_amdgcn_s_setprio(1);
    #pragma unroll
    for (int j = 0; j < 4; ++j)
      #pragma unroll
      for (int i = 0; i < 8; ++i)
        acc[j][i] = __builtin_amdgcn_mfma_f32_16x16x32_bf16(bfr[j], af[i], acc[j][i], 0, 0, 0);
    __builtin_amdgcn_s_setprio(0);
  }
#undef STAGE_W

  const float* bp = bias;
  int reg0 = 0;
  if (bias && b2) { reg0 = (bn >> 9) << 9; bp = reg0 == 0 ? bias : (reg0 == 512 ? b2 : b3); }
  float4 bv[4];
  #pragma unroll
  for (int jN = 0; jN < 4; ++jN) {
    const int gn0 = bn + wn + jN * 16 + quad * 4;
    bv[jN] = bias ? *(const float4*)&bp[gn0 - reg0] : make_float4(0.f, 0.f, 0.f, 0.f);
  }

  if (mode <= 1) {
    __syncthreads();
    u16t* E = SH;
    #pragma unroll
    for (int jN = 0; jN < 4; ++jN) {
      const int cl = wn + jN * 16 + quad * 4;
      const int seg = cl >> 3, intra = cl & 7;
      #pragma unroll
      for (int iM = 0; iM < 8; ++iM) {
        const int r = wm + iM * 16 + lr;
        float v0 = acc[jN][iM][0] + bv[jN].x, v1 = acc[jN][iM][1] + bv[jN].y;
        float v2 = acc[jN][iM][2] + bv[jN].z, v3 = acc[jN][iM][3] + bv[jN].w;
        union { u16t h[4]; uint2 u; } pk;
        if (mode == 1) {
          pk.h[0] = f2b(gelu_erf(v0)); pk.h[1] = f2b(gelu_erf(v1));
          pk.h[2] = f2b(gelu_erf(v2)); pk.h[3] = f2b(gelu_erf(v3));
        } else {
          pk.h[0] = f2b(v0); pk.h[1] = f2b(v1); pk.h[2] = f2b(v2); pk.h[3] = f2b(v3);
        }
        *(uint2*)&E[r * 128 + ((seg ^ (r & 7)) << 3) + intra] = pk.u;
      }
    }
    __syncthreads();
    const int rr = tid >> 2, s0 = tid & 3;
    #pragma unroll
    for (int pass = 0; pass < 4; ++pass) {
      const int r = pass * 64 + rr;
      u16t* gout = Cb + (size_t)(bm + r) * N + bn;
      #pragma unroll
      for (int it = 0; it < 4; ++it) {
        const int s = s0 + it * 4;
        uint4 u = *(const uint4*)&E[r * 128 + ((s ^ (r & 7)) << 3)];
        *(uint4*)(gout + s * 8) = u;
      }
    }
  } else {
    #pragma unroll
    for (int jN = 0; jN < 4; ++jN) {
      const int gn0 = bn + wn + jN * 16 + quad * 4;
      #pragma unroll
      for (int iM = 0; iM < 8; ++iM) {
        const int gm = bm + wm + iM * 16 + lr;
        const size_t off = (size_t)gm * N + gn0;
        float v0 = acc[jN][iM][0] + bv[jN].x, v1 = acc[jN][iM][1] + bv[jN].y;
        float v2 = acc[jN][iM][2] + bv[jN].z, v3 = acc[jN][iM][3] + bv[jN].w;
        if (mode == 2) {
          float4 c = *(float4*)(Cf + off);
          c.x += v0; c.y += v1; c.z += v2; c.w += v3;
          *(float4*)(Cf + off) = c;
        } else {
          *(float4*)(Cf + off) = make_float4(v0, v1, v2, v3);
        }
      }
    }
  }
}

// ---------------- weight prep: packed layout (see header comment) -----------
// PW[(nb*(K/32)+kt)*4096 + c*512 + (rl*4 + (seg^((rl>>1)&3)))*8 + intra]
//  = (W[k][n] + 2*down@up),  n = orow0 + n0 + i,  k = k0 + tx.
__global__ __launch_bounds__(256) void k_prep_w(
    const float* __restrict__ W, const float* __restrict__ down,
    const float* __restrict__ up, u16t* __restrict__ Wt, int K, int N,
    size_t ostride, int orow0)
{
  __shared__ float t[32][33];
  const int z = blockIdx.z;
  const float* Wz = W + (size_t)z * K * N;
  u16t* Wtz = Wt + (size_t)z * ostride;
  const int k0 = blockIdx.x * 32, n0 = blockIdx.y * 32;
  const int tx = threadIdx.x & 31, ty = threadIdx.x >> 5;
  for (int i = ty; i < 32; i += 8) {
    const int kk = k0 + i, nn = n0 + tx;
    float v = Wz[(size_t)kk * N + nn];
    if (down) {
      const float* dz = down + (size_t)z * K * 8 + (size_t)kk * 8;
      const float* uz = up + (size_t)z * 8 * N + nn;
      float lv = 0.f;
      #pragma unroll
      for (int r = 0; r < 8; ++r) lv += dz[r] * uz[(size_t)r * N];
      v += 2.0f * lv;   // LORA_SCALING
    }
    t[i][tx] = v;
  }
  __syncthreads();
  const int kt = k0 >> 5, seg = tx >> 3, intra = tx & 7;
  for (int i = ty; i < 32; i += 8) {
    const int n_g = orow0 + n0 + i;
    const int nb = n_g >> 7, cc = (n_g >> 4) & 7, rl = n_g & 15;
    Wtz[(((size_t)nb * (K >> 5) + kt) * 8 + cc) * 512 +
        (rl * 4 + (seg ^ ((rl >> 1) & 3))) * 8 + intra] = f2b(t[tx][i]);
  }
}

// ---------------- patch gather: pt[(b*256+np)*128 + f*16+p] = x[b, np*16+p, f]
__global__ void k_patch(const float* __restrict__ x, u16t* __restrict__ pt) {
  const int idx = blockIdx.x * 256 + threadIdx.x;
  const int col = idx & 127, row = idx >> 7;
  const int f = col >> 4, pp = col & 15;
  const int b = row >> 8, np = row & 255;
  pt[idx] = f2b(x[(((size_t)b << 12) + np * 16 + pp) * 8 + f]);
}

// ---------------- LayerNorm (one wave per 512-row) -> bf16 ----------------
__global__ __launch_bounds__(256) void k_ln(
    const float* __restrict__ xin, const float* __restrict__ w,
    const float* __restrict__ bb, u16t* __restrict__ y)
{
  const int row = blockIdx.x * 4 + (threadIdx.x >> 6);
  const int lane = threadIdx.x & 63;
  const float4* xr = (const float4*)(xin + (size_t)row * 512);
  float4 a = xr[lane * 2], c = xr[lane * 2 + 1];
  float s = a.x + a.y + a.z + a.w + c.x + c.y + c.z + c.w;
  float qq = a.x * a.x + a.y * a.y + a.z * a.z + a.w * a.w +
             c.x * c.x + c.y * c.y + c.z * c.z + c.w * c.w;
  #pragma unroll
  for (int o = 32; o > 0; o >>= 1) { s += __shfl_xor(s, o); qq += __shfl_xor(qq, o); }
  const float mean = s * (1.f / 512.f);
  const float rs = rsqrtf(qq * (1.f / 512.f) - mean * mean + 1e-5f);
  const float4* wr = (const float4*)w; const float4* br = (const float4*)bb;
  float4 w0 = wr[lane * 2], w1 = wr[lane * 2 + 1];
  float4 b0 = br[lane * 2], b1 = br[lane * 2 + 1];
  union { u16t h[8]; uint4 v; } pk;
  pk.h[0] = f2b((a.x - mean) * rs * w0.x + b0.x);
  pk.h[1] = f2b((a.y - mean) * rs * w0.y + b0.y);
  pk.h[2] = f2b((a.z - mean) * rs * w0.z + b0.z);
  pk.h[3] = f2b((a.w - mean) * rs * w0.w + b0.w);
  pk.h[4] = f2b((c.x - mean) * rs * w1.x + b1.x);
  pk.h[5] = f2b((c.y - mean) * rs * w1.y + b1.y);
  pk.h[6] = f2b((c.z - mean) * rs * w1.z + b1.z);
  pk.h[7] = f2b((c.w - mean) * rs * w1.w + b1.w);
  *(uint4*)(y + (size_t)row * 512 + lane * 8) = pk.v;
}

// ---------------- patch LN + pos_enc -> h (fp32) ----------------
__global__ __launch_bounds__(256) void k_ln_pos(
    const float* __restrict__ xin, const float* __restrict__ w,
    const float* __restrict__ bb, const float* __restrict__ pos,
    float* __restrict__ h)
{
  const int row = blockIdx.x * 4 + (threadIdx.x >> 6);
  const int lane = threadIdx.x & 63;
  const float4* xr = (const float4*)(xin + (size_t)row * 512);
  float4 a = xr[lane * 2], c = xr[lane * 2 + 1];
  float s = a.x + a.y + a.z + a.w + c.x + c.y + c.z + c.w;
  float qq = a.x * a.x + a.y * a.y + a.z * a.z + a.w * a.w +
             c.x * c.x + c.y * c.y + c.z * c.z + c.w * c.w;
  #pragma unroll
  for (int o = 32; o > 0; o >>= 1) { s += __shfl_xor(s, o); qq += __shfl_xor(qq, o); }
  const float mean = s * (1.f / 512.f);
  const float rs = rsqrtf(qq * (1.f / 512.f) - mean * mean + 1e-5f);
  const float4* wr = (const float4*)w; const float4* br = (const float4*)bb;
  float4 w0 = wr[lane * 2], w1 = wr[lane * 2 + 1];
  float4 b0 = br[lane * 2], b1 = br[lane * 2 + 1];
  const int np = row & 255;
  const float4* pr = (const float4*)(pos + (size_t)np * 512);
  float4 p0 = pr[lane * 2], p1 = pr[lane * 2 + 1];
  float4 o0, o1;
  o0.x = (a.x - mean) * rs * w0.x + b0.x + p0.x;
  o0.y = (a.y - mean) * rs * w0.y + b0.y + p0.y;
  o0.z = (a.z - mean) * rs * w0.z + b0.z + p0.z;
  o0.w = (a.w - mean) * rs * w0.w + b0.w + p0.w;
  o1.x = (c.x - mean) * rs * w1.x + b1.x + p1.x;
  o1.y = (c.y - mean) * rs * w1.y + b1.y + p1.y;
  o1.z = (c.z - mean) * rs * w1.z + b1.z + p1.z;
  o1.w = (c.w - mean) * rs * w1.w + b1.w + p1.w;
  float4* hr = (float4*)(h + (size_t)row * 512);
  hr[lane * 2] = o0; hr[lane * 2 + 1] = o1;
}

// ---------------- MFMA flash attention -------------------------------------
__global__ __launch_bounds__(256) void k_attn(
    const u16t* __restrict__ qkv, u16t* __restrict__ out)
{
  __shared__ __align__(16) u16t Qs[128 * LDSP];
  __shared__ __align__(16) u16t Ks[64 * LDSP];
  __shared__ __align__(16) u16t Vts[64 * LDSP];

  const int bh = blockIdx.x >> 1, half = blockIdx.x & 1;
  const int b = bh >> 3, hd = bh & 7;
  const int tid = threadIdx.x, wave = tid >> 6, lane = tid & 63;
  const int lr = lane & 15, quad = lane >> 4;

  const size_t rowbase = (size_t)b * 256;
  const u16t* qg = qkv + (rowbase + half * 128) * 1536 + hd * 64;
  const u16t* kg = qkv + rowbase * 1536 + 512 + hd * 64;
  const u16t* vg = qkv + rowbase * 1536 + 1024 + hd * 64;

  #pragma unroll
  for (int i = 0; i < 4; ++i) {
    const int idx = tid + i * 256, row = idx >> 3, seg = idx & 7;
    uint4 u = *(const uint4*)(qg + (size_t)row * 1536 + seg * 8);
    *(uint4*)&Qs[row * LDSP + seg * 8] = u;
  }
  __syncthreads();

  bf16x8 qf[2][2];
  #pragma unroll
  for (int qi = 0; qi < 2; ++qi)
    #pragma unroll
    for (int dh = 0; dh < 2; ++dh)
      qf[qi][dh] = *(const bf16x8*)&Qs[(wave * 32 + qi * 16 + lr) * LDSP + dh * 32 + quad * 8];

  f32x4 O[2][4] = {};
  float mrun[2] = {-1e30f, -1e30f}, lrun[2] = {0.f, 0.f};

  for (int c = 0; c < 4; ++c) {
    __syncthreads();
    #pragma unroll
    for (int i = 0; i < 2; ++i) {
      const int idx = tid + i * 256, row = idx >> 3, seg = idx & 7;
      uint4 u = *(const uint4*)(kg + (size_t)(c * 64 + row) * 1536 + seg * 8);
      *(uint4*)&Ks[row * LDSP + seg * 8] = u;
    }
    {
      const int key = tid & 63, dg = (tid >> 6) * 16;
      const u16t* vrow = vg + (size_t)(c * 64 + key) * 1536 + dg;
      union { u16t h[16]; uint4 v[2]; } tmp;
      tmp.v[0] = *(const uint4*)(vrow);
      tmp.v[1] = *(const uint4*)(vrow + 8);
      #pragma unroll
      for (int i = 0; i < 16; ++i)
        Vts[(dg + i) * LDSP + key] = tmp.h[i];
    }
    __syncthreads();

    #pragma unroll
    for (int qi = 0; qi < 2; ++qi) {
      f32x4 s[4];
      #pragma unroll
      for (int kt = 0; kt < 4; ++kt) {
        f32x4 a = {};
        #pragma unroll
        for (int dh = 0; dh < 2; ++dh) {
          bf16x8 kf = *(const bf16x8*)&Ks[(kt * 16 + lr) * LDSP + dh * 32 + quad * 8];
          a = __builtin_amdgcn_mfma_f32_16x16x32_bf16(kf, qf[qi][dh], a, 0, 0, 0);
        }
        s[kt] = a;
      }
      constexpr float SC = 0.125f * 1.44269504088896f;
      float cmax = -1e30f;
      #pragma unroll
      for (int kt = 0; kt < 4; ++kt)
        #pragma unroll
        for (int r = 0; r < 4; ++r) { s[kt][r] *= SC; cmax = fmaxf(cmax, s[kt][r]); }
      cmax = fmaxf(cmax, __shfl_xor(cmax, 16));
      cmax = fmaxf(cmax, __shfl_xor(cmax, 32));
      const float mn = fmaxf(mrun[qi], cmax);
      const float alpha = exp2f(mrun[qi] - mn);
      mrun[qi] = mn;
      float lsum = 0.f;
      s16x4 pf[4];
      #pragma unroll
      for (int kt = 0; kt < 4; ++kt) {
        #pragma unroll
        for (int r = 0; r < 4; ++r) {
          const u16t eb = f2b(exp2f(s[kt][r] - mn));
          pf[kt][r] = (short)eb;
          lsum += b2f(eb);
        }
      }
      lsum += __shfl_xor(lsum, 16);
      lsum += __shfl_xor(lsum, 32);
      lrun[qi] = lrun[qi] * alpha + lsum;
      #pragma unroll
      for (int dt = 0; dt < 4; ++dt) {
        f32x4 o = O[qi][dt];
        o[0] *= alpha; o[1] *= alpha; o[2] *= alpha; o[3] *= alpha;
        #pragma unroll
        for (int kt = 0; kt < 4; ++kt) {
          s16x4 vf = *(const s16x4*)&Vts[(dt * 16 + lr) * LDSP + kt * 16 + quad * 4];
          o = __builtin_amdgcn_mfma_f32_16x16x16bf16_1k(vf, pf[kt], o, 0, 0, 0);
        }
        O[qi][dt] = o;
      }
    }
  }
  #pragma unroll
  for (int qi = 0; qi < 2; ++qi) {
    const float rl = 1.f / lrun[qi];
    u16t* orow = out + (rowbase + half * 128 + wave * 32 + qi * 16 + lr) * 512 + hd * 64 + quad * 4;
    #pragma unroll
    for (int dt = 0; dt < 4; ++dt) {
      union { u16t h[4]; uint2 v; } pk;
      #pragma unroll
      for (int r = 0; r < 4; ++r) pk.h[r] = f2b(O[qi][dt][r] * rl);
      *(uint2*)(orow + dt * 16) = pk.v;
    }
  }
}

// ---------------- final mean over patches ----------------
__global__ void k_mean(const u16t* __restrict__ y, float* __restrict__ out) {
  const int b = blockIdx.x, d = threadIdx.x;   // 64 x 512
  float s = 0.f;
  #pragma unroll 8
  for (int np = 0; np < 256; ++np) s += b2f(y[((size_t)b * 256 + np) * 512 + d]);
  out[(size_t)b * 512 + d] = s * (1.f / 256.f);
}

// ---------------- host ----------------
extern "C" void kernel_launch(void* const* d_in, const int* in_sizes, int n_in,
                              void* d_out, int out_size, void* d_ws, size_t ws_size,
                              hipStream_t stream)
{
  (void)in_sizes; (void)n_in; (void)out_size;
  const float* x        = (const float*)d_in[0];
  const float* patch_w  = (const float*)d_in[1];
  const float* patch_b  = (const float*)d_in[2];
  const float* patch_ln_w = (const float*)d_in[3];
  const float* patch_ln_b = (const float*)d_in[4];
  const float* pos_enc  = (const float*)d_in[5];
  const float* ln1_w    = (const float*)d_in[6];
  const float* ln1_b    = (const float*)d_in[7];
  const float* q_w      = (const float*)d_in[8];
  const float* q_b      = (const float*)d_in[9];
  const float* k_w      = (const float*)d_in[10];
  const float* k_b      = (const float*)d_in[11];
  const float* v_w      = (const float*)d_in[12];
  const float* v_b      = (const float*)d_in[13];
  const float* lq_down  = (const float*)d_in[14];
  const float* lq_up    = (const float*)d_in[15];
  const float* lk_down  = (const float*)d_in[16];
  const float* lk_up    = (const float*)d_in[17];
  const float* lv_down  = (const float*)d_in[18];
  const float* lv_up    = (const float*)d_in[19];
  const float* o_w      = (const float*)d_in[20];
  const float* o_b      = (const float*)d_in[21];
  const float* ln2_w    = (const float*)d_in[22];
  const float* ln2_b    = (const float*)d_in[23];
  const float* ff1_w    = (const float*)d_in[24];
  const float* ff1_b    = (const float*)d_in[25];
  const float* ff2_w    = (const float*)d_in[26];
  const float* ff2_b    = (const float*)d_in[27];
  const float* norm_w   = (const float*)d_in[28];
  const float* norm_b   = (const float*)d_in[29];
  float* out = (float*)d_out;

  // workspace carve (~148.1 MiB)
  char* p = (char*)d_ws;
  float* h  = (float*)p;  p += (size_t)MROWS * 512 * 4;       // 32 MB
  u16t*  y  = (u16t*)p;   p += (size_t)MROWS * 512 * 2;       // 16 MB
  char* uni = p;          p += (size_t)4 * MROWS * 512 * 2;   // 64 MB union
  u16t* qkvb = (u16t*)uni;                                    // [M,1536] (48 MB)
  u16t* ab = (u16t*)(uni + (size_t)MROWS * 1536 * 2);         // [M,512]  (16 MB)
  u16t* g  = (u16t*)uni;                                      // [M,2048] aliases qkv+ab
  float* pe = (float*)uni;                                    // [M,512] fp32 (pre-LN patch)
  u16t* pt = (u16t*)(uni + (size_t)MROWS * 512 * 4);          // [M,128] after pe
  u16t* wqkv = (u16t*)p; p += (size_t)NLAYER * 1536 * 512 * 2;
  u16t* wo = (u16t*)p; p += (size_t)NLAYER * 512 * 512 * 2;
  u16t* w1 = (u16t*)p; p += (size_t)NLAYER * 512 * 2048 * 2;
  u16t* w2 = (u16t*)p; p += (size_t)NLAYER * 2048 * 512 * 2;
  u16t* wp = (u16t*)p; p += (size_t)512 * 128 * 2;
  if ((size_t)(p - (char*)d_ws) > ws_size) return;

  const dim3 blk(256);
  const size_t QKVS = (size_t)1536 * 512;
  k_prep_w<<<dim3(16, 16, NLAYER), blk, 0, stream>>>(q_w, lq_down, lq_up, wqkv, 512, 512, QKVS, 0);
  k_prep_w<<<dim3(16, 16, NLAYER), blk, 0, stream>>>(k_w, lk_down, lk_up, wqkv, 512, 512, QKVS, 512);
  k_prep_w<<<dim3(16, 16, NLAYER), blk, 0, stream>>>(v_w, lv_down, lv_up, wqkv, 512, 512, QKVS, 1024);
  k_prep_w<<<dim3(16, 16, NLAYER), blk, 0, stream>>>(o_w, nullptr, nullptr, wo, 512, 512, (size_t)512 * 512, 0);
  k_prep_w<<<dim3(16, 64, NLAYER), blk, 0, stream>>>(ff1_w, nullptr, nullptr, w1, 512, 2048, (size_t)512 * 2048, 0);
  k_prep_w<<<dim3(64, 16, NLAYER), blk, 0, stream>>>(ff2_w, nullptr, nullptr, w2, 2048, 512, (size_t)2048 * 512, 0);
  k_prep_w<<<dim3(4, 16, 1),       blk, 0, stream>>>(patch_w, nullptr, nullptr, wp, 128, 512, 0, 0);

  k_patch<<<dim3(MROWS * 128 / 256), blk, 0, stream>>>(x, pt);
  k_gemm<<<dim3(128 * 4), blk, 0, stream>>>(pt, wp, patch_b, nullptr, nullptr, pe, nullptr, MROWS, 512, 128, 3);
  k_ln_pos<<<dim3(MROWS / 4), blk, 0, stream>>>(pe, patch_ln_w, patch_ln_b, pos_enc, h);

  for (int i = 0; i < NLAYER; ++i) {
    const size_t ws512 = (size_t)i * 512 * 512, wsff = (size_t)i * 512 * 2048;
    k_ln<<<dim3(MROWS / 4), blk, 0, stream>>>(h, ln1_w + i * 512, ln1_b + i * 512, y);
    k_gemm<<<dim3(128 * 12), blk, 0, stream>>>(y, wqkv + i * QKVS, q_b + i * 512, k_b + i * 512,
                                               v_b + i * 512, nullptr, qkvb, MROWS, 1536, 512, 0);
    k_attn<<<dim3(1024), blk, 0, stream>>>(qkvb, ab);
    k_gemm<<<dim3(128 * 4), blk, 0, stream>>>(ab, wo + ws512, o_b + i * 512, nullptr, nullptr, h, nullptr, MROWS, 512, 512, 2);
    k_ln<<<dim3(MROWS / 4), blk, 0, stream>>>(h, ln2_w + i * 512, ln2_b + i * 512, y);
    k_gemmw<<<dim3(64 * 16), blk, 0, stream>>>(y, w1 + wsff, ff1_b + i * 2048, nullptr, nullptr, nullptr, g, MROWS, 2048, 512, 1);
    k_gemm<<<dim3(128 * 4), blk, 0, stream>>>(g, w2 + wsff, ff2_b + i * 512, nullptr, nullptr, h, nullptr, MROWS, 512, 2048, 2);
  }
  k_ln<<<dim3(MROWS / 4), blk, 0, stream>>>(h, norm_w, norm_b, y);
  k_mean<<<dim3(BATCH), dim3(512), 0, stream>>>(y, out);
}

// Round 7
// 1450.139 us; speedup vs baseline: 1.1280x; 1.0014x over previous
//
#include <hip/hip_runtime.h>
#include <cstdint>
#include <cstddef>

// ---------------- constants ----------------
constexpr int BATCH = 64, SEQ = 4096, FEAT = 8, PLEN = 16;
constexpr int DMODEL = 512, NHEAD = 8, NLAYER = 6, DFF = 2048;
constexpr int NPATCH = 256, MROWS = BATCH * NPATCH;   // 16384
constexpr int DK = 64;
constexpr int LDSP = 72;   // padded LDS row stride (u16) for attn tiles

typedef unsigned short u16t;
typedef __bf16 bf16t;
typedef bf16t bf16x8 __attribute__((ext_vector_type(8)));
typedef short s16x4 __attribute__((ext_vector_type(4)));
typedef float f32x4 __attribute__((ext_vector_type(4)));

__device__ __forceinline__ float b2f(u16t u) {
  union { unsigned int ui; float f; } v; v.ui = ((unsigned int)u) << 16; return v.f;
}
__device__ __forceinline__ u16t f2b(float f) {
  union { float f; unsigned int ui; } v; v.f = f;
  return (u16t)((v.ui + 0x7fffu + ((v.ui >> 16) & 1u)) >> 16);
}
__device__ __forceinline__ void g2l16(void* lds, const void* g) {
  __builtin_amdgcn_global_load_lds(
      (__attribute__((address_space(1))) void*)g,
      (__attribute__((address_space(3))) void*)lds, 16, 0, 0);
}

// exact-erf GELU via Abramowitz-Stegun 7.1.26 (|erf err| < 1.5e-7).
__device__ __forceinline__ float gelu_erf(float x) {
  const float z = fabsf(x) * 0.70710678118654752f;
  const float t = __builtin_amdgcn_rcpf(__builtin_fmaf(0.3275911f, z, 1.0f));
  float p = __builtin_fmaf(1.061405429f, t, -1.453152027f);
  p = __builtin_fmaf(p, t, 1.421413741f);
  p = __builtin_fmaf(p, t, -0.284496736f);
  p = __builtin_fmaf(p, t, 0.254829592f);
  const float e = __expf(-z * z);
  const float er = __builtin_fmaf(-p * t, e, 1.0f);   // erf(|z|)
  const float s = copysignf(er, x);
  return 0.5f * x * (1.0f + s);
}

// ---------------- packed-weight layout (R15/R6-verified on 128^2 kernel) ----
// PW[(nb*(K/32) + kt)*4096 + c*512 + (rl*4 + (seg^((rl>>1)&3)))*8 + intra]
//  = W^T[n = nb*128 + c*16 + rl][k = kt*32 + seg*8 + intra]     (u16 units)
// One contiguous 8KB blob per (128-row N-block, 32-col K-tile), in EXACTLY
// the order the wave's lanes stage it (XOR swizzle baked in).  B staging
// reads contiguous 1KB per g2l16 -> halves VMEM request count for B.
// R6 A/B: -15us/dispatch on the 128^2 kernel; REGRESSED the 256x128 kernel
// (60->104us, mechanism unattributed) -> k_gemmw stays on unpacked B.

// ---------------- R13 GEMM: 128x128 tile, 3 blocks/CU, packed B -------------
// Routed to QKV (1536 blk), O/FF2/patch (512 blk).  R6-verified.
// Ring-3 x 16KB, counted vmcnt(4), 1 barrier/K-tile.
// mode 0: Cb = bf16(acc+bias)        mode 1: Cb = bf16(gelu(acc+bias))
// mode 2: Cf += acc+bias (residual)  mode 3: Cf  = acc+bias
__global__ __launch_bounds__(256, 3) void k_gemm(
    const u16t* __restrict__ A, const u16t* __restrict__ Bt,
    const float* __restrict__ bias, const float* __restrict__ b2,
    const float* __restrict__ b3, float* __restrict__ Cf,
    u16t* __restrict__ Cb, int M, int N, int K, int mode)
{
  __shared__ __align__(16) u16t SH[3 * 8192];   // 48 KiB ring; epilogue reuses

  const int nbn = N >> 7;                       // N / 128
  const int cpx = gridDim.x >> 3;
  const int wgid = (blockIdx.x & 7) * cpx + (blockIdx.x >> 3);
  const int bm = (wgid / nbn) << 7;             // 128-row tile
  const int bn = (wgid % nbn) << 7;             // 128-col tile

  const int tid = threadIdx.x, wave = tid >> 6, lane = tid & 63;
  const int lr = lane & 15, quad = lane >> 4;
  const int wm = (wave >> 1) << 6;              // 0 / 64
  const int wn = (wave & 1) << 6;               // 0 / 64

  const int sseg = (lane & 3) ^ ((lane >> 3) & 3);
  const u16t* gA = A + (size_t)(bm + (lane >> 2)) * K + sseg * 8;
  // packed B: per K-tile one contiguous 8KB blob
  const u16t* gBp = Bt + ((size_t)(bn >> 7) * (K >> 5)) * 4096 + (size_t)lane * 8;

  const int sw8 = (quad ^ ((lr >> 1) & 3)) << 3;
  const int aoff = (wm + lr) * 32 + sw8;          // + i*512 per M-frag
  const int boff = 4096 + (wn + lr) * 32 + sw8;   // + j*512 per N-frag

  f32x4 acc[4][4] = {};

  u16t* buf0 = SH;
  u16t* buf1 = SH + 8192;
  u16t* buf2 = SH + 16384;

#define STAGE(BUF_, S_) do {                                                   \
    g2l16((BUF_) + wave * 512,        gA + (size_t)(wave * 16) * K + (S_) * 32);   \
    g2l16((BUF_) + (wave + 4) * 512,  gA + (size_t)((wave + 4) * 16) * K + (S_) * 32); \
    g2l16((BUF_) + 4096 + wave * 512,       gBp + (size_t)(S_) * 4096 + wave * 512);   \
    g2l16((BUF_) + 4096 + (wave + 4) * 512, gBp + (size_t)(S_) * 4096 + (wave + 4) * 512); \
  } while (0)

  const int nt = K >> 5;
  STAGE(buf0, 0);
  STAGE(buf1, 1);

  for (int t = 0; t < nt - 1; ++t) {
    asm volatile("s_waitcnt vmcnt(4)" ::: "memory");
    __builtin_amdgcn_s_barrier();
    asm volatile("" ::: "memory");
    if (t + 2 < nt) STAGE(buf2, t + 2);
    bf16x8 af[4], bfr[4];
    #pragma unroll
    for (int i = 0; i < 4; ++i) af[i] = *(const bf16x8*)&buf0[aoff + i * 512];
    #pragma unroll
    for (int j = 0; j < 4; ++j) bfr[j] = *(const bf16x8*)&buf0[boff + j * 512];
    __builtin_amdgcn_s_setprio(1);
    #pragma unroll
    for (int j = 0; j < 4; ++j)
      #pragma unroll
      for (int i = 0; i < 4; ++i)
        acc[j][i] = __builtin_amdgcn_mfma_f32_16x16x32_bf16(bfr[j], af[i], acc[j][i], 0, 0, 0);
    __builtin_amdgcn_s_setprio(0);
    u16t* tmp = buf0; buf0 = buf1; buf1 = buf2; buf2 = tmp;
  }
  {
    asm volatile("s_waitcnt vmcnt(0)" ::: "memory");
    __builtin_amdgcn_s_barrier();
    asm volatile("" ::: "memory");
    bf16x8 af[4], bfr[4];
    #pragma unroll
    for (int i = 0; i < 4; ++i) af[i] = *(const bf16x8*)&buf0[aoff + i * 512];
    #pragma unroll
    for (int j = 0; j < 4; ++j) bfr[j] = *(const bf16x8*)&buf0[boff + j * 512];
    __builtin_amdgcn_s_setprio(1);
    #pragma unroll
    for (int j = 0; j < 4; ++j)
      #pragma unroll
      for (int i = 0; i < 4; ++i)
        acc[j][i] = __builtin_amdgcn_mfma_f32_16x16x32_bf16(bfr[j], af[i], acc[j][i], 0, 0, 0);
    __builtin_amdgcn_s_setprio(0);
  }
#undef STAGE

  const float* bp = bias;
  int reg0 = 0;
  if (bias && b2) { reg0 = (bn >> 9) << 9; bp = reg0 == 0 ? bias : (reg0 == 512 ? b2 : b3); }
  float4 bv[4];
  #pragma unroll
  for (int jN = 0; jN < 4; ++jN) {
    const int gn0 = bn + wn + jN * 16 + quad * 4;
    bv[jN] = bias ? *(const float4*)&bp[gn0 - reg0] : make_float4(0.f, 0.f, 0.f, 0.f);
  }

  if (mode <= 1) {
    __syncthreads();
    u16t* E = SH;      // [128][128] u16 (32KB), seg-swizzled
    #pragma unroll
    for (int jN = 0; jN < 4; ++jN) {
      const int cl = wn + jN * 16 + quad * 4;
      const int seg = cl >> 3, intra = cl & 7;
      #pragma unroll
      for (int iM = 0; iM < 4; ++iM) {
        const int r = wm + iM * 16 + lr;
        float v0 = acc[jN][iM][0] + bv[jN].x, v1 = acc[jN][iM][1] + bv[jN].y;
        float v2 = acc[jN][iM][2] + bv[jN].z, v3 = acc[jN][iM][3] + bv[jN].w;
        union { u16t h[4]; uint2 u; } pk;
        if (mode == 1) {
          pk.h[0] = f2b(gelu_erf(v0)); pk.h[1] = f2b(gelu_erf(v1));
          pk.h[2] = f2b(gelu_erf(v2)); pk.h[3] = f2b(gelu_erf(v3));
        } else {
          pk.h[0] = f2b(v0); pk.h[1] = f2b(v1); pk.h[2] = f2b(v2); pk.h[3] = f2b(v3);
        }
        *(uint2*)&E[r * 128 + ((seg ^ (r & 7)) << 3) + intra] = pk.u;
      }
    }
    __syncthreads();
    const int rr = tid >> 2, s0 = tid & 3;
    #pragma unroll
    for (int pass = 0; pass < 2; ++pass) {
      const int r = pass * 64 + rr;
      u16t* gout = Cb + (size_t)(bm + r) * N + bn;
      #pragma unroll
      for (int it = 0; it < 4; ++it) {
        const int s = s0 + it * 4;
        uint4 u = *(const uint4*)&E[r * 128 + ((s ^ (r & 7)) << 3)];
        *(uint4*)(gout + s * 8) = u;
      }
    }
  } else {
    #pragma unroll
    for (int jN = 0; jN < 4; ++jN) {
      const int gn0 = bn + wn + jN * 16 + quad * 4;
      #pragma unroll
      for (int iM = 0; iM < 4; ++iM) {
        const int gm = bm + wm + iM * 16 + lr;
        const size_t off = (size_t)gm * N + gn0;
        float v0 = acc[jN][iM][0] + bv[jN].x, v1 = acc[jN][iM][1] + bv[jN].y;
        float v2 = acc[jN][iM][2] + bv[jN].z, v3 = acc[jN][iM][3] + bv[jN].w;
        if (mode == 2) {
          float4 c = *(float4*)(Cf + off);
          c.x += v0; c.y += v1; c.z += v2; c.w += v3;
          *(float4*)(Cf + off) = c;
        } else {
          *(float4*)(Cf + off) = make_float4(v0, v1, v2, v3);
        }
      }
    }
  }
}

// ---------------- R10 GEMM: 256x128 tile, 2 blocks/CU (FF1 route) ----------
// UNPACKED B (R5-verified 60.4us; packed-B regressed this kernel in R6).
__global__ __launch_bounds__(256, 2) void k_gemmw(
    const u16t* __restrict__ A, const u16t* __restrict__ Bt,
    const float* __restrict__ bias, const float* __restrict__ b2,
    const float* __restrict__ b3, float* __restrict__ Cf,
    u16t* __restrict__ Cb, int M, int N, int K, int mode)
{
  __shared__ __align__(16) u16t SH[3 * 12288];   // 72 KiB ring; epilogue reuses

  const int nbn = N >> 7;                       // N / 128
  const int cpx = gridDim.x >> 3;
  const int wgid = (blockIdx.x & 7) * cpx + (blockIdx.x >> 3);
  const int bm = (wgid / nbn) << 8;             // 256-row tile
  const int bn = (wgid % nbn) << 7;             // 128-col tile

  const int tid = threadIdx.x, wave = tid >> 6, lane = tid & 63;
  const int lr = lane & 15, quad = lane >> 4;
  const int wm = (wave >> 1) << 7;              // 0 / 128
  const int wn = (wave & 1) << 6;               // 0 / 64

  const int sseg = (lane & 3) ^ ((lane >> 3) & 3);
  const u16t* gA = A + (size_t)(bm + (lane >> 2)) * K + sseg * 8;
  const u16t* gB = Bt + (size_t)(bn + (lane >> 2)) * K + sseg * 8;

  const int sw8 = (quad ^ ((lr >> 1) & 3)) << 3;
  const int aoff = (wm + lr) * 32 + sw8;          // + i*512 per M-frag
  const int boff = 8192 + (wn + lr) * 32 + sw8;   // + j*512 per N-frag

  f32x4 acc[4][8] = {};   // [jN][iM]

  u16t* buf0 = SH;
  u16t* buf1 = SH + 12288;
  u16t* buf2 = SH + 24576;

#define STAGE_W(BUF_, S_) do {                                                 \
    g2l16((BUF_) + wave * 512,        gA + (size_t)(wave * 16) * K + (S_) * 32);   \
    g2l16((BUF_) + (wave + 4) * 512,  gA + (size_t)((wave + 4) * 16) * K + (S_) * 32); \
    g2l16((BUF_) + (wave + 8) * 512,  gA + (size_t)((wave + 8) * 16) * K + (S_) * 32); \
    g2l16((BUF_) + (wave + 12) * 512, gA + (size_t)((wave + 12) * 16) * K + (S_) * 32); \
    g2l16((BUF_) + 8192 + wave * 512, gB + (size_t)(wave * 16) * K + (S_) * 32);   \
    g2l16((BUF_) + 8192 + (wave + 4) * 512, gB + (size_t)((wave + 4) * 16) * K + (S_) * 32); \
  } while (0)

  const int nt = K >> 5;
  STAGE_W(buf0, 0);
  STAGE_W(buf1, 1);

  for (int t = 0; t < nt - 1; ++t) {
    asm volatile("s_waitcnt vmcnt(6)" ::: "memory");
    __builtin_amdgcn_s_barrier();
    asm volatile("" ::: "memory");
    if (t + 2 < nt) STAGE_W(buf2, t + 2);
    bf16x8 af[8], bfr[4];
    #pragma unroll
    for (int i = 0; i < 8; ++i) af[i] = *(const bf16x8*)&buf0[aoff + i * 512];
    #pragma unroll
    for (int j = 0; j < 4; ++j) bfr[j] = *(const bf16x8*)&buf0[boff + j * 512];
    __builtin_amdgcn_s_setprio(1);
    #pragma unroll
    for (int j = 0; j < 4; ++j)
      #pragma unroll
      for (int i = 0; i < 8; ++i)
        acc[j][i] = __builtin_amdgcn_mfma_f32_16x16x32_bf16(bfr[j], af[i], acc[j][i], 0, 0, 0);
    __builtin_amdgcn_s_setprio(0);
    u16t* tmp = buf0; buf0 = buf1; buf1 = buf2; buf2 = tmp;
  }
  {
    asm volatile("s_waitcnt vmcnt(0)" ::: "memory");
    __builtin_amdgcn_s_barrier();
    asm volatile("" ::: "memory");
    bf16x8 af[8], bfr[4];
    #pragma unroll
    for (int i = 0; i < 8; ++i) af[i] = *(const bf16x8*)&buf0[aoff + i * 512];
    #pragma unroll
    for (int j = 0; j < 4; ++j) bfr[j] = *(const bf16x8*)&buf0[boff + j * 512];
    __builtin_amdgcn_s_setprio(1);
    #pragma unroll
    for (int j = 0; j < 4; ++j)
      #pragma unroll
      for (int i = 0; i < 8; ++i)
        acc[j][i] = __builtin_amdgcn_mfma_f32_16x16x32_bf16(bfr[j], af[i], acc[j][i], 0, 0, 0);
    __builtin_amdgcn_s_setprio(0);
  }
#undef STAGE_W

  const float* bp = bias;
  int reg0 = 0;
  if (bias && b2) { reg0 = (bn >> 9) << 9; bp = reg0 == 0 ? bias : (reg0 == 512 ? b2 : b3); }
  float4 bv[4];
  #pragma unroll
  for (int jN = 0; jN < 4; ++jN) {
    const int gn0 = bn + wn + jN * 16 + quad * 4;
    bv[jN] = bias ? *(const float4*)&bp[gn0 - reg0] : make_float4(0.f, 0.f, 0.f, 0.f);
  }

  if (mode <= 1) {
    __syncthreads();
    u16t* E = SH;
    #pragma unroll
    for (int jN = 0; jN < 4; ++jN) {
      const int cl = wn + jN * 16 + quad * 4;
      const int seg = cl >> 3, intra = cl & 7;
      #pragma unroll
      for (int iM = 0; iM < 8; ++iM) {
        const int r = wm + iM * 16 + lr;
        float v0 = acc[jN][iM][0] + bv[jN].x, v1 = acc[jN][iM][1] + bv[jN].y;
        float v2 = acc[jN][iM][2] + bv[jN].z, v3 = acc[jN][iM][3] + bv[jN].w;
        union { u16t h[4]; uint2 u; } pk;
        if (mode == 1) {
          pk.h[0] = f2b(gelu_erf(v0)); pk.h[1] = f2b(gelu_erf(v1));
          pk.h[2] = f2b(gelu_erf(v2)); pk.h[3] = f2b(gelu_erf(v3));
        } else {
          pk.h[0] = f2b(v0); pk.h[1] = f2b(v1); pk.h[2] = f2b(v2); pk.h[3] = f2b(v3);
        }
        *(uint2*)&E[r * 128 + ((seg ^ (r & 7)) << 3) + intra] = pk.u;
      }
    }
    __syncthreads();
    const int rr = tid >> 2, s0 = tid & 3;
    #pragma unroll
    for (int pass = 0; pass < 4; ++pass) {
      const int r = pass * 64 + rr;
      u16t* gout = Cb + (size_t)(bm + r) * N + bn;
      #pragma unroll
      for (int it = 0; it < 4; ++it) {
        const int s = s0 + it * 4;
        uint4 u = *(const uint4*)&E[r * 128 + ((s ^ (r & 7)) << 3)];
        *(uint4*)(gout + s * 8) = u;
      }
    }
  } else {
    #pragma unroll
    for (int jN = 0; jN < 4; ++jN) {
      const int gn0 = bn + wn + jN * 16 + quad * 4;
      #pragma unroll
      for (int iM = 0; iM < 8; ++iM) {
        const int gm = bm + wm + iM * 16 + lr;
        const size_t off = (size_t)gm * N + gn0;
        float v0 = acc[jN][iM][0] + bv[jN].x, v1 = acc[jN][iM][1] + bv[jN].y;
        float v2 = acc[jN][iM][2] + bv[jN].z, v3 = acc[jN][iM][3] + bv[jN].w;
        if (mode == 2) {
          float4 c = *(float4*)(Cf + off);
          c.x += v0; c.y += v1; c.z += v2; c.w += v3;
          *(float4*)(Cf + off) = c;
        } else {
          *(float4*)(Cf + off) = make_float4(v0, v1, v2, v3);
        }
      }
    }
  }
}

// ---------------- weight prep (pk=1: packed layout; pk=0: row-major W^T) ----
__global__ __launch_bounds__(256) void k_prep_w(
    const float* __restrict__ W, const float* __restrict__ down,
    const float* __restrict__ up, u16t* __restrict__ Wt, int K, int N,
    size_t ostride, int orow0, int pk)
{
  __shared__ float t[32][33];
  const int z = blockIdx.z;
  const float* Wz = W + (size_t)z * K * N;
  const int k0 = blockIdx.x * 32, n0 = blockIdx.y * 32;
  const int tx = threadIdx.x & 31, ty = threadIdx.x >> 5;
  for (int i = ty; i < 32; i += 8) {
    const int kk = k0 + i, nn = n0 + tx;
    float v = Wz[(size_t)kk * N + nn];
    if (down) {
      const float* dz = down + (size_t)z * K * 8 + (size_t)kk * 8;
      const float* uz = up + (size_t)z * 8 * N + nn;
      float lv = 0.f;
      #pragma unroll
      for (int r = 0; r < 8; ++r) lv += dz[r] * uz[(size_t)r * N];
      v += 2.0f * lv;   // LORA_SCALING
    }
    t[i][tx] = v;
  }
  __syncthreads();
  if (pk) {
    u16t* Wtz = Wt + (size_t)z * ostride;
    const int kt = k0 >> 5, seg = tx >> 3, intra = tx & 7;
    for (int i = ty; i < 32; i += 8) {
      const int n_g = orow0 + n0 + i;
      const int nb = n_g >> 7, cc = (n_g >> 4) & 7, rl = n_g & 15;
      Wtz[(((size_t)nb * (K >> 5) + kt) * 8 + cc) * 512 +
          (rl * 4 + (seg ^ ((rl >> 1) & 3))) * 8 + intra] = f2b(t[tx][i]);
    }
  } else {
    u16t* Wtz = Wt + (size_t)z * ostride + (size_t)orow0 * K;
    for (int i = ty; i < 32; i += 8)
      Wtz[(size_t)(n0 + i) * K + k0 + tx] = f2b(t[tx][i]);
  }
}

// ---------------- patch gather: pt[(b*256+np)*128 + f*16+p] = x[b, np*16+p, f]
__global__ void k_patch(const float* __restrict__ x, u16t* __restrict__ pt) {
  const int idx = blockIdx.x * 256 + threadIdx.x;
  const int col = idx & 127, row = idx >> 7;
  const int f = col >> 4, pp = col & 15;
  const int b = row >> 8, np = row & 255;
  pt[idx] = f2b(x[(((size_t)b << 12) + np * 16 + pp) * 8 + f]);
}

// ---------------- LayerNorm (one wave per 512-row) -> bf16 ----------------
__global__ __launch_bounds__(256) void k_ln(
    const float* __restrict__ xin, const float* __restrict__ w,
    const float* __restrict__ bb, u16t* __restrict__ y)
{
  const int row = blockIdx.x * 4 + (threadIdx.x >> 6);
  const int lane = threadIdx.x & 63;
  const float4* xr = (const float4*)(xin + (size_t)row * 512);
  float4 a = xr[lane * 2], c = xr[lane * 2 + 1];
  float s = a.x + a.y + a.z + a.w + c.x + c.y + c.z + c.w;
  float qq = a.x * a.x + a.y * a.y + a.z * a.z + a.w * a.w +
             c.x * c.x + c.y * c.y + c.z * c.z + c.w * c.w;
  #pragma unroll
  for (int o = 32; o > 0; o >>= 1) { s += __shfl_xor(s, o); qq += __shfl_xor(qq, o); }
  const float mean = s * (1.f / 512.f);
  const float rs = rsqrtf(qq * (1.f / 512.f) - mean * mean + 1e-5f);
  const float4* wr = (const float4*)w; const float4* br = (const float4*)bb;
  float4 w0 = wr[lane * 2], w1 = wr[lane * 2 + 1];
  float4 b0 = br[lane * 2], b1 = br[lane * 2 + 1];
  union { u16t h[8]; uint4 v; } pk;
  pk.h[0] = f2b((a.x - mean) * rs * w0.x + b0.x);
  pk.h[1] = f2b((a.y - mean) * rs * w0.y + b0.y);
  pk.h[2] = f2b((a.z - mean) * rs * w0.z + b0.z);
  pk.h[3] = f2b((a.w - mean) * rs * w0.w + b0.w);
  pk.h[4] = f2b((c.x - mean) * rs * w1.x + b1.x);
  pk.h[5] = f2b((c.y - mean) * rs * w1.y + b1.y);
  pk.h[6] = f2b((c.z - mean) * rs * w1.z + b1.z);
  pk.h[7] = f2b((c.w - mean) * rs * w1.w + b1.w);
  *(uint4*)(y + (size_t)row * 512 + lane * 8) = pk.v;
}

// ---------------- patch LN + pos_enc -> h (fp32) ----------------
__global__ __launch_bounds__(256) void k_ln_pos(
    const float* __restrict__ xin, const float* __restrict__ w,
    const float* __restrict__ bb, const float* __restrict__ pos,
    float* __restrict__ h)
{
  const int row = blockIdx.x * 4 + (threadIdx.x >> 6);
  const int lane = threadIdx.x & 63;
  const float4* xr = (const float4*)(xin + (size_t)row * 512);
  float4 a = xr[lane * 2], c = xr[lane * 2 + 1];
  float s = a.x + a.y + a.z + a.w + c.x + c.y + c.z + c.w;
  float qq = a.x * a.x + a.y * a.y + a.z * a.z + a.w * a.w +
             c.x * c.x + c.y * c.y + c.z * c.z + c.w * c.w;
  #pragma unroll
  for (int o = 32; o > 0; o >>= 1) { s += __shfl_xor(s, o); qq += __shfl_xor(qq, o); }
  const float mean = s * (1.f / 512.f);
  const float rs = rsqrtf(qq * (1.f / 512.f) - mean * mean + 1e-5f);
  const float4* wr = (const float4*)w; const float4* br = (const float4*)bb;
  float4 w0 = wr[lane * 2], w1 = wr[lane * 2 + 1];
  float4 b0 = br[lane * 2], b1 = br[lane * 2 + 1];
  const int np = row & 255;
  const float4* pr = (const float4*)(pos + (size_t)np * 512);
  float4 p0 = pr[lane * 2], p1 = pr[lane * 2 + 1];
  float4 o0, o1;
  o0.x = (a.x - mean) * rs * w0.x + b0.x + p0.x;
  o0.y = (a.y - mean) * rs * w0.y + b0.y + p0.y;
  o0.z = (a.z - mean) * rs * w0.z + b0.z + p0.z;
  o0.w = (a.w - mean) * rs * w0.w + b0.w + p0.w;
  o1.x = (c.x - mean) * rs * w1.x + b1.x + p1.x;
  o1.y = (c.y - mean) * rs * w1.y + b1.y + p1.y;
  o1.z = (c.z - mean) * rs * w1.z + b1.z + p1.z;
  o1.w = (c.w - mean) * rs * w1.w + b1.w + p1.w;
  float4* hr = (float4*)(h + (size_t)row * 512);
  hr[lane * 2] = o0; hr[lane * 2 + 1] = o1;
}

// ---------------- MFMA flash attention -------------------------------------
__global__ __launch_bounds__(256) void k_attn(
    const u16t* __restrict__ qkv, u16t* __restrict__ out)
{
  __shared__ __align__(16) u16t Qs[128 * LDSP];
  __shared__ __align__(16) u16t Ks[64 * LDSP];
  __shared__ __align__(16) u16t Vts[64 * LDSP];

  const int bh = blockIdx.x >> 1, half = blockIdx.x & 1;
  const int b = bh >> 3, hd = bh & 7;
  const int tid = threadIdx.x, wave = tid >> 6, lane = tid & 63;
  const int lr = lane & 15, quad = lane >> 4;

  const size_t rowbase = (size_t)b * 256;
  const u16t* qg = qkv + (rowbase + half * 128) * 1536 + hd * 64;
  const u16t* kg = qkv + rowbase * 1536 + 512 + hd * 64;
  const u16t* vg = qkv + rowbase * 1536 + 1024 + hd * 64;

  #pragma unroll
  for (int i = 0; i < 4; ++i) {
    const int idx = tid + i * 256, row = idx >> 3, seg = idx & 7;
    uint4 u = *(const uint4*)(qg + (size_t)row * 1536 + seg * 8);
    *(uint4*)&Qs[row * LDSP + seg * 8] = u;
  }
  __syncthreads();

  bf16x8 qf[2][2];
  #pragma unroll
  for (int qi = 0; qi < 2; ++qi)
    #pragma unroll
    for (int dh = 0; dh < 2; ++dh)
      qf[qi][dh] = *(const bf16x8*)&Qs[(wave * 32 + qi * 16 + lr) * LDSP + dh * 32 + quad * 8];

  f32x4 O[2][4] = {};
  float mrun[2] = {-1e30f, -1e30f}, lrun[2] = {0.f, 0.f};

  for (int c = 0; c < 4; ++c) {
    __syncthreads();
    #pragma unroll
    for (int i = 0; i < 2; ++i) {
      const int idx = tid + i * 256, row = idx >> 3, seg = idx & 7;
      uint4 u = *(const uint4*)(kg + (size_t)(c * 64 + row) * 1536 + seg * 8);
      *(uint4*)&Ks[row * LDSP + seg * 8] = u;
    }
    {
      const int key = tid & 63, dg = (tid >> 6) * 16;
      const u16t* vrow = vg + (size_t)(c * 64 + key) * 1536 + dg;
      union { u16t h[16]; uint4 v[2]; } tmp;
      tmp.v[0] = *(const uint4*)(vrow);
      tmp.v[1] = *(const uint4*)(vrow + 8);
      #pragma unroll
      for (int i = 0; i < 16; ++i)
        Vts[(dg + i) * LDSP + key] = tmp.h[i];
    }
    __syncthreads();

    #pragma unroll
    for (int qi = 0; qi < 2; ++qi) {
      f32x4 s[4];
      #pragma unroll
      for (int kt = 0; kt < 4; ++kt) {
        f32x4 a = {};
        #pragma unroll
        for (int dh = 0; dh < 2; ++dh) {
          bf16x8 kf = *(const bf16x8*)&Ks[(kt * 16 + lr) * LDSP + dh * 32 + quad * 8];
          a = __builtin_amdgcn_mfma_f32_16x16x32_bf16(kf, qf[qi][dh], a, 0, 0, 0);
        }
        s[kt] = a;
      }
      constexpr float SC = 0.125f * 1.44269504088896f;
      float cmax = -1e30f;
      #pragma unroll
      for (int kt = 0; kt < 4; ++kt)
        #pragma unroll
        for (int r = 0; r < 4; ++r) { s[kt][r] *= SC; cmax = fmaxf(cmax, s[kt][r]); }
      cmax = fmaxf(cmax, __shfl_xor(cmax, 16));
      cmax = fmaxf(cmax, __shfl_xor(cmax, 32));
      const float mn = fmaxf(mrun[qi], cmax);
      const float alpha = exp2f(mrun[qi] - mn);
      mrun[qi] = mn;
      float lsum = 0.f;
      s16x4 pf[4];
      #pragma unroll
      for (int kt = 0; kt < 4; ++kt) {
        #pragma unroll
        for (int r = 0; r < 4; ++r) {
          const u16t eb = f2b(exp2f(s[kt][r] - mn));
          pf[kt][r] = (short)eb;
          lsum += b2f(eb);
        }
      }
      lsum += __shfl_xor(lsum, 16);
      lsum += __shfl_xor(lsum, 32);
      lrun[qi] = lrun[qi] * alpha + lsum;
      #pragma unroll
      for (int dt = 0; dt < 4; ++dt) {
        f32x4 o = O[qi][dt];
        o[0] *= alpha; o[1] *= alpha; o[2] *= alpha; o[3] *= alpha;
        #pragma unroll
        for (int kt = 0; kt < 4; ++kt) {
          s16x4 vf = *(const s16x4*)&Vts[(dt * 16 + lr) * LDSP + kt * 16 + quad * 4];
          o = __builtin_amdgcn_mfma_f32_16x16x16bf16_1k(vf, pf[kt], o, 0, 0, 0);
        }
        O[qi][dt] = o;
      }
    }
  }
  #pragma unroll
  for (int qi = 0; qi < 2; ++qi) {
    const float rl = 1.f / lrun[qi];
    u16t* orow = out + (rowbase + half * 128 + wave * 32 + qi * 16 + lr) * 512 + hd * 64 + quad * 4;
    #pragma unroll
    for (int dt = 0; dt < 4; ++dt) {
      union { u16t h[4]; uint2 v; } pk;
      #pragma unroll
      for (int r = 0; r < 4; ++r) pk.h[r] = f2b(O[qi][dt][r] * rl);
      *(uint2*)(orow + dt * 16) = pk.v;
    }
  }
}

// ---------------- final mean over patches ----------------
__global__ void k_mean(const u16t* __restrict__ y, float* __restrict__ out) {
  const int b = blockIdx.x, d = threadIdx.x;   // 64 x 512
  float s = 0.f;
  #pragma unroll 8
  for (int np = 0; np < 256; ++np) s += b2f(y[((size_t)b * 256 + np) * 512 + d]);
  out[(size_t)b * 512 + d] = s * (1.f / 256.f);
}

// ---------------- host ----------------
extern "C" void kernel_launch(void* const* d_in, const int* in_sizes, int n_in,
                              void* d_out, int out_size, void* d_ws, size_t ws_size,
                              hipStream_t stream)
{
  (void)in_sizes; (void)n_in; (void)out_size;
  const float* x        = (const float*)d_in[0];
  const float* patch_w  = (const float*)d_in[1];
  const float* patch_b  = (const float*)d_in[2];
  const float* patch_ln_w = (const float*)d_in[3];
  const float* patch_ln_b = (const float*)d_in[4];
  const float* pos_enc  = (const float*)d_in[5];
  const float* ln1_w    = (const float*)d_in[6];
  const float* ln1_b    = (const float*)d_in[7];
  const float* q_w      = (const float*)d_in[8];
  const float* q_b      = (const float*)d_in[9];
  const float* k_w      = (const float*)d_in[10];
  const float* k_b      = (const float*)d_in[11];
  const float* v_w      = (const float*)d_in[12];
  const float* v_b      = (const float*)d_in[13];
  const float* lq_down  = (const float*)d_in[14];
  const float* lq_up    = (const float*)d_in[15];
  const float* lk_down  = (const float*)d_in[16];
  const float* lk_up    = (const float*)d_in[17];
  const float* lv_down  = (const float*)d_in[18];
  const float* lv_up    = (const float*)d_in[19];
  const float* o_w      = (const float*)d_in[20];
  const float* o_b      = (const float*)d_in[21];
  const float* ln2_w    = (const float*)d_in[22];
  const float* ln2_b    = (const float*)d_in[23];
  const float* ff1_w    = (const float*)d_in[24];
  const float* ff1_b    = (const float*)d_in[25];
  const float* ff2_w    = (const float*)d_in[26];
  const float* ff2_b    = (const float*)d_in[27];
  const float* norm_w   = (const float*)d_in[28];
  const float* norm_b   = (const float*)d_in[29];
  float* out = (float*)d_out;

  // workspace carve (~148.1 MiB)
  char* p = (char*)d_ws;
  float* h  = (float*)p;  p += (size_t)MROWS * 512 * 4;       // 32 MB
  u16t*  y  = (u16t*)p;   p += (size_t)MROWS * 512 * 2;       // 16 MB
  char* uni = p;          p += (size_t)4 * MROWS * 512 * 2;   // 64 MB union
  u16t* qkvb = (u16t*)uni;                                    // [M,1536] (48 MB)
  u16t* ab = (u16t*)(uni + (size_t)MROWS * 1536 * 2);         // [M,512]  (16 MB)
  u16t* g  = (u16t*)uni;                                      // [M,2048] aliases qkv+ab
  float* pe = (float*)uni;                                    // [M,512] fp32 (pre-LN patch)
  u16t* pt = (u16t*)(uni + (size_t)MROWS * 512 * 4);          // [M,128] after pe
  u16t* wqkv = (u16t*)p; p += (size_t)NLAYER * 1536 * 512 * 2;
  u16t* wo = (u16t*)p; p += (size_t)NLAYER * 512 * 512 * 2;
  u16t* w1 = (u16t*)p; p += (size_t)NLAYER * 512 * 2048 * 2;
  u16t* w2 = (u16t*)p; p += (size_t)NLAYER * 2048 * 512 * 2;
  u16t* wp = (u16t*)p; p += (size_t)512 * 128 * 2;
  if ((size_t)(p - (char*)d_ws) > ws_size) return;

  const dim3 blk(256);
  const size_t QKVS = (size_t)1536 * 512;
  // packed (pk=1) for 128^2-kernel consumers; unpacked (pk=0) for FF1/k_gemmw
  k_prep_w<<<dim3(16, 16, NLAYER), blk, 0, stream>>>(q_w, lq_down, lq_up, wqkv, 512, 512, QKVS, 0, 1);
  k_prep_w<<<dim3(16, 16, NLAYER), blk, 0, stream>>>(k_w, lk_down, lk_up, wqkv, 512, 512, QKVS, 512, 1);
  k_prep_w<<<dim3(16, 16, NLAYER), blk, 0, stream>>>(v_w, lv_down, lv_up, wqkv, 512, 512, QKVS, 1024, 1);
  k_prep_w<<<dim3(16, 16, NLAYER), blk, 0, stream>>>(o_w, nullptr, nullptr, wo, 512, 512, (size_t)512 * 512, 0, 1);
  k_prep_w<<<dim3(16, 64, NLAYER), blk, 0, stream>>>(ff1_w, nullptr, nullptr, w1, 512, 2048, (size_t)512 * 2048, 0, 0);
  k_prep_w<<<dim3(64, 16, NLAYER), blk, 0, stream>>>(ff2_w, nullptr, nullptr, w2, 2048, 512, (size_t)2048 * 512, 0, 1);
  k_prep_w<<<dim3(4, 16, 1),       blk, 0, stream>>>(patch_w, nullptr, nullptr, wp, 128, 512, 0, 0, 1);

  k_patch<<<dim3(MROWS * 128 / 256), blk, 0, stream>>>(x, pt);
  k_gemm<<<dim3(128 * 4), blk, 0, stream>>>(pt, wp, patch_b, nullptr, nullptr, pe, nullptr, MROWS, 512, 128, 3);
  k_ln_pos<<<dim3(MROWS / 4), blk, 0, stream>>>(pe, patch_ln_w, patch_ln_b, pos_enc, h);

  for (int i = 0; i < NLAYER; ++i) {
    const size_t ws512 = (size_t)i * 512 * 512, wsff = (size_t)i * 512 * 2048;
    k_ln<<<dim3(MROWS / 4), blk, 0, stream>>>(h, ln1_w + i * 512, ln1_b + i * 512, y);
    k_gemm<<<dim3(128 * 12), blk, 0, stream>>>(y, wqkv + i * QKVS, q_b + i * 512, k_b + i * 512,
                                               v_b + i * 512, nullptr, qkvb, MROWS, 1536, 512, 0);
    k_attn<<<dim3(1024), blk, 0, stream>>>(qkvb, ab);
    k_gemm<<<dim3(128 * 4), blk, 0, stream>>>(ab, wo + ws512, o_b + i * 512, nullptr, nullptr, h, nullptr, MROWS, 512, 512, 2);
    k_ln<<<dim3(MROWS / 4), blk, 0, stream>>>(h, ln2_w + i * 512, ln2_b + i * 512, y);
    k_gemmw<<<dim3(64 * 16), blk, 0, stream>>>(y, w1 + wsff, ff1_b + i * 2048, nullptr, nullptr, nullptr, g, MROWS, 2048, 512, 1);
    k_gemm<<<dim3(128 * 4), blk, 0, stream>>>(g, w2 + wsff, ff2_b + i * 512, nullptr, nullptr, h, nullptr, MROWS, 512, 2048, 2);
  }
  k_ln<<<dim3(MROWS / 4), blk, 0, stream>>>(h, norm_w, norm_b, y);
  k_mean<<<dim3(BATCH), dim3(512), 0, stream>>>(y, out);
}